// Round 1
// baseline (2213.066 us; speedup 1.0000x reference)
//
#include <hip/hip_runtime.h>
#include <hip/hip_bf16.h>

#define T_TOKENS 16384
#define DMODEL 512
#define FFEAT 64
#define DFEMB 64
#define RIN 576
#define DRH 128
#define NG 8
#define NES 2
#define NE 16
#define DHID 256

__device__ __forceinline__ float gelu_f(float x) {
    return 0.5f * x * (1.0f + erff(x * 0.7071067811865476f));
}

// ---------------- Kernel 1: LayerNorm + out = hidden ----------------
__global__ __launch_bounds__(64) void hg_ln_kernel(
    const float* __restrict__ hidden, const float* __restrict__ lng,
    const float* __restrict__ lnb, float* __restrict__ hbuf,
    float* __restrict__ out)
{
    const int t = blockIdx.x;
    const int lane = threadIdx.x;
    const float* row = hidden + (size_t)t * DMODEL;
    float4 v0 = ((const float4*)row)[lane * 2 + 0];
    float4 v1 = ((const float4*)row)[lane * 2 + 1];
    float s = v0.x + v0.y + v0.z + v0.w + v1.x + v1.y + v1.z + v1.w;
    #pragma unroll
    for (int m = 1; m < 64; m <<= 1) s += __shfl_xor(s, m);
    const float mu = s * (1.0f / DMODEL);
    float sq = 0.f;
    {
        float d;
        d = v0.x - mu; sq += d * d;  d = v0.y - mu; sq += d * d;
        d = v0.z - mu; sq += d * d;  d = v0.w - mu; sq += d * d;
        d = v1.x - mu; sq += d * d;  d = v1.y - mu; sq += d * d;
        d = v1.z - mu; sq += d * d;  d = v1.w - mu; sq += d * d;
    }
    #pragma unroll
    for (int m = 1; m < 64; m <<= 1) sq += __shfl_xor(sq, m);
    const float rstd = rsqrtf(sq * (1.0f / DMODEL) + 1e-5f);
    float4 g0 = ((const float4*)lng)[lane * 2 + 0];
    float4 g1 = ((const float4*)lng)[lane * 2 + 1];
    float4 b0 = ((const float4*)lnb)[lane * 2 + 0];
    float4 b1 = ((const float4*)lnb)[lane * 2 + 1];
    float4 h0, h1;
    h0.x = (v0.x - mu) * rstd * g0.x + b0.x;
    h0.y = (v0.y - mu) * rstd * g0.y + b0.y;
    h0.z = (v0.z - mu) * rstd * g0.z + b0.z;
    h0.w = (v0.w - mu) * rstd * g0.w + b0.w;
    h1.x = (v1.x - mu) * rstd * g1.x + b1.x;
    h1.y = (v1.y - mu) * rstd * g1.y + b1.y;
    h1.z = (v1.z - mu) * rstd * g1.z + b1.z;
    h1.w = (v1.w - mu) * rstd * g1.w + b1.w;
    float* hrow = hbuf + (size_t)t * DMODEL;
    ((float4*)hrow)[lane * 2 + 0] = h0;
    ((float4*)hrow)[lane * 2 + 1] = h1;
    float* orow = out + (size_t)t * DMODEL;
    ((float4*)orow)[lane * 2 + 0] = v0;
    ((float4*)orow)[lane * 2 + 1] = v1;
}

// ---------------- Kernel 2: routing ----------------
#define TT 16
#define RSTR 584   // 576 + 8 pad (stride %32 == 8, 16B aligned)

__global__ __launch_bounds__(256) void hg_router_kernel(
    const float* __restrict__ hbuf, const float* __restrict__ feat,
    const float* __restrict__ stageW, const float* __restrict__ stageb,
    const float* __restrict__ gfW, const float* __restrict__ gfb,
    const float* __restrict__ psW1, const float* __restrict__ psb1,
    const float* __restrict__ psW2, const float* __restrict__ psb2,
    const float* __restrict__ irW1, const float* __restrict__ irb1,
    const float* __restrict__ irW2, const float* __restrict__ irb2,
    int* __restrict__ counts, int* __restrict__ list_tok,
    float* __restrict__ list_w)
{
    __shared__ float s_rin[TT][RSTR];
    __shared__ float s_feat[TT][FFEAT + 4];
    __shared__ float s_gemb[TT][DFEMB + 8];
    __shared__ float s_glog[TT][NG];
    __shared__ float s_ilog[TT][NG][NES];

    const int thr = threadIdx.x;
    const int t0 = blockIdx.x * TT;

    // phase 0: load h rows and feat rows
    {
        const int ti = thr >> 4;
        const int cc = thr & 15;
        const float* hrow = hbuf + (size_t)(t0 + ti) * DMODEL;
        #pragma unroll
        for (int j = 0; j < 8; ++j) {
            const int col = cc * 4 + j * 64;
            *(float4*)&s_rin[ti][col] = *(const float4*)&hrow[col];
        }
        const float* frow = feat + (size_t)(t0 + ti) * FFEAT;
        *(float4*)&s_feat[ti][cc * 4] = *(const float4*)&frow[cc * 4];
    }
    __syncthreads();

    // phase 1: stage_emb -> s_rin[t][512..575]
    {
        const int ti = thr >> 4;
        const int j0 = (thr & 15) * 4;
        float a0 = stageb[j0], a1 = stageb[j0 + 1], a2 = stageb[j0 + 2], a3 = stageb[j0 + 3];
        #pragma unroll 8
        for (int f = 0; f < FFEAT; ++f) {
            const float a = s_feat[ti][f];
            float4 w = *(const float4*)&stageW[f * DFEMB + j0];
            a0 = fmaf(a, w.x, a0); a1 = fmaf(a, w.y, a1);
            a2 = fmaf(a, w.z, a2); a3 = fmaf(a, w.w, a3);
        }
        float4 r; r.x = a0; r.y = a1; r.z = a2; r.w = a3;
        *(float4*)&s_rin[ti][DMODEL + j0] = r;
    }
    __syncthreads();

    const int r = thr >> 5;   // rowgroup: tokens 2r, 2r+1
    const int c = thr & 31;   // colgroup: cols 4c..4c+3

    // phase 2: per-group scorers -> s_glog
    for (int g = 0; g < NG; ++g) {
        float acc0[4] = {0.f, 0.f, 0.f, 0.f};
        float acc1[4] = {0.f, 0.f, 0.f, 0.f};
        const float* W = psW1 + (size_t)g * RIN * DRH + c * 4;
        #pragma unroll 4
        for (int k = 0; k < RIN; ++k) {
            float4 w = *(const float4*)(W + (size_t)k * DRH);
            const float a0 = s_rin[2 * r + 0][k];
            const float a1 = s_rin[2 * r + 1][k];
            acc0[0] = fmaf(a0, w.x, acc0[0]); acc0[1] = fmaf(a0, w.y, acc0[1]);
            acc0[2] = fmaf(a0, w.z, acc0[2]); acc0[3] = fmaf(a0, w.w, acc0[3]);
            acc1[0] = fmaf(a1, w.x, acc1[0]); acc1[1] = fmaf(a1, w.y, acc1[1]);
            acc1[2] = fmaf(a1, w.z, acc1[2]); acc1[3] = fmaf(a1, w.w, acc1[3]);
        }
        float4 b1 = *(const float4*)&psb1[g * DRH + c * 4];
        float4 w2 = *(const float4*)&psW2[g * DRH + c * 4];
        float p0 = gelu_f(acc0[0] + b1.x) * w2.x + gelu_f(acc0[1] + b1.y) * w2.y
                 + gelu_f(acc0[2] + b1.z) * w2.z + gelu_f(acc0[3] + b1.w) * w2.w;
        float p1 = gelu_f(acc1[0] + b1.x) * w2.x + gelu_f(acc1[1] + b1.y) * w2.y
                 + gelu_f(acc1[2] + b1.z) * w2.z + gelu_f(acc1[3] + b1.w) * w2.w;
        #pragma unroll
        for (int m = 1; m < 32; m <<= 1) { p0 += __shfl_xor(p0, m); p1 += __shfl_xor(p1, m); }
        if (c == 0) {
            s_glog[2 * r + 0][g] = p0 + psb2[g];
            s_glog[2 * r + 1][g] = p1 + psb2[g];
        }
    }

    // phase 3: intra-group routers -> s_ilog
    for (int g = 0; g < NG; ++g) {
        __syncthreads();  // previous g's reads of s_gemb done
        {
            const int ti = thr >> 4;
            const int j0 = (thr & 15) * 4;
            float4 acc = *(const float4*)&gfb[g * DFEMB + j0];
            #pragma unroll
            for (int f = 0; f < 8; ++f) {
                const float a = s_feat[ti][g * 8 + f];
                float4 w = *(const float4*)&gfW[(size_t)(g * 8 + f) * DFEMB + j0];
                acc.x = fmaf(a, w.x, acc.x); acc.y = fmaf(a, w.y, acc.y);
                acc.z = fmaf(a, w.z, acc.z); acc.w = fmaf(a, w.w, acc.w);
            }
            *(float4*)&s_gemb[ti][j0] = acc;
        }
        __syncthreads();

        float acc0[4] = {0.f, 0.f, 0.f, 0.f};
        float acc1[4] = {0.f, 0.f, 0.f, 0.f};
        const float* W = irW1 + (size_t)g * RIN * DRH + c * 4;
        #pragma unroll 4
        for (int k = 0; k < DMODEL; ++k) {
            float4 w = *(const float4*)(W + (size_t)k * DRH);
            const float a0 = s_rin[2 * r + 0][k];
            const float a1 = s_rin[2 * r + 1][k];
            acc0[0] = fmaf(a0, w.x, acc0[0]); acc0[1] = fmaf(a0, w.y, acc0[1]);
            acc0[2] = fmaf(a0, w.z, acc0[2]); acc0[3] = fmaf(a0, w.w, acc0[3]);
            acc1[0] = fmaf(a1, w.x, acc1[0]); acc1[1] = fmaf(a1, w.y, acc1[1]);
            acc1[2] = fmaf(a1, w.z, acc1[2]); acc1[3] = fmaf(a1, w.w, acc1[3]);
        }
        #pragma unroll 4
        for (int k = 0; k < DFEMB; ++k) {
            float4 w = *(const float4*)(W + (size_t)(DMODEL + k) * DRH);
            const float a0 = s_gemb[2 * r + 0][k];
            const float a1 = s_gemb[2 * r + 1][k];
            acc0[0] = fmaf(a0, w.x, acc0[0]); acc0[1] = fmaf(a0, w.y, acc0[1]);
            acc0[2] = fmaf(a0, w.z, acc0[2]); acc0[3] = fmaf(a0, w.w, acc0[3]);
            acc1[0] = fmaf(a1, w.x, acc1[0]); acc1[1] = fmaf(a1, w.y, acc1[1]);
            acc1[2] = fmaf(a1, w.z, acc1[2]); acc1[3] = fmaf(a1, w.w, acc1[3]);
        }
        float4 b1 = *(const float4*)&irb1[g * DRH + c * 4];
        const float b1a[4] = {b1.x, b1.y, b1.z, b1.w};
        float q00 = 0.f, q01 = 0.f, q10 = 0.f, q11 = 0.f;
        #pragma unroll
        for (int j = 0; j < 4; ++j) {
            float2 wk = *(const float2*)&irW2[(size_t)(g * DRH + c * 4 + j) * NES];
            const float v0 = gelu_f(acc0[j] + b1a[j]);
            const float v1 = gelu_f(acc1[j] + b1a[j]);
            q00 = fmaf(v0, wk.x, q00); q01 = fmaf(v0, wk.y, q01);
            q10 = fmaf(v1, wk.x, q10); q11 = fmaf(v1, wk.y, q11);
        }
        #pragma unroll
        for (int m = 1; m < 32; m <<= 1) {
            q00 += __shfl_xor(q00, m); q01 += __shfl_xor(q01, m);
            q10 += __shfl_xor(q10, m); q11 += __shfl_xor(q11, m);
        }
        if (c == 0) {
            s_ilog[2 * r + 0][g][0] = q00 + irb2[g * NES + 0];
            s_ilog[2 * r + 0][g][1] = q01 + irb2[g * NES + 1];
            s_ilog[2 * r + 1][g][0] = q10 + irb2[g * NES + 0];
            s_ilog[2 * r + 1][g][1] = q11 + irb2[g * NES + 1];
        }
    }
    __syncthreads();

    // phase 4: top-2 groups -> softmax -> argmax expert -> expert lists
    if (thr < TT) {
        const int t = t0 + thr;
        float gl[NG];
        #pragma unroll
        for (int g = 0; g < NG; ++g) gl[g] = s_glog[thr][g];
        int i1 = 0; float m1 = gl[0];
        #pragma unroll
        for (int g = 1; g < NG; ++g) if (gl[g] > m1) { m1 = gl[g]; i1 = g; }
        int i2 = -1; float m2 = -3.4e38f;
        #pragma unroll
        for (int g = 0; g < NG; ++g) if (g != i1 && gl[g] > m2) { m2 = gl[g]; i2 = g; }
        const float ex = expf(m2 - m1);
        const float inv = 1.0f / (1.0f + ex);
        const int   gsel[2] = {i1, i2};
        const float wsel[2] = {inv, ex * inv};
        #pragma unroll
        for (int s = 0; s < 2; ++s) {
            const int g = gsel[s];
            const int kk = (s_ilog[thr][g][1] > s_ilog[thr][g][0]) ? 1 : 0;
            const int eid = g * NES + kk;
            const int pos = atomicAdd(&counts[eid], 1);
            list_tok[(size_t)eid * T_TOKENS + pos] = t;
            list_w[(size_t)eid * T_TOKENS + pos] = wsel[s];
        }
    }
}

// ---------------- Kernel 3: sparse experts ----------------
#define ET 16
#define HSTR 520
#define EHSTR 264

__global__ __launch_bounds__(256) void hg_expert_kernel(
    const float* __restrict__ hbuf,
    const float* __restrict__ eW1, const float* __restrict__ eb1,
    const float* __restrict__ eW2, const float* __restrict__ eb2,
    const float* __restrict__ alpha_p,
    const int* __restrict__ counts, const int* __restrict__ list_tok,
    const float* __restrict__ list_w, float* __restrict__ out)
{
    const int e = blockIdx.y;
    const int cnt = counts[e];
    const int base = blockIdx.x * ET;
    if (base >= cnt) return;
    const int n = min(ET, cnt - base);

    __shared__ float s_h[ET][HSTR];
    __shared__ float s_eh[ET][EHSTR];
    __shared__ int   s_tok[ET];
    __shared__ float s_w[ET];

    const int thr = threadIdx.x;
    if (thr < ET) {
        const int i = thr;
        const int src = base + ((i < n) ? i : (n - 1));
        s_tok[i] = list_tok[(size_t)e * T_TOKENS + src];
        s_w[i]   = (i < n) ? list_w[(size_t)e * T_TOKENS + base + i] : 0.0f;
    }
    __syncthreads();

    // gather h rows
    {
        const int ti = thr >> 4;
        const int cc = thr & 15;
        const float* hrow = hbuf + (size_t)s_tok[ti] * DMODEL;
        #pragma unroll
        for (int j = 0; j < 8; ++j) {
            const int col = cc * 4 + j * 64;
            *(float4*)&s_h[ti][col] = *(const float4*)&hrow[col];
        }
    }
    __syncthreads();

    const int r = thr >> 5;  // tokens 2r, 2r+1
    const int c = thr & 31;  // cols 8c..8c+7

    // GEMM1: eh = gelu(h @ eW1 + eb1), 512 -> 256
    {
        float acc0[8] = {0.f,0.f,0.f,0.f,0.f,0.f,0.f,0.f};
        float acc1[8] = {0.f,0.f,0.f,0.f,0.f,0.f,0.f,0.f};
        const float* W = eW1 + (size_t)e * DMODEL * DHID + c * 8;
        #pragma unroll 4
        for (int k = 0; k < DMODEL; ++k) {
            float4 wa = *(const float4*)(W + (size_t)k * DHID);
            float4 wb = *(const float4*)(W + (size_t)k * DHID + 4);
            const float a0 = s_h[2 * r + 0][k];
            const float a1 = s_h[2 * r + 1][k];
            acc0[0] = fmaf(a0, wa.x, acc0[0]); acc0[1] = fmaf(a0, wa.y, acc0[1]);
            acc0[2] = fmaf(a0, wa.z, acc0[2]); acc0[3] = fmaf(a0, wa.w, acc0[3]);
            acc0[4] = fmaf(a0, wb.x, acc0[4]); acc0[5] = fmaf(a0, wb.y, acc0[5]);
            acc0[6] = fmaf(a0, wb.z, acc0[6]); acc0[7] = fmaf(a0, wb.w, acc0[7]);
            acc1[0] = fmaf(a1, wa.x, acc1[0]); acc1[1] = fmaf(a1, wa.y, acc1[1]);
            acc1[2] = fmaf(a1, wa.z, acc1[2]); acc1[3] = fmaf(a1, wa.w, acc1[3]);
            acc1[4] = fmaf(a1, wb.x, acc1[4]); acc1[5] = fmaf(a1, wb.y, acc1[5]);
            acc1[6] = fmaf(a1, wb.z, acc1[6]); acc1[7] = fmaf(a1, wb.w, acc1[7]);
        }
        float4 ba = *(const float4*)&eb1[e * DHID + c * 8];
        float4 bb = *(const float4*)&eb1[e * DHID + c * 8 + 4];
        const float bias[8] = {ba.x, ba.y, ba.z, ba.w, bb.x, bb.y, bb.z, bb.w};
        #pragma unroll
        for (int j = 0; j < 8; ++j) {
            s_eh[2 * r + 0][c * 8 + j] = gelu_f(acc0[j] + bias[j]);
            s_eh[2 * r + 1][c * 8 + j] = gelu_f(acc1[j] + bias[j]);
        }
    }
    __syncthreads();

    // GEMM2: out += alpha * w * (eh @ eW2 + eb2), 256 -> 512 in 2 passes
    const float alpha = alpha_p[0];
    const float w0 = s_w[2 * r + 0] * alpha;
    const float w1 = s_w[2 * r + 1] * alpha;
    for (int p = 0; p < 2; ++p) {
        float acc0[8] = {0.f,0.f,0.f,0.f,0.f,0.f,0.f,0.f};
        float acc1[8] = {0.f,0.f,0.f,0.f,0.f,0.f,0.f,0.f};
        const int col0 = p * 256 + c * 8;
        const float* W = eW2 + (size_t)e * DHID * DMODEL + col0;
        #pragma unroll 4
        for (int k = 0; k < DHID; ++k) {
            float4 wa = *(const float4*)(W + (size_t)k * DMODEL);
            float4 wb = *(const float4*)(W + (size_t)k * DMODEL + 4);
            const float a0 = s_eh[2 * r + 0][k];
            const float a1 = s_eh[2 * r + 1][k];
            acc0[0] = fmaf(a0, wa.x, acc0[0]); acc0[1] = fmaf(a0, wa.y, acc0[1]);
            acc0[2] = fmaf(a0, wa.z, acc0[2]); acc0[3] = fmaf(a0, wa.w, acc0[3]);
            acc0[4] = fmaf(a0, wb.x, acc0[4]); acc0[5] = fmaf(a0, wb.y, acc0[5]);
            acc0[6] = fmaf(a0, wb.z, acc0[6]); acc0[7] = fmaf(a0, wb.w, acc0[7]);
            acc1[0] = fmaf(a1, wa.x, acc1[0]); acc1[1] = fmaf(a1, wa.y, acc1[1]);
            acc1[2] = fmaf(a1, wa.z, acc1[2]); acc1[3] = fmaf(a1, wa.w, acc1[3]);
            acc1[4] = fmaf(a1, wb.x, acc1[4]); acc1[5] = fmaf(a1, wb.y, acc1[5]);
            acc1[6] = fmaf(a1, wb.z, acc1[6]); acc1[7] = fmaf(a1, wb.w, acc1[7]);
        }
        float4 ba = *(const float4*)&eb2[e * DMODEL + col0];
        float4 bb = *(const float4*)&eb2[e * DMODEL + col0 + 4];
        const float bias[8] = {ba.x, ba.y, ba.z, ba.w, bb.x, bb.y, bb.z, bb.w};
        float* o0 = out + (size_t)s_tok[2 * r + 0] * DMODEL + col0;
        float* o1 = out + (size_t)s_tok[2 * r + 1] * DMODEL + col0;
        #pragma unroll
        for (int j = 0; j < 8; ++j) {
            atomicAdd(&o0[j], w0 * (acc0[j] + bias[j]));
            atomicAdd(&o1[j], w1 * (acc1[j] + bias[j]));
        }
    }
}

// ---------------- launch ----------------
extern "C" void kernel_launch(void* const* d_in, const int* in_sizes, int n_in,
                              void* d_out, int out_size, void* d_ws, size_t ws_size,
                              hipStream_t stream) {
    const float* hidden = (const float*)d_in[0];
    const float* feat   = (const float*)d_in[1];
    const float* ln_g   = (const float*)d_in[2];
    const float* ln_b   = (const float*)d_in[3];
    const float* stageW = (const float*)d_in[4];
    const float* stageb = (const float*)d_in[5];
    const float* gfW    = (const float*)d_in[6];
    const float* gfb    = (const float*)d_in[7];
    const float* psW1   = (const float*)d_in[8];
    const float* psb1   = (const float*)d_in[9];
    const float* psW2   = (const float*)d_in[10];
    const float* psb2   = (const float*)d_in[11];
    const float* irW1   = (const float*)d_in[12];
    const float* irb1   = (const float*)d_in[13];
    const float* irW2   = (const float*)d_in[14];
    const float* irb2   = (const float*)d_in[15];
    const float* eW1    = (const float*)d_in[16];
    const float* eb1    = (const float*)d_in[17];
    const float* eW2    = (const float*)d_in[18];
    const float* eb2    = (const float*)d_in[19];
    const float* alpha  = (const float*)d_in[20];

    float* out = (float*)d_out;
    float* hbuf = (float*)d_ws;
    int* counts = (int*)(hbuf + (size_t)T_TOKENS * DMODEL);
    int* list_tok = counts + 32;
    float* list_w = (float*)(list_tok + (size_t)NE * T_TOKENS);

    hipMemsetAsync(counts, 0, 32 * sizeof(int), stream);

    hg_ln_kernel<<<T_TOKENS, 64, 0, stream>>>(hidden, ln_g, ln_b, hbuf, out);

    hg_router_kernel<<<T_TOKENS / TT, 256, 0, stream>>>(
        hbuf, feat, stageW, stageb, gfW, gfb, psW1, psb1, psW2, psb2,
        irW1, irb1, irW2, irb2, counts, list_tok, list_w);

    dim3 eg(T_TOKENS / ET, NE);
    hg_expert_kernel<<<eg, 256, 0, stream>>>(
        hbuf, eW1, eb1, eW2, eb2, alpha, counts, list_tok, list_w, out);
}

// Round 2
// 1995.536 us; speedup vs baseline: 1.1090x; 1.1090x over previous
//
#include <hip/hip_runtime.h>
#include <hip/hip_bf16.h>

#define T_TOKENS 16384
#define DMODEL 512
#define FFEAT 64
#define DFEMB 64
#define RIN 576
#define DRH 128
#define NG 8
#define NES 2
#define NE 16
#define DHID 256

__device__ __forceinline__ float gelu_f(float x) {
    return 0.5f * x * (1.0f + erff(x * 0.7071067811865476f));
}

// ---------------- Kernel 1: LayerNorm + out = hidden ----------------
__global__ __launch_bounds__(64) void hg_ln_kernel(
    const float* __restrict__ hidden, const float* __restrict__ lng,
    const float* __restrict__ lnb, float* __restrict__ hbuf,
    float* __restrict__ out)
{
    const int t = blockIdx.x;
    const int lane = threadIdx.x;
    const float* row = hidden + (size_t)t * DMODEL;
    float4 v0 = ((const float4*)row)[lane * 2 + 0];
    float4 v1 = ((const float4*)row)[lane * 2 + 1];
    float s = v0.x + v0.y + v0.z + v0.w + v1.x + v1.y + v1.z + v1.w;
    #pragma unroll
    for (int m = 1; m < 64; m <<= 1) s += __shfl_xor(s, m);
    const float mu = s * (1.0f / DMODEL);
    float sq = 0.f;
    {
        float d;
        d = v0.x - mu; sq += d * d;  d = v0.y - mu; sq += d * d;
        d = v0.z - mu; sq += d * d;  d = v0.w - mu; sq += d * d;
        d = v1.x - mu; sq += d * d;  d = v1.y - mu; sq += d * d;
        d = v1.z - mu; sq += d * d;  d = v1.w - mu; sq += d * d;
    }
    #pragma unroll
    for (int m = 1; m < 64; m <<= 1) sq += __shfl_xor(sq, m);
    const float rstd = rsqrtf(sq * (1.0f / DMODEL) + 1e-5f);
    float4 g0 = ((const float4*)lng)[lane * 2 + 0];
    float4 g1 = ((const float4*)lng)[lane * 2 + 1];
    float4 b0 = ((const float4*)lnb)[lane * 2 + 0];
    float4 b1 = ((const float4*)lnb)[lane * 2 + 1];
    float4 h0, h1;
    h0.x = (v0.x - mu) * rstd * g0.x + b0.x;
    h0.y = (v0.y - mu) * rstd * g0.y + b0.y;
    h0.z = (v0.z - mu) * rstd * g0.z + b0.z;
    h0.w = (v0.w - mu) * rstd * g0.w + b0.w;
    h1.x = (v1.x - mu) * rstd * g1.x + b1.x;
    h1.y = (v1.y - mu) * rstd * g1.y + b1.y;
    h1.z = (v1.z - mu) * rstd * g1.z + b1.z;
    h1.w = (v1.w - mu) * rstd * g1.w + b1.w;
    float* hrow = hbuf + (size_t)t * DMODEL;
    ((float4*)hrow)[lane * 2 + 0] = h0;
    ((float4*)hrow)[lane * 2 + 1] = h1;
    float* orow = out + (size_t)t * DMODEL;
    ((float4*)orow)[lane * 2 + 0] = v0;
    ((float4*)orow)[lane * 2 + 1] = v1;
}

// ---------------- Kernel 2: router as tiled GEMM ----------------
// Block = 64 tokens x 1 group. N = 256 (ps 128 | ir 128). K = 512 (h, shared)
// + 64 tail (stage_emb for ps, gemb for ir). Second layers fused.
#define BM 64
#define KT 32
#define XSTR 68   // 64 + 4 pad, keeps float4 alignment (68*4 % 16 == 0)

__global__ __launch_bounds__(256) void hg_router_big(
    const float* __restrict__ hbuf, const float* __restrict__ feat,
    const float* __restrict__ stageW, const float* __restrict__ stageb,
    const float* __restrict__ gfW, const float* __restrict__ gfb,
    const float* __restrict__ psW1, const float* __restrict__ psb1,
    const float* __restrict__ psW2, const float* __restrict__ psb2,
    const float* __restrict__ irW1, const float* __restrict__ irb1,
    const float* __restrict__ irW2, const float* __restrict__ irb2,
    float* __restrict__ glog_buf, float* __restrict__ ilog_buf)
{
    __shared__ float s_xT[2][KT][XSTR];   // h K-tile, transposed [k][token]
    __shared__ float s_psT[DFEMB][XSTR];  // stage_emb transposed [j][token]
    __shared__ float s_irT[DFEMB][XSTR];  // gemb transposed
    __shared__ float s_feat[BM][FFEAT + 4];

    const int thr = threadIdx.x;
    const int t0 = blockIdx.x * BM;
    const int g  = blockIdx.y;
    const int tg = thr >> 5;          // 0..7  token group (8 tokens each)
    const int cg = thr & 31;          // 0..31 col group
    const bool isPS = (cg < 16);
    const int colb = (cg & 15) * 8;   // 0..120

    // stage h K-tile (transposed) into LDS
    auto stage = [&](int buf, int kt) {
        const int ti = thr >> 2;
        const int ko = (thr & 3) * 8;
        const float* hp = hbuf + (size_t)(t0 + ti) * DMODEL + kt * KT + ko;
        float4 a = ((const float4*)hp)[0];
        float4 b = ((const float4*)hp)[1];
        s_xT[buf][ko + 0][ti] = a.x; s_xT[buf][ko + 1][ti] = a.y;
        s_xT[buf][ko + 2][ti] = a.z; s_xT[buf][ko + 3][ti] = a.w;
        s_xT[buf][ko + 4][ti] = b.x; s_xT[buf][ko + 5][ti] = b.y;
        s_xT[buf][ko + 6][ti] = b.z; s_xT[buf][ko + 7][ti] = b.w;
    };

    // ---- preamble: load feat tile + first h tile ----
    {
        const int ti = thr >> 2;
        const int f0 = (thr & 3) * 16;
        const float* fr = feat + (size_t)(t0 + ti) * FFEAT + f0;
        float4 a = ((const float4*)fr)[0];
        float4 b = ((const float4*)fr)[1];
        float4 c = ((const float4*)fr)[2];
        float4 d = ((const float4*)fr)[3];
        *(float4*)&s_feat[ti][f0 + 0]  = a;
        *(float4*)&s_feat[ti][f0 + 4]  = b;
        *(float4*)&s_feat[ti][f0 + 8]  = c;
        *(float4*)&s_feat[ti][f0 + 12] = d;
    }
    stage(0, 0);
    __syncthreads();

    // ---- compute stage_emb and gemb (transposed into LDS) ----
    {
        const int jj = (thr & 15) * 4;      // 4 emb cols
        const int tq = (thr >> 4) * 4;      // 4 tokens
        float4 acc0, acc1, acc2, acc3;
        float4 bs = *(const float4*)&stageb[jj];
        acc0 = bs; acc1 = bs; acc2 = bs; acc3 = bs;
        #pragma unroll 8
        for (int f = 0; f < FFEAT; ++f) {
            float4 w = *(const float4*)&stageW[f * DFEMB + jj];
            float a0 = s_feat[tq + 0][f], a1 = s_feat[tq + 1][f];
            float a2 = s_feat[tq + 2][f], a3 = s_feat[tq + 3][f];
            acc0.x = fmaf(a0, w.x, acc0.x); acc0.y = fmaf(a0, w.y, acc0.y);
            acc0.z = fmaf(a0, w.z, acc0.z); acc0.w = fmaf(a0, w.w, acc0.w);
            acc1.x = fmaf(a1, w.x, acc1.x); acc1.y = fmaf(a1, w.y, acc1.y);
            acc1.z = fmaf(a1, w.z, acc1.z); acc1.w = fmaf(a1, w.w, acc1.w);
            acc2.x = fmaf(a2, w.x, acc2.x); acc2.y = fmaf(a2, w.y, acc2.y);
            acc2.z = fmaf(a2, w.z, acc2.z); acc2.w = fmaf(a2, w.w, acc2.w);
            acc3.x = fmaf(a3, w.x, acc3.x); acc3.y = fmaf(a3, w.y, acc3.y);
            acc3.z = fmaf(a3, w.z, acc3.z); acc3.w = fmaf(a3, w.w, acc3.w);
        }
        s_psT[jj + 0][tq + 0] = acc0.x; s_psT[jj + 1][tq + 0] = acc0.y;
        s_psT[jj + 2][tq + 0] = acc0.z; s_psT[jj + 3][tq + 0] = acc0.w;
        s_psT[jj + 0][tq + 1] = acc1.x; s_psT[jj + 1][tq + 1] = acc1.y;
        s_psT[jj + 2][tq + 1] = acc1.z; s_psT[jj + 3][tq + 1] = acc1.w;
        s_psT[jj + 0][tq + 2] = acc2.x; s_psT[jj + 1][tq + 2] = acc2.y;
        s_psT[jj + 2][tq + 2] = acc2.z; s_psT[jj + 3][tq + 2] = acc2.w;
        s_psT[jj + 0][tq + 3] = acc3.x; s_psT[jj + 1][tq + 3] = acc3.y;
        s_psT[jj + 2][tq + 3] = acc3.z; s_psT[jj + 3][tq + 3] = acc3.w;

        float4 gb = *(const float4*)&gfb[g * DFEMB + jj];
        acc0 = gb; acc1 = gb; acc2 = gb; acc3 = gb;
        #pragma unroll
        for (int f = 0; f < 8; ++f) {
            float4 w = *(const float4*)&gfW[((size_t)g * 8 + f) * DFEMB + jj];
            float a0 = s_feat[tq + 0][g * 8 + f], a1 = s_feat[tq + 1][g * 8 + f];
            float a2 = s_feat[tq + 2][g * 8 + f], a3 = s_feat[tq + 3][g * 8 + f];
            acc0.x = fmaf(a0, w.x, acc0.x); acc0.y = fmaf(a0, w.y, acc0.y);
            acc0.z = fmaf(a0, w.z, acc0.z); acc0.w = fmaf(a0, w.w, acc0.w);
            acc1.x = fmaf(a1, w.x, acc1.x); acc1.y = fmaf(a1, w.y, acc1.y);
            acc1.z = fmaf(a1, w.z, acc1.z); acc1.w = fmaf(a1, w.w, acc1.w);
            acc2.x = fmaf(a2, w.x, acc2.x); acc2.y = fmaf(a2, w.y, acc2.y);
            acc2.z = fmaf(a2, w.z, acc2.z); acc2.w = fmaf(a2, w.w, acc2.w);
            acc3.x = fmaf(a3, w.x, acc3.x); acc3.y = fmaf(a3, w.y, acc3.y);
            acc3.z = fmaf(a3, w.z, acc3.z); acc3.w = fmaf(a3, w.w, acc3.w);
        }
        s_irT[jj + 0][tq + 0] = acc0.x; s_irT[jj + 1][tq + 0] = acc0.y;
        s_irT[jj + 2][tq + 0] = acc0.z; s_irT[jj + 3][tq + 0] = acc0.w;
        s_irT[jj + 0][tq + 1] = acc1.x; s_irT[jj + 1][tq + 1] = acc1.y;
        s_irT[jj + 2][tq + 1] = acc1.z; s_irT[jj + 3][tq + 1] = acc1.w;
        s_irT[jj + 0][tq + 2] = acc2.x; s_irT[jj + 1][tq + 2] = acc2.y;
        s_irT[jj + 2][tq + 2] = acc2.z; s_irT[jj + 3][tq + 2] = acc2.w;
        s_irT[jj + 0][tq + 3] = acc3.x; s_irT[jj + 1][tq + 3] = acc3.y;
        s_irT[jj + 2][tq + 3] = acc3.z; s_irT[jj + 3][tq + 3] = acc3.w;
    }
    __syncthreads();

    // ---- main K loop over h (double-buffered) ----
    float acc[8][8];
    #pragma unroll
    for (int i = 0; i < 8; ++i)
        #pragma unroll
        for (int j = 0; j < 8; ++j) acc[i][j] = 0.f;

    const float* W1 = (isPS ? psW1 : irW1) + (size_t)g * RIN * DRH + colb;

    const int NKT = DMODEL / KT;  // 16
    for (int kt = 0; kt < NKT; ++kt) {
        const int cur = kt & 1;
        if (kt + 1 < NKT) stage(cur ^ 1, kt + 1);
        const float* Wk = W1 + (size_t)(kt * KT) * DRH;
        #pragma unroll 2
        for (int k = 0; k < KT; ++k) {
            float4 wa = *(const float4*)(Wk + (size_t)k * DRH);
            float4 wb = *(const float4*)(Wk + (size_t)k * DRH + 4);
            float4 a0 = *(const float4*)&s_xT[cur][k][tg * 8];
            float4 a1 = *(const float4*)&s_xT[cur][k][tg * 8 + 4];
            const float av[8] = {a0.x, a0.y, a0.z, a0.w, a1.x, a1.y, a1.z, a1.w};
            const float wv[8] = {wa.x, wa.y, wa.z, wa.w, wb.x, wb.y, wb.z, wb.w};
            #pragma unroll
            for (int i = 0; i < 8; ++i)
                #pragma unroll
                for (int j = 0; j < 8; ++j)
                    acc[i][j] = fmaf(av[i], wv[j], acc[i][j]);
        }
        __syncthreads();
    }

    // ---- K tail: 64 rows (stage_emb for ps, gemb for ir) ----
    {
        const float* Wk = W1 + (size_t)DMODEL * DRH;
        const float (*xT)[XSTR] = isPS ? s_psT : s_irT;
        #pragma unroll 2
        for (int k = 0; k < DFEMB; ++k) {
            float4 wa = *(const float4*)(Wk + (size_t)k * DRH);
            float4 wb = *(const float4*)(Wk + (size_t)k * DRH + 4);
            float4 a0 = *(const float4*)&xT[k][tg * 8];
            float4 a1 = *(const float4*)&xT[k][tg * 8 + 4];
            const float av[8] = {a0.x, a0.y, a0.z, a0.w, a1.x, a1.y, a1.z, a1.w};
            const float wv[8] = {wa.x, wa.y, wa.z, wa.w, wb.x, wb.y, wb.z, wb.w};
            #pragma unroll
            for (int i = 0; i < 8; ++i)
                #pragma unroll
                for (int j = 0; j < 8; ++j)
                    acc[i][j] = fmaf(av[i], wv[j], acc[i][j]);
        }
    }

    // ---- second layers, fused ----
    if (isPS) {
        float4 ba = *(const float4*)&psb1[g * DRH + colb];
        float4 bb = *(const float4*)&psb1[g * DRH + colb + 4];
        float4 wa = *(const float4*)&psW2[g * DRH + colb];
        float4 wb = *(const float4*)&psW2[g * DRH + colb + 4];
        const float b1[8] = {ba.x, ba.y, ba.z, ba.w, bb.x, bb.y, bb.z, bb.w};
        const float w2[8] = {wa.x, wa.y, wa.z, wa.w, wb.x, wb.y, wb.z, wb.w};
        float p[8];
        #pragma unroll
        for (int i = 0; i < 8; ++i) {
            float s = 0.f;
            #pragma unroll
            for (int j = 0; j < 8; ++j) s += gelu_f(acc[i][j] + b1[j]) * w2[j];
            p[i] = s;
        }
        #pragma unroll
        for (int m = 1; m < 16; m <<= 1)
            #pragma unroll
            for (int i = 0; i < 8; ++i) p[i] += __shfl_xor(p[i], m);
        if (cg == 0) {
            const float b2 = psb2[g];
            #pragma unroll
            for (int i = 0; i < 8; ++i)
                glog_buf[(size_t)(t0 + tg * 8 + i) * NG + g] = p[i] + b2;
        }
    } else {
        float4 ba = *(const float4*)&irb1[g * DRH + colb];
        float4 bb = *(const float4*)&irb1[g * DRH + colb + 4];
        const float b1[8] = {ba.x, ba.y, ba.z, ba.w, bb.x, bb.y, bb.z, bb.w};
        float wk0[8], wk1[8];
        #pragma unroll
        for (int j = 0; j < 8; ++j) {
            float2 wk = *(const float2*)&irW2[(size_t)(g * DRH + colb + j) * NES];
            wk0[j] = wk.x; wk1[j] = wk.y;
        }
        float q0[8], q1[8];
        #pragma unroll
        for (int i = 0; i < 8; ++i) {
            float s0 = 0.f, s1 = 0.f;
            #pragma unroll
            for (int j = 0; j < 8; ++j) {
                float v = gelu_f(acc[i][j] + b1[j]);
                s0 = fmaf(v, wk0[j], s0);
                s1 = fmaf(v, wk1[j], s1);
            }
            q0[i] = s0; q1[i] = s1;
        }
        #pragma unroll
        for (int m = 1; m < 16; m <<= 1)
            #pragma unroll
            for (int i = 0; i < 8; ++i) {
                q0[i] += __shfl_xor(q0[i], m);
                q1[i] += __shfl_xor(q1[i], m);
            }
        if (cg == 16) {
            const float b20 = irb2[g * NES + 0];
            const float b21 = irb2[g * NES + 1];
            #pragma unroll
            for (int i = 0; i < 8; ++i) {
                const size_t t = t0 + tg * 8 + i;
                ilog_buf[t * (NG * NES) + g * NES + 0] = q0[i] + b20;
                ilog_buf[t * (NG * NES) + g * NES + 1] = q1[i] + b21;
            }
        }
    }
}

// ---------------- Kernel 2b: finalize routing, build expert lists ----------------
__global__ __launch_bounds__(256) void hg_finalize(
    const float* __restrict__ glog_buf, const float* __restrict__ ilog_buf,
    int* __restrict__ counts, int* __restrict__ list_tok,
    float* __restrict__ list_w)
{
    const int t = blockIdx.x * 256 + threadIdx.x;
    float gl[NG];
    *(float4*)&gl[0] = ((const float4*)(glog_buf + (size_t)t * NG))[0];
    *(float4*)&gl[4] = ((const float4*)(glog_buf + (size_t)t * NG))[1];
    int i1 = 0; float m1 = gl[0];
    #pragma unroll
    for (int g = 1; g < NG; ++g) if (gl[g] > m1) { m1 = gl[g]; i1 = g; }
    int i2 = -1; float m2 = -3.4e38f;
    #pragma unroll
    for (int g = 0; g < NG; ++g) if (g != i1 && gl[g] > m2) { m2 = gl[g]; i2 = g; }
    const float ex = expf(m2 - m1);
    const float inv = 1.0f / (1.0f + ex);
    const int   gsel[2] = {i1, i2};
    const float wsel[2] = {inv, ex * inv};
    #pragma unroll
    for (int s = 0; s < 2; ++s) {
        const int g = gsel[s];
        const float il0 = ilog_buf[(size_t)t * (NG * NES) + g * NES + 0];
        const float il1 = ilog_buf[(size_t)t * (NG * NES) + g * NES + 1];
        const int kk = (il1 > il0) ? 1 : 0;
        const int eid = g * NES + kk;
        const int pos = atomicAdd(&counts[eid], 1);
        list_tok[(size_t)eid * T_TOKENS + pos] = t;
        list_w[(size_t)eid * T_TOKENS + pos] = wsel[s];
    }
}

// ---------------- Kernel 3: sparse experts ----------------
#define ET 16
#define HSTR 520
#define EHSTR 264

__global__ __launch_bounds__(256) void hg_expert_kernel(
    const float* __restrict__ hbuf,
    const float* __restrict__ eW1, const float* __restrict__ eb1,
    const float* __restrict__ eW2, const float* __restrict__ eb2,
    const float* __restrict__ alpha_p,
    const int* __restrict__ counts, const int* __restrict__ list_tok,
    const float* __restrict__ list_w, float* __restrict__ out)
{
    const int e = blockIdx.y;
    const int cnt = counts[e];
    const int base = blockIdx.x * ET;
    if (base >= cnt) return;
    const int n = min(ET, cnt - base);

    __shared__ float s_h[ET][HSTR];
    __shared__ float s_eh[ET][EHSTR];
    __shared__ int   s_tok[ET];
    __shared__ float s_w[ET];

    const int thr = threadIdx.x;
    if (thr < ET) {
        const int i = thr;
        const int src = base + ((i < n) ? i : (n - 1));
        s_tok[i] = list_tok[(size_t)e * T_TOKENS + src];
        s_w[i]   = (i < n) ? list_w[(size_t)e * T_TOKENS + base + i] : 0.0f;
    }
    __syncthreads();

    {
        const int ti = thr >> 4;
        const int cc = thr & 15;
        const float* hrow = hbuf + (size_t)s_tok[ti] * DMODEL;
        #pragma unroll
        for (int j = 0; j < 8; ++j) {
            const int col = cc * 4 + j * 64;
            *(float4*)&s_h[ti][col] = *(const float4*)&hrow[col];
        }
    }
    __syncthreads();

    const int r = thr >> 5;
    const int c = thr & 31;

    {
        float acc0[8] = {0.f,0.f,0.f,0.f,0.f,0.f,0.f,0.f};
        float acc1[8] = {0.f,0.f,0.f,0.f,0.f,0.f,0.f,0.f};
        const float* W = eW1 + (size_t)e * DMODEL * DHID + c * 8;
        #pragma unroll 4
        for (int k = 0; k < DMODEL; ++k) {
            float4 wa = *(const float4*)(W + (size_t)k * DHID);
            float4 wb = *(const float4*)(W + (size_t)k * DHID + 4);
            const float a0 = s_h[2 * r + 0][k];
            const float a1 = s_h[2 * r + 1][k];
            acc0[0] = fmaf(a0, wa.x, acc0[0]); acc0[1] = fmaf(a0, wa.y, acc0[1]);
            acc0[2] = fmaf(a0, wa.z, acc0[2]); acc0[3] = fmaf(a0, wa.w, acc0[3]);
            acc0[4] = fmaf(a0, wb.x, acc0[4]); acc0[5] = fmaf(a0, wb.y, acc0[5]);
            acc0[6] = fmaf(a0, wb.z, acc0[6]); acc0[7] = fmaf(a0, wb.w, acc0[7]);
            acc1[0] = fmaf(a1, wa.x, acc1[0]); acc1[1] = fmaf(a1, wa.y, acc1[1]);
            acc1[2] = fmaf(a1, wa.z, acc1[2]); acc1[3] = fmaf(a1, wa.w, acc1[3]);
            acc1[4] = fmaf(a1, wb.x, acc1[4]); acc1[5] = fmaf(a1, wb.y, acc1[5]);
            acc1[6] = fmaf(a1, wb.z, acc1[6]); acc1[7] = fmaf(a1, wb.w, acc1[7]);
        }
        float4 ba = *(const float4*)&eb1[e * DHID + c * 8];
        float4 bb = *(const float4*)&eb1[e * DHID + c * 8 + 4];
        const float bias[8] = {ba.x, ba.y, ba.z, ba.w, bb.x, bb.y, bb.z, bb.w};
        #pragma unroll
        for (int j = 0; j < 8; ++j) {
            s_eh[2 * r + 0][c * 8 + j] = gelu_f(acc0[j] + bias[j]);
            s_eh[2 * r + 1][c * 8 + j] = gelu_f(acc1[j] + bias[j]);
        }
    }
    __syncthreads();

    const float alpha = alpha_p[0];
    const float w0 = s_w[2 * r + 0] * alpha;
    const float w1 = s_w[2 * r + 1] * alpha;
    for (int p = 0; p < 2; ++p) {
        float acc0[8] = {0.f,0.f,0.f,0.f,0.f,0.f,0.f,0.f};
        float acc1[8] = {0.f,0.f,0.f,0.f,0.f,0.f,0.f,0.f};
        const int col0 = p * 256 + c * 8;
        const float* W = eW2 + (size_t)e * DHID * DMODEL + col0;
        #pragma unroll 4
        for (int k = 0; k < DHID; ++k) {
            float4 wa = *(const float4*)(W + (size_t)k * DMODEL);
            float4 wb = *(const float4*)(W + (size_t)k * DMODEL + 4);
            const float a0 = s_eh[2 * r + 0][k];
            const float a1 = s_eh[2 * r + 1][k];
            acc0[0] = fmaf(a0, wa.x, acc0[0]); acc0[1] = fmaf(a0, wa.y, acc0[1]);
            acc0[2] = fmaf(a0, wa.z, acc0[2]); acc0[3] = fmaf(a0, wa.w, acc0[3]);
            acc0[4] = fmaf(a0, wb.x, acc0[4]); acc0[5] = fmaf(a0, wb.y, acc0[5]);
            acc0[6] = fmaf(a0, wb.z, acc0[6]); acc0[7] = fmaf(a0, wb.w, acc0[7]);
            acc1[0] = fmaf(a1, wa.x, acc1[0]); acc1[1] = fmaf(a1, wa.y, acc1[1]);
            acc1[2] = fmaf(a1, wa.z, acc1[2]); acc1[3] = fmaf(a1, wa.w, acc1[3]);
            acc1[4] = fmaf(a1, wb.x, acc1[4]); acc1[5] = fmaf(a1, wb.y, acc1[5]);
            acc1[6] = fmaf(a1, wb.z, acc1[6]); acc1[7] = fmaf(a1, wb.w, acc1[7]);
        }
        float4 ba = *(const float4*)&eb2[e * DMODEL + col0];
        float4 bb = *(const float4*)&eb2[e * DMODEL + col0 + 4];
        const float bias[8] = {ba.x, ba.y, ba.z, ba.w, bb.x, bb.y, bb.z, bb.w};
        float* o0 = out + (size_t)s_tok[2 * r + 0] * DMODEL + col0;
        float* o1 = out + (size_t)s_tok[2 * r + 1] * DMODEL + col0;
        #pragma unroll
        for (int j = 0; j < 8; ++j) {
            atomicAdd(&o0[j], w0 * (acc0[j] + bias[j]));
            atomicAdd(&o1[j], w1 * (acc1[j] + bias[j]));
        }
    }
}

// ---------------- launch ----------------
extern "C" void kernel_launch(void* const* d_in, const int* in_sizes, int n_in,
                              void* d_out, int out_size, void* d_ws, size_t ws_size,
                              hipStream_t stream) {
    const float* hidden = (const float*)d_in[0];
    const float* feat   = (const float*)d_in[1];
    const float* ln_g   = (const float*)d_in[2];
    const float* ln_b   = (const float*)d_in[3];
    const float* stageW = (const float*)d_in[4];
    const float* stageb = (const float*)d_in[5];
    const float* gfW    = (const float*)d_in[6];
    const float* gfb    = (const float*)d_in[7];
    const float* psW1   = (const float*)d_in[8];
    const float* psb1   = (const float*)d_in[9];
    const float* psW2   = (const float*)d_in[10];
    const float* psb2   = (const float*)d_in[11];
    const float* irW1   = (const float*)d_in[12];
    const float* irb1   = (const float*)d_in[13];
    const float* irW2   = (const float*)d_in[14];
    const float* irb2   = (const float*)d_in[15];
    const float* eW1    = (const float*)d_in[16];
    const float* eb1    = (const float*)d_in[17];
    const float* eW2    = (const float*)d_in[18];
    const float* eb2    = (const float*)d_in[19];
    const float* alpha  = (const float*)d_in[20];

    float* out = (float*)d_out;
    float* hbuf = (float*)d_ws;
    int* counts = (int*)(hbuf + (size_t)T_TOKENS * DMODEL);
    int* list_tok = counts + 32;
    float* list_w = (float*)(list_tok + (size_t)NE * T_TOKENS);
    float* glog_buf = list_w + (size_t)NE * T_TOKENS;
    float* ilog_buf = glog_buf + (size_t)T_TOKENS * NG;

    hipMemsetAsync(counts, 0, 32 * sizeof(int), stream);

    hg_ln_kernel<<<T_TOKENS, 64, 0, stream>>>(hidden, ln_g, ln_b, hbuf, out);

    dim3 rg(T_TOKENS / BM, NG);
    hg_router_big<<<rg, 256, 0, stream>>>(
        hbuf, feat, stageW, stageb, gfW, gfb, psW1, psb1, psW2, psb2,
        irW1, irb1, irW2, irb2, glog_buf, ilog_buf);

    hg_finalize<<<T_TOKENS / 256, 256, 0, stream>>>(
        glog_buf, ilog_buf, counts, list_tok, list_w);

    dim3 eg(T_TOKENS / ET, NE);
    hg_expert_kernel<<<eg, 256, 0, stream>>>(
        hbuf, eW1, eb1, eW2, eb2, alpha, counts, list_tok, list_w, out);
}

// Round 3
// 1018.166 us; speedup vs baseline: 2.1736x; 1.9599x over previous
//
#include <hip/hip_runtime.h>
#include <hip/hip_bf16.h>

#define T_TOKENS 16384
#define DMODEL 512
#define FFEAT 64
#define DFEMB 64
#define RIN 576
#define DRH 128
#define NG 8
#define NES 2
#define NE 16
#define DHID 256

typedef float f32x4 __attribute__((ext_vector_type(4)));
typedef short bf16x8 __attribute__((ext_vector_type(8)));

#define MFMA16(a, b, c) __builtin_amdgcn_mfma_f32_16x16x32_bf16((a), (b), (c), 0, 0, 0)

__device__ __forceinline__ float gelu_f(float x) {
    return 0.5f * x * (1.0f + erff(x * 0.7071067811865476f));
}
__device__ __forceinline__ unsigned short f2bf_rne(float x) {
    union { float f; unsigned u; } v; v.f = x;
    unsigned r = v.u + 0x7fffu + ((v.u >> 16) & 1u);
    return (unsigned short)(r >> 16);
}
__device__ __forceinline__ float bf2f(unsigned short h) {
    union { unsigned u; float f; } v; v.u = ((unsigned)h) << 16;
    return v.f;
}

// ---------------- Kernel 1: LayerNorm + out = hidden ----------------
__global__ __launch_bounds__(64) void k_ln(
    const float* __restrict__ hidden, const float* __restrict__ lng,
    const float* __restrict__ lnb, float* __restrict__ hbuf,
    float* __restrict__ out)
{
    const int t = blockIdx.x;
    const int lane = threadIdx.x;
    const float* row = hidden + (size_t)t * DMODEL;
    float4 v0 = ((const float4*)row)[lane * 2 + 0];
    float4 v1 = ((const float4*)row)[lane * 2 + 1];
    float s = v0.x + v0.y + v0.z + v0.w + v1.x + v1.y + v1.z + v1.w;
    #pragma unroll
    for (int m = 1; m < 64; m <<= 1) s += __shfl_xor(s, m);
    const float mu = s * (1.0f / DMODEL);
    float sq = 0.f;
    {
        float d;
        d = v0.x - mu; sq += d * d;  d = v0.y - mu; sq += d * d;
        d = v0.z - mu; sq += d * d;  d = v0.w - mu; sq += d * d;
        d = v1.x - mu; sq += d * d;  d = v1.y - mu; sq += d * d;
        d = v1.z - mu; sq += d * d;  d = v1.w - mu; sq += d * d;
    }
    #pragma unroll
    for (int m = 1; m < 64; m <<= 1) sq += __shfl_xor(sq, m);
    const float rstd = rsqrtf(sq * (1.0f / DMODEL) + 1e-5f);
    float4 g0 = ((const float4*)lng)[lane * 2 + 0];
    float4 g1 = ((const float4*)lng)[lane * 2 + 1];
    float4 b0 = ((const float4*)lnb)[lane * 2 + 0];
    float4 b1 = ((const float4*)lnb)[lane * 2 + 1];
    float4 h0, h1;
    h0.x = (v0.x - mu) * rstd * g0.x + b0.x;
    h0.y = (v0.y - mu) * rstd * g0.y + b0.y;
    h0.z = (v0.z - mu) * rstd * g0.z + b0.z;
    h0.w = (v0.w - mu) * rstd * g0.w + b0.w;
    h1.x = (v1.x - mu) * rstd * g1.x + b1.x;
    h1.y = (v1.y - mu) * rstd * g1.y + b1.y;
    h1.z = (v1.z - mu) * rstd * g1.z + b1.z;
    h1.w = (v1.w - mu) * rstd * g1.w + b1.w;
    float* hrow = hbuf + (size_t)t * DMODEL;
    ((float4*)hrow)[lane * 2 + 0] = h0;
    ((float4*)hrow)[lane * 2 + 1] = h1;
    float* orow = out + (size_t)t * DMODEL;
    ((float4*)orow)[lane * 2 + 0] = v0;
    ((float4*)orow)[lane * 2 + 1] = v1;
}

// ---------------- transpose + bf16 hi/lo split: in[K][N] -> out[N][K] ----------------
__global__ __launch_bounds__(256) void k_wsplitT(
    const float* __restrict__ in, unsigned short* __restrict__ outHi,
    unsigned short* __restrict__ outLo, int K, int N,
    long inBS, long outBS)
{
    __shared__ float s_t[32][33];
    const int b = blockIdx.y;
    const int tilesN = N >> 5;
    const int ko = (blockIdx.x / tilesN) << 5;
    const int no = (blockIdx.x % tilesN) << 5;
    const int tid = threadIdx.x;
    const int r = tid >> 3;
    const int c0 = (tid & 7) * 4;
    {
        const float* p = in + (size_t)b * inBS + (size_t)(ko + r) * N + no + c0;
        float4 v = *(const float4*)p;
        s_t[r][c0] = v.x; s_t[r][c0 + 1] = v.y; s_t[r][c0 + 2] = v.z; s_t[r][c0 + 3] = v.w;
    }
    __syncthreads();
    {
        float vv[4];
        #pragma unroll
        for (int j = 0; j < 4; ++j) vv[j] = s_t[c0 + j][r];
        ushort4 hi, lo;
        hi.x = f2bf_rne(vv[0]); lo.x = f2bf_rne(vv[0] - bf2f(hi.x));
        hi.y = f2bf_rne(vv[1]); lo.y = f2bf_rne(vv[1] - bf2f(hi.y));
        hi.z = f2bf_rne(vv[2]); lo.z = f2bf_rne(vv[2] - bf2f(hi.z));
        hi.w = f2bf_rne(vv[3]); lo.w = f2bf_rne(vv[3] - bf2f(hi.w));
        const size_t off = (size_t)b * outBS + (size_t)(no + r) * K + ko + c0;
        *(ushort4*)(outHi + off) = hi;
        if (outLo) *(ushort4*)(outLo + off) = lo;
    }
}

// ---------------- Kernel 2: router via split-bf16 MFMA ----------------
// grid (T/32, 8 groups), 256 thr = 4 waves. waves 0,1 -> ps cols 0-63/64-127;
// waves 2,3 -> ir. K = 512 (h, split on the fly) + 64 tail (se / gemb).
__global__ __launch_bounds__(256) void hg_router_mfma(
    const float* __restrict__ hbuf, const float* __restrict__ feat,
    const float* __restrict__ stageW, const float* __restrict__ stageb,
    const float* __restrict__ gfW, const float* __restrict__ gfb,
    const unsigned short* __restrict__ W1T_hi, const unsigned short* __restrict__ W1T_lo,
    const float* __restrict__ psb1, const float* __restrict__ psW2, const float* __restrict__ psb2,
    const float* __restrict__ irb1, const float* __restrict__ irW2, const float* __restrict__ irb2,
    float* __restrict__ glog_buf, float* __restrict__ ilog_buf)
{
    __shared__ __align__(16) unsigned short s_ahi[2][32][32];
    __shared__ __align__(16) unsigned short s_alo[2][32][32];
    __shared__ __align__(16) unsigned short s_thi[2][2][32][32];
    __shared__ __align__(16) unsigned short s_tlo[2][2][32][32];
    __shared__ float s_feat[32][FFEAT];
    __shared__ float s_redP[2][32];
    __shared__ float s_redI[2][32][2];

    const int tid = threadIdx.x;
    const int lane = tid & 63;
    const int wid = tid >> 6;
    const int t0 = blockIdx.x * 32;
    const int g = blockIdx.y;
    const int sel = wid >> 1;        // 0 = ps, 1 = ir
    const int colhalf = wid & 1;     // which 64-col half

    // ---- prologue: feat tile + first h k-tile ----
    {
        const int row = tid >> 3;
        const int c0 = (tid & 7) * 8;
        const float* fp = feat + (size_t)(t0 + row) * FFEAT + c0;
        float4 a = ((const float4*)fp)[0];
        float4 b = ((const float4*)fp)[1];
        *(float4*)&s_feat[row][c0] = a;
        *(float4*)&s_feat[row][c0 + 4] = b;
    }
    {
        const int row = tid >> 3;
        const int c0 = (tid & 7) * 4;
        float4 v = *(const float4*)(hbuf + (size_t)(t0 + row) * DMODEL + c0);
        ushort4 hi, lo;
        hi.x = f2bf_rne(v.x); lo.x = f2bf_rne(v.x - bf2f(hi.x));
        hi.y = f2bf_rne(v.y); lo.y = f2bf_rne(v.y - bf2f(hi.y));
        hi.z = f2bf_rne(v.z); lo.z = f2bf_rne(v.z - bf2f(hi.z));
        hi.w = f2bf_rne(v.w); lo.w = f2bf_rne(v.w - bf2f(hi.w));
        *(ushort4*)&s_ahi[0][row][c0] = hi;
        *(ushort4*)&s_alo[0][row][c0] = lo;
    }
    __syncthreads();

    // ---- tails: se (ps) and gemb (ir), split hi/lo into s_thi/s_tlo ----
    {
        const int row = tid >> 3;
        const int j0 = (tid & 7) * 8;
        float acc[8];
        #pragma unroll
        for (int j = 0; j < 8; ++j) acc[j] = stageb[j0 + j];
        #pragma unroll 4
        for (int f = 0; f < FFEAT; ++f) {
            const float a = s_feat[row][f];
            const float4 w0 = *(const float4*)&stageW[f * DFEMB + j0];
            const float4 w1 = *(const float4*)&stageW[f * DFEMB + j0 + 4];
            acc[0] = fmaf(a, w0.x, acc[0]); acc[1] = fmaf(a, w0.y, acc[1]);
            acc[2] = fmaf(a, w0.z, acc[2]); acc[3] = fmaf(a, w0.w, acc[3]);
            acc[4] = fmaf(a, w1.x, acc[4]); acc[5] = fmaf(a, w1.y, acc[5]);
            acc[6] = fmaf(a, w1.z, acc[6]); acc[7] = fmaf(a, w1.w, acc[7]);
        }
        const int ks = j0 >> 5, kk = j0 & 31;
        ushort4 h0, l0, h1, l1;
        h0.x = f2bf_rne(acc[0]); l0.x = f2bf_rne(acc[0] - bf2f(h0.x));
        h0.y = f2bf_rne(acc[1]); l0.y = f2bf_rne(acc[1] - bf2f(h0.y));
        h0.z = f2bf_rne(acc[2]); l0.z = f2bf_rne(acc[2] - bf2f(h0.z));
        h0.w = f2bf_rne(acc[3]); l0.w = f2bf_rne(acc[3] - bf2f(h0.w));
        h1.x = f2bf_rne(acc[4]); l1.x = f2bf_rne(acc[4] - bf2f(h1.x));
        h1.y = f2bf_rne(acc[5]); l1.y = f2bf_rne(acc[5] - bf2f(h1.y));
        h1.z = f2bf_rne(acc[6]); l1.z = f2bf_rne(acc[6] - bf2f(h1.z));
        h1.w = f2bf_rne(acc[7]); l1.w = f2bf_rne(acc[7] - bf2f(h1.w));
        *(ushort4*)&s_thi[0][ks][row][kk] = h0;  *(ushort4*)&s_thi[0][ks][row][kk + 4] = h1;
        *(ushort4*)&s_tlo[0][ks][row][kk] = l0;  *(ushort4*)&s_tlo[0][ks][row][kk + 4] = l1;
    }
    {
        const int row = tid >> 3;
        const int j0 = (tid & 7) * 8;
        float acc[8];
        #pragma unroll
        for (int j = 0; j < 8; ++j) acc[j] = gfb[g * DFEMB + j0 + j];
        #pragma unroll
        for (int f = 0; f < 8; ++f) {
            const float a = s_feat[row][g * 8 + f];
            const float4 w0 = *(const float4*)&gfW[(size_t)(g * 8 + f) * DFEMB + j0];
            const float4 w1 = *(const float4*)&gfW[(size_t)(g * 8 + f) * DFEMB + j0 + 4];
            acc[0] = fmaf(a, w0.x, acc[0]); acc[1] = fmaf(a, w0.y, acc[1]);
            acc[2] = fmaf(a, w0.z, acc[2]); acc[3] = fmaf(a, w0.w, acc[3]);
            acc[4] = fmaf(a, w1.x, acc[4]); acc[5] = fmaf(a, w1.y, acc[5]);
            acc[6] = fmaf(a, w1.z, acc[6]); acc[7] = fmaf(a, w1.w, acc[7]);
        }
        const int ks = j0 >> 5, kk = j0 & 31;
        ushort4 h0, l0, h1, l1;
        h0.x = f2bf_rne(acc[0]); l0.x = f2bf_rne(acc[0] - bf2f(h0.x));
        h0.y = f2bf_rne(acc[1]); l0.y = f2bf_rne(acc[1] - bf2f(h0.y));
        h0.z = f2bf_rne(acc[2]); l0.z = f2bf_rne(acc[2] - bf2f(h0.z));
        h0.w = f2bf_rne(acc[3]); l0.w = f2bf_rne(acc[3] - bf2f(h0.w));
        h1.x = f2bf_rne(acc[4]); l1.x = f2bf_rne(acc[4] - bf2f(h1.x));
        h1.y = f2bf_rne(acc[5]); l1.y = f2bf_rne(acc[5] - bf2f(h1.y));
        h1.z = f2bf_rne(acc[6]); l1.z = f2bf_rne(acc[6] - bf2f(h1.z));
        h1.w = f2bf_rne(acc[7]); l1.w = f2bf_rne(acc[7] - bf2f(h1.w));
        *(ushort4*)&s_thi[1][ks][row][kk] = h0;  *(ushort4*)&s_thi[1][ks][row][kk + 4] = h1;
        *(ushort4*)&s_tlo[1][ks][row][kk] = l0;  *(ushort4*)&s_tlo[1][ks][row][kk + 4] = l1;
    }
    __syncthreads();

    // ---- main MFMA loop: K = 18 steps of 32 (16 h + 2 tail) ----
    f32x4 acc[2][4];
    #pragma unroll
    for (int m = 0; m < 2; ++m)
        #pragma unroll
        for (int n = 0; n < 4; ++n) { acc[m][n].x = 0.f; acc[m][n].y = 0.f; acc[m][n].z = 0.f; acc[m][n].w = 0.f; }

    const size_t wbase = ((size_t)(g * 2 + sel) * DRH + colhalf * 64) * RIN;
    const int arow = lane & 15;
    const int koff = (lane >> 4) * 8;

    for (int kt = 0; kt < 18; ++kt) {
        if (kt + 1 < 16) {
            const int row = tid >> 3;
            const int c0 = (tid & 7) * 4;
            float4 v = *(const float4*)(hbuf + (size_t)(t0 + row) * DMODEL + (kt + 1) * 32 + c0);
            ushort4 hi, lo;
            hi.x = f2bf_rne(v.x); lo.x = f2bf_rne(v.x - bf2f(hi.x));
            hi.y = f2bf_rne(v.y); lo.y = f2bf_rne(v.y - bf2f(hi.y));
            hi.z = f2bf_rne(v.z); lo.z = f2bf_rne(v.z - bf2f(hi.z));
            hi.w = f2bf_rne(v.w); lo.w = f2bf_rne(v.w - bf2f(hi.w));
            *(ushort4*)&s_ahi[(kt + 1) & 1][row][c0] = hi;
            *(ushort4*)&s_alo[(kt + 1) & 1][row][c0] = lo;
        }
        const unsigned short (*Ahi)[32] = (kt < 16) ? s_ahi[kt & 1] : s_thi[sel][kt - 16];
        const unsigned short (*Alo)[32] = (kt < 16) ? s_alo[kt & 1] : s_tlo[sel][kt - 16];

        bf16x8 ah0 = *(const bf16x8*)&Ahi[arow][koff];
        bf16x8 ah1 = *(const bf16x8*)&Ahi[arow + 16][koff];
        bf16x8 al0 = *(const bf16x8*)&Alo[arow][koff];
        bf16x8 al1 = *(const bf16x8*)&Alo[arow + 16][koff];

        const int kg = kt * 32 + koff;
        #pragma unroll
        for (int n = 0; n < 4; ++n) {
            const size_t woff = wbase + (size_t)(n * 16 + arow) * RIN + kg;
            bf16x8 bh = *(const bf16x8*)(W1T_hi + woff);
            bf16x8 bl = *(const bf16x8*)(W1T_lo + woff);
            acc[0][n] = MFMA16(ah0, bh, acc[0][n]);
            acc[0][n] = MFMA16(ah0, bl, acc[0][n]);
            acc[0][n] = MFMA16(al0, bh, acc[0][n]);
            acc[1][n] = MFMA16(ah1, bh, acc[1][n]);
            acc[1][n] = MFMA16(ah1, bl, acc[1][n]);
            acc[1][n] = MFMA16(al1, bh, acc[1][n]);
        }
        __syncthreads();
    }

    // ---- fused second layers ----
    const int colb = colhalf * 64;
    if (sel == 0) {
        float part[2][4] = {{0.f,0.f,0.f,0.f},{0.f,0.f,0.f,0.f}};
        #pragma unroll
        for (int n = 0; n < 4; ++n) {
            const int col = g * DRH + colb + n * 16 + arow;
            const float b1 = psb1[col];
            const float w2 = psW2[col];
            #pragma unroll
            for (int m = 0; m < 2; ++m)
                #pragma unroll
                for (int j = 0; j < 4; ++j)
                    part[m][j] += gelu_f(acc[m][n][j] + b1) * w2;
        }
        #pragma unroll
        for (int mk = 1; mk < 16; mk <<= 1)
            #pragma unroll
            for (int m = 0; m < 2; ++m)
                #pragma unroll
                for (int j = 0; j < 4; ++j)
                    part[m][j] += __shfl_xor(part[m][j], mk);
        if ((lane & 15) == 0) {
            const int q = lane >> 4;
            #pragma unroll
            for (int m = 0; m < 2; ++m)
                #pragma unroll
                for (int j = 0; j < 4; ++j)
                    s_redP[wid][m * 16 + q * 4 + j] = part[m][j];
        }
    } else {
        float p0[2][4] = {{0.f,0.f,0.f,0.f},{0.f,0.f,0.f,0.f}};
        float p1[2][4] = {{0.f,0.f,0.f,0.f},{0.f,0.f,0.f,0.f}};
        #pragma unroll
        for (int n = 0; n < 4; ++n) {
            const int col = g * DRH + colb + n * 16 + arow;
            const float b1 = irb1[col];
            const float w20 = irW2[(size_t)col * NES + 0];
            const float w21 = irW2[(size_t)col * NES + 1];
            #pragma unroll
            for (int m = 0; m < 2; ++m)
                #pragma unroll
                for (int j = 0; j < 4; ++j) {
                    const float v = gelu_f(acc[m][n][j] + b1);
                    p0[m][j] = fmaf(v, w20, p0[m][j]);
                    p1[m][j] = fmaf(v, w21, p1[m][j]);
                }
        }
        #pragma unroll
        for (int mk = 1; mk < 16; mk <<= 1)
            #pragma unroll
            for (int m = 0; m < 2; ++m)
                #pragma unroll
                for (int j = 0; j < 4; ++j) {
                    p0[m][j] += __shfl_xor(p0[m][j], mk);
                    p1[m][j] += __shfl_xor(p1[m][j], mk);
                }
        if ((lane & 15) == 0) {
            const int q = lane >> 4;
            #pragma unroll
            for (int m = 0; m < 2; ++m)
                #pragma unroll
                for (int j = 0; j < 4; ++j) {
                    s_redI[wid - 2][m * 16 + q * 4 + j][0] = p0[m][j];
                    s_redI[wid - 2][m * 16 + q * 4 + j][1] = p1[m][j];
                }
        }
    }
    __syncthreads();
    if (tid < 32) {
        glog_buf[(size_t)(t0 + tid) * NG + g] = s_redP[0][tid] + s_redP[1][tid] + psb2[g];
    } else if (tid < 64) {
        const int row = tid - 32;
        const size_t ib = ((size_t)(t0 + row) * NG + g) * NES;
        ilog_buf[ib + 0] = s_redI[0][row][0] + s_redI[1][row][0] + irb2[g * NES + 0];
        ilog_buf[ib + 1] = s_redI[0][row][1] + s_redI[1][row][1] + irb2[g * NES + 1];
    }
}

// ---------------- Kernel 2b: finalize with margin check ----------------
#define MARGIN 2e-3f
__global__ __launch_bounds__(256) void hg_finalize2(
    const float* __restrict__ glog_buf, const float* __restrict__ ilog_buf,
    int* __restrict__ counts, int* __restrict__ nfix, int* __restrict__ fix_list,
    int* __restrict__ list_tok, float* __restrict__ list_w)
{
    const int t = blockIdx.x * 256 + threadIdx.x;
    float gl[NG];
    *(float4*)&gl[0] = ((const float4*)(glog_buf + (size_t)t * NG))[0];
    *(float4*)&gl[4] = ((const float4*)(glog_buf + (size_t)t * NG))[1];
    int i1 = 0; float m1 = gl[0];
    #pragma unroll
    for (int g = 1; g < NG; ++g) if (gl[g] > m1) { m1 = gl[g]; i1 = g; }
    int i2 = -1; float m2 = -3.4e38f;
    #pragma unroll
    for (int g = 0; g < NG; ++g) if (g != i1 && gl[g] > m2) { m2 = gl[g]; i2 = g; }
    float m3 = -3.4e38f;
    #pragma unroll
    for (int g = 0; g < NG; ++g) if (g != i1 && g != i2 && gl[g] > m3) m3 = gl[g];

    const float ila0 = ilog_buf[((size_t)t * NG + i1) * NES + 0];
    const float ila1 = ilog_buf[((size_t)t * NG + i1) * NES + 1];
    const float ilb0 = ilog_buf[((size_t)t * NG + i2) * NES + 0];
    const float ilb1 = ilog_buf[((size_t)t * NG + i2) * NES + 1];

    const bool flag = ((m2 - m3) < MARGIN) || (fabsf(ila1 - ila0) < MARGIN)
                   || (fabsf(ilb1 - ilb0) < MARGIN);
    if (flag) {
        const int p = atomicAdd(nfix, 1);
        fix_list[p] = t;
        return;
    }
    const float ex = expf(m2 - m1);
    const float inv = 1.0f / (1.0f + ex);
    const int   gsel[2] = {i1, i2};
    const float wsel[2] = {inv, ex * inv};
    const int   ksel[2] = {(ila1 > ila0) ? 1 : 0, (ilb1 > ilb0) ? 1 : 0};
    #pragma unroll
    for (int s = 0; s < 2; ++s) {
        const int eid = gsel[s] * NES + ksel[s];
        const int pos = atomicAdd(&counts[eid], 1);
        list_tok[(size_t)eid * T_TOKENS + pos] = t;
        list_w[(size_t)eid * T_TOKENS + pos] = wsel[s];
    }
}

// ---------------- Kernel 2c: exact fp32 fixup for near-tie tokens ----------------
__global__ __launch_bounds__(64) void hg_fixup(
    const float* __restrict__ hidden, const float* __restrict__ feat,
    const float* __restrict__ lng, const float* __restrict__ lnb,
    const float* __restrict__ stageW, const float* __restrict__ stageb,
    const float* __restrict__ gfW, const float* __restrict__ gfb,
    const float* __restrict__ psW1, const float* __restrict__ psb1,
    const float* __restrict__ psW2, const float* __restrict__ psb2,
    const float* __restrict__ irW1, const float* __restrict__ irb1,
    const float* __restrict__ irW2, const float* __restrict__ irb2,
    const int* __restrict__ nfix, const int* __restrict__ fix_list,
    int* __restrict__ counts, int* __restrict__ list_tok, float* __restrict__ list_w)
{
    __shared__ float s_rin[RIN];
    const int lane = threadIdx.x;
    const int nf = nfix[0];
    for (int idx = blockIdx.x; idx < nf; idx += gridDim.x) {
        const int t = fix_list[idx];
        // exact LayerNorm
        const float* row = hidden + (size_t)t * DMODEL;
        float4 v0 = ((const float4*)row)[lane * 2 + 0];
        float4 v1 = ((const float4*)row)[lane * 2 + 1];
        float s = v0.x + v0.y + v0.z + v0.w + v1.x + v1.y + v1.z + v1.w;
        #pragma unroll
        for (int m = 1; m < 64; m <<= 1) s += __shfl_xor(s, m);
        const float mu = s * (1.0f / DMODEL);
        float sq = 0.f;
        { float d;
          d = v0.x - mu; sq += d * d; d = v0.y - mu; sq += d * d;
          d = v0.z - mu; sq += d * d; d = v0.w - mu; sq += d * d;
          d = v1.x - mu; sq += d * d; d = v1.y - mu; sq += d * d;
          d = v1.z - mu; sq += d * d; d = v1.w - mu; sq += d * d; }
        #pragma unroll
        for (int m = 1; m < 64; m <<= 1) sq += __shfl_xor(sq, m);
        const float rstd = rsqrtf(sq * (1.0f / DMODEL) + 1e-5f);
        {
            float4 g0 = ((const float4*)lng)[lane * 2 + 0];
            float4 g1 = ((const float4*)lng)[lane * 2 + 1];
            float4 b0 = ((const float4*)lnb)[lane * 2 + 0];
            float4 b1 = ((const float4*)lnb)[lane * 2 + 1];
            s_rin[lane * 8 + 0] = (v0.x - mu) * rstd * g0.x + b0.x;
            s_rin[lane * 8 + 1] = (v0.y - mu) * rstd * g0.y + b0.y;
            s_rin[lane * 8 + 2] = (v0.z - mu) * rstd * g0.z + b0.z;
            s_rin[lane * 8 + 3] = (v0.w - mu) * rstd * g0.w + b0.w;
            s_rin[lane * 8 + 4] = (v1.x - mu) * rstd * g1.x + b1.x;
            s_rin[lane * 8 + 5] = (v1.y - mu) * rstd * g1.y + b1.y;
            s_rin[lane * 8 + 6] = (v1.z - mu) * rstd * g1.z + b1.z;
            s_rin[lane * 8 + 7] = (v1.w - mu) * rstd * g1.w + b1.w;
        }
        // stage_emb col = lane
        {
            float se = stageb[lane];
            for (int f = 0; f < FFEAT; ++f)
                se = fmaf(feat[(size_t)t * FFEAT + f], stageW[f * DFEMB + lane], se);
            s_rin[DMODEL + lane] = se;
        }
        __syncthreads();
        // exact glog
        float gl[NG];
        for (int g = 0; g < NG; ++g) {
            float a0 = psb1[g * DRH + lane];
            float a1 = psb1[g * DRH + 64 + lane];
            const float* W = psW1 + (size_t)g * RIN * DRH;
            for (int k = 0; k < RIN; ++k) {
                const float r = s_rin[k];
                a0 = fmaf(r, W[(size_t)k * DRH + lane], a0);
                a1 = fmaf(r, W[(size_t)k * DRH + 64 + lane], a1);
            }
            float p = gelu_f(a0) * psW2[g * DRH + lane] + gelu_f(a1) * psW2[g * DRH + 64 + lane];
            #pragma unroll
            for (int m = 1; m < 64; m <<= 1) p += __shfl_xor(p, m);
            gl[g] = p + psb2[g];
        }
        int i1 = 0; float m1 = gl[0];
        #pragma unroll
        for (int g = 1; g < NG; ++g) if (gl[g] > m1) { m1 = gl[g]; i1 = g; }
        int i2 = -1; float m2 = -3.4e38f;
        #pragma unroll
        for (int g = 0; g < NG; ++g) if (g != i1 && gl[g] > m2) { m2 = gl[g]; i2 = g; }
        const float ex = expf(m2 - m1);
        const float inv = 1.0f / (1.0f + ex);
        const int   gsel[2] = {i1, i2};
        const float wsel[2] = {inv, ex * inv};
        for (int sidx = 0; sidx < 2; ++sidx) {
            const int g = gsel[sidx];
            float ge = gfb[g * DFEMB + lane];
            #pragma unroll
            for (int f = 0; f < 8; ++f)
                ge = fmaf(feat[(size_t)t * FFEAT + g * 8 + f],
                          gfW[(size_t)(g * 8 + f) * DFEMB + lane], ge);
            __syncthreads();
            s_rin[DMODEL + lane] = ge;
            __syncthreads();
            float a0 = irb1[g * DRH + lane];
            float a1 = irb1[g * DRH + 64 + lane];
            const float* W = irW1 + (size_t)g * RIN * DRH;
            for (int k = 0; k < RIN; ++k) {
                const float r = s_rin[k];
                a0 = fmaf(r, W[(size_t)k * DRH + lane], a0);
                a1 = fmaf(r, W[(size_t)k * DRH + 64 + lane], a1);
            }
            const float ga0 = gelu_f(a0), ga1 = gelu_f(a1);
            float e0 = ga0 * irW2[(size_t)(g * DRH + lane) * NES + 0]
                     + ga1 * irW2[(size_t)(g * DRH + 64 + lane) * NES + 0];
            float e1 = ga0 * irW2[(size_t)(g * DRH + lane) * NES + 1]
                     + ga1 * irW2[(size_t)(g * DRH + 64 + lane) * NES + 1];
            #pragma unroll
            for (int m = 1; m < 64; m <<= 1) {
                e0 += __shfl_xor(e0, m);
                e1 += __shfl_xor(e1, m);
            }
            if (lane == 0) {
                const int eid = g * NES + ((e1 > e0) ? 1 : 0);
                const int pos = atomicAdd(&counts[eid], 1);
                list_tok[(size_t)eid * T_TOKENS + pos] = t;
                list_w[(size_t)eid * T_TOKENS + pos] = wsel[sidx];
            }
        }
        __syncthreads();
    }
}

// ---------------- Kernel 3: experts via bf16 MFMA ----------------
__global__ __launch_bounds__(256) void hg_expert_mfma(
    const float* __restrict__ hbuf,
    const unsigned short* __restrict__ eW1T, const float* __restrict__ eb1,
    const unsigned short* __restrict__ eW2T, const float* __restrict__ eb2,
    const float* __restrict__ alpha_p,
    const int* __restrict__ counts, const int* __restrict__ list_tok,
    const float* __restrict__ list_w, float* __restrict__ out)
{
    const int e = blockIdx.y;
    const int cnt = counts[e];
    const int base = blockIdx.x * 32;
    if (base >= cnt) return;
    const int n = min(32, cnt - base);

    __shared__ __align__(16) unsigned short s_a[2][32][32];
    __shared__ __align__(16) unsigned short s_eh[32][264];
    __shared__ int s_tok[32];
    __shared__ float s_w[32];

    const int tid = threadIdx.x;
    const int lane = tid & 63;
    const int wid = tid >> 6;

    if (tid < 32) {
        const int src = base + ((tid < n) ? tid : (n - 1));
        s_tok[tid] = list_tok[(size_t)e * T_TOKENS + src];
        s_w[tid] = (tid < n) ? list_w[(size_t)e * T_TOKENS + base + tid] : 0.f;
    }
    __syncthreads();

    {   // stage k-tile 0
        const int row = tid >> 3;
        const int c0 = (tid & 7) * 4;
        float4 v = *(const float4*)(hbuf + (size_t)s_tok[row] * DMODEL + c0);
        ushort4 hv;
        hv.x = f2bf_rne(v.x); hv.y = f2bf_rne(v.y); hv.z = f2bf_rne(v.z); hv.w = f2bf_rne(v.w);
        *(ushort4*)&s_a[0][row][c0] = hv;
    }
    __syncthreads();

    const int arow = lane & 15;
    const int koff = (lane >> 4) * 8;

    // GEMM1: eh = gelu(h @ eW1 + b1), K=512, N=256 (wave: 64 cols)
    f32x4 acc1[2][4];
    #pragma unroll
    for (int m = 0; m < 2; ++m)
        #pragma unroll
        for (int nn = 0; nn < 4; ++nn) { acc1[m][nn].x = 0.f; acc1[m][nn].y = 0.f; acc1[m][nn].z = 0.f; acc1[m][nn].w = 0.f; }

    for (int kt = 0; kt < 16; ++kt) {
        if (kt + 1 < 16) {
            const int row = tid >> 3;
            const int c0 = (tid & 7) * 4;
            float4 v = *(const float4*)(hbuf + (size_t)s_tok[row] * DMODEL + (kt + 1) * 32 + c0);
            ushort4 hv;
            hv.x = f2bf_rne(v.x); hv.y = f2bf_rne(v.y); hv.z = f2bf_rne(v.z); hv.w = f2bf_rne(v.w);
            *(ushort4*)&s_a[(kt + 1) & 1][row][c0] = hv;
        }
        bf16x8 a0 = *(const bf16x8*)&s_a[kt & 1][arow][koff];
        bf16x8 a1 = *(const bf16x8*)&s_a[kt & 1][arow + 16][koff];
        const int kg = kt * 32 + koff;
        #pragma unroll
        for (int nn = 0; nn < 4; ++nn) {
            const int col = wid * 64 + nn * 16 + arow;
            bf16x8 b = *(const bf16x8*)(eW1T + ((size_t)e * DHID + col) * DMODEL + kg);
            acc1[0][nn] = MFMA16(a0, b, acc1[0][nn]);
            acc1[1][nn] = MFMA16(a1, b, acc1[1][nn]);
        }
        __syncthreads();
    }

    #pragma unroll
    for (int m = 0; m < 2; ++m)
        #pragma unroll
        for (int nn = 0; nn < 4; ++nn) {
            const int col = wid * 64 + nn * 16 + arow;
            const float b1 = eb1[e * DHID + col];
            #pragma unroll
            for (int j = 0; j < 4; ++j) {
                const int r = m * 16 + (lane >> 4) * 4 + j;
                s_eh[r][col] = f2bf_rne(gelu_f(acc1[m][nn][j] + b1));
            }
        }
    __syncthreads();

    // GEMM2: K=256, N=512 (wave: 128 cols)
    f32x4 acc2[2][8];
    #pragma unroll
    for (int m = 0; m < 2; ++m)
        #pragma unroll
        for (int nn = 0; nn < 8; ++nn) { acc2[m][nn].x = 0.f; acc2[m][nn].y = 0.f; acc2[m][nn].z = 0.f; acc2[m][nn].w = 0.f; }

    for (int kt = 0; kt < 8; ++kt) {
        bf16x8 a0 = *(const bf16x8*)&s_eh[arow][kt * 32 + koff];
        bf16x8 a1 = *(const bf16x8*)&s_eh[arow + 16][kt * 32 + koff];
        const int kg = kt * 32 + koff;
        #pragma unroll
        for (int nn = 0; nn < 8; ++nn) {
            const int col = wid * 128 + nn * 16 + arow;
            bf16x8 b = *(const bf16x8*)(eW2T + ((size_t)e * DMODEL + col) * DHID + kg);
            acc2[0][nn] = MFMA16(a0, b, acc2[0][nn]);
            acc2[1][nn] = MFMA16(a1, b, acc2[1][nn]);
        }
    }

    const float alpha = alpha_p[0];
    #pragma unroll
    for (int m = 0; m < 2; ++m)
        #pragma unroll
        for (int nn = 0; nn < 8; ++nn) {
            const int col = wid * 128 + nn * 16 + arow;
            const float b2 = eb2[e * DMODEL + col];
            #pragma unroll
            for (int j = 0; j < 4; ++j) {
                const int r = m * 16 + (lane >> 4) * 4 + j;
                if (r < n) {
                    const float wv = s_w[r] * alpha;
                    atomicAdd(out + (size_t)s_tok[r] * DMODEL + col, wv * (acc2[m][nn][j] + b2));
                }
            }
        }
}

// ---------------- launch ----------------
extern "C" void kernel_launch(void* const* d_in, const int* in_sizes, int n_in,
                              void* d_out, int out_size, void* d_ws, size_t ws_size,
                              hipStream_t stream) {
    const float* hidden = (const float*)d_in[0];
    const float* feat   = (const float*)d_in[1];
    const float* ln_g   = (const float*)d_in[2];
    const float* ln_b   = (const float*)d_in[3];
    const float* stageW = (const float*)d_in[4];
    const float* stageb = (const float*)d_in[5];
    const float* gfW    = (const float*)d_in[6];
    const float* gfb    = (const float*)d_in[7];
    const float* psW1   = (const float*)d_in[8];
    const float* psb1   = (const float*)d_in[9];
    const float* psW2   = (const float*)d_in[10];
    const float* psb2   = (const float*)d_in[11];
    const float* irW1   = (const float*)d_in[12];
    const float* irb1   = (const float*)d_in[13];
    const float* irW2   = (const float*)d_in[14];
    const float* irb2   = (const float*)d_in[15];
    const float* eW1    = (const float*)d_in[16];
    const float* eb1    = (const float*)d_in[17];
    const float* eW2    = (const float*)d_in[18];
    const float* eb2    = (const float*)d_in[19];
    const float* alpha  = (const float*)d_in[20];

    float* out = (float*)d_out;

    char* p = (char*)d_ws;
    float* hbuf = (float*)p;                 p += (size_t)T_TOKENS * DMODEL * 4;     // 33.5 MB
    unsigned short* W1T_hi = (unsigned short*)p; p += (size_t)NG * 2 * DRH * RIN * 2; // 2.36 MB
    unsigned short* W1T_lo = (unsigned short*)p; p += (size_t)NG * 2 * DRH * RIN * 2;
    unsigned short* eW1T = (unsigned short*)p;   p += (size_t)NE * DHID * DMODEL * 2; // 4.2 MB
    unsigned short* eW2T = (unsigned short*)p;   p += (size_t)NE * DMODEL * DHID * 2; // 4.2 MB
    float* glog_buf = (float*)p;             p += (size_t)T_TOKENS * NG * 4;
    float* ilog_buf = (float*)p;             p += (size_t)T_TOKENS * NG * NES * 4;
    int* counts = (int*)p;                   p += 128;   // 16 counts + nfix + pad
    int* nfix = counts + 16;
    int* fix_list = (int*)p;                 p += (size_t)T_TOKENS * 4;
    int* list_tok = (int*)p;                 p += (size_t)NE * T_TOKENS * 4;
    float* list_w = (float*)p;               p += (size_t)NE * T_TOKENS * 4;

    hipMemsetAsync(counts, 0, 128, stream);

    k_ln<<<T_TOKENS, 64, 0, stream>>>(hidden, ln_g, ln_b, hbuf, out);

    // weight transposes + bf16 splits
    k_wsplitT<<<dim3((RIN / 32) * (DRH / 32), NG), 256, 0, stream>>>(
        psW1, W1T_hi, W1T_lo, RIN, DRH, (long)RIN * DRH, (long)2 * DRH * RIN);
    k_wsplitT<<<dim3((RIN / 32) * (DRH / 32), NG), 256, 0, stream>>>(
        irW1, W1T_hi + (size_t)DRH * RIN, W1T_lo + (size_t)DRH * RIN,
        RIN, DRH, (long)RIN * DRH, (long)2 * DRH * RIN);
    k_wsplitT<<<dim3((DMODEL / 32) * (DHID / 32), NE), 256, 0, stream>>>(
        eW1, eW1T, nullptr, DMODEL, DHID, (long)DMODEL * DHID, (long)DHID * DMODEL);
    k_wsplitT<<<dim3((DHID / 32) * (DMODEL / 32), NE), 256, 0, stream>>>(
        eW2, eW2T, nullptr, DHID, DMODEL, (long)DHID * DMODEL, (long)DMODEL * DHID);

    hg_router_mfma<<<dim3(T_TOKENS / 32, NG), 256, 0, stream>>>(
        hbuf, feat, stageW, stageb, gfW, gfb, W1T_hi, W1T_lo,
        psb1, psW2, psb2, irb1, irW2, irb2, glog_buf, ilog_buf);

    hg_finalize2<<<T_TOKENS / 256, 256, 0, stream>>>(
        glog_buf, ilog_buf, counts, nfix, fix_list, list_tok, list_w);

    hg_fixup<<<128, 64, 0, stream>>>(
        hidden, feat, ln_g, ln_b, stageW, stageb, gfW, gfb,
        psW1, psb1, psW2, psb2, irW1, irb1, irW2, irb2,
        nfix, fix_list, counts, list_tok, list_w);

    hg_expert_mfma<<<dim3(T_TOKENS / 32, NE), 256, 0, stream>>>(
        hbuf, eW1T, eb1, eW2T, eb2, alpha, counts, list_tok, list_w, out);
}

// Round 4
// 832.668 us; speedup vs baseline: 2.6578x; 1.2228x over previous
//
#include <hip/hip_runtime.h>
#include <hip/hip_bf16.h>

#define T_TOKENS 16384
#define DMODEL 512
#define FFEAT 64
#define DFEMB 64
#define RIN 576
#define DRH 128
#define NG 8
#define NES 2
#define NE 16
#define DHID 256

typedef float f32x4 __attribute__((ext_vector_type(4)));
typedef short bf16x8 __attribute__((ext_vector_type(8)));
#define MFMA16(a, b, c) __builtin_amdgcn_mfma_f32_16x16x32_bf16((a), (b), (c), 0, 0, 0)

__device__ __forceinline__ float gelu_f(float x) {
    return 0.5f * x * (1.0f + erff(x * 0.7071067811865476f));
}
__device__ __forceinline__ unsigned short f2bf_rne(float x) {
    union { float f; unsigned u; } v; v.f = x;
    unsigned r = v.u + 0x7fffu + ((v.u >> 16) & 1u);
    return (unsigned short)(r >> 16);
}
__device__ __forceinline__ float bf2f(unsigned short h) {
    union { unsigned u; float f; } v; v.u = ((unsigned)h) << 16;
    return v.f;
}
__device__ __forceinline__ void gl_lds16(const unsigned short* g, unsigned short* l) {
    __builtin_amdgcn_global_load_lds(
        (const __attribute__((address_space(1))) unsigned int*)g,
        (__attribute__((address_space(3))) unsigned int*)l, 16, 0, 0);
}

// ---------- Kernel 1: LN + split to swizzled A (hi/lo) + out = hidden ----------
// A[t][0..511] = LN(h), A[t][512..575] = feat. Element k of each 32-chunk stored
// at k ^ (((t>>1)&3)*8)  (pre-swizzle so LDS stays linear for global_load_lds).
__global__ __launch_bounds__(256) void k_prep(
    const float* __restrict__ hidden, const float* __restrict__ feat,
    const float* __restrict__ lng, const float* __restrict__ lnb,
    unsigned short* __restrict__ Ahi, unsigned short* __restrict__ Alo,
    float* __restrict__ out)
{
    const int t = blockIdx.x * 4 + (threadIdx.x >> 6);
    const int lane = threadIdx.x & 63;
    const float* row = hidden + (size_t)t * DMODEL;
    float4 v0 = ((const float4*)row)[lane * 2 + 0];
    float4 v1 = ((const float4*)row)[lane * 2 + 1];
    float s = v0.x + v0.y + v0.z + v0.w + v1.x + v1.y + v1.z + v1.w;
    #pragma unroll
    for (int m = 1; m < 64; m <<= 1) s += __shfl_xor(s, m);
    const float mu = s * (1.0f / DMODEL);
    float sq = 0.f;
    { float d;
      d = v0.x - mu; sq += d * d; d = v0.y - mu; sq += d * d;
      d = v0.z - mu; sq += d * d; d = v0.w - mu; sq += d * d;
      d = v1.x - mu; sq += d * d; d = v1.y - mu; sq += d * d;
      d = v1.z - mu; sq += d * d; d = v1.w - mu; sq += d * d; }
    #pragma unroll
    for (int m = 1; m < 64; m <<= 1) sq += __shfl_xor(sq, m);
    const float rstd = rsqrtf(sq * (1.0f / DMODEL) + 1e-5f);
    float4 g0 = ((const float4*)lng)[lane * 2 + 0];
    float4 g1 = ((const float4*)lng)[lane * 2 + 1];
    float4 b0 = ((const float4*)lnb)[lane * 2 + 0];
    float4 b1 = ((const float4*)lnb)[lane * 2 + 1];
    float h[8];
    h[0] = (v0.x - mu) * rstd * g0.x + b0.x;
    h[1] = (v0.y - mu) * rstd * g0.y + b0.y;
    h[2] = (v0.z - mu) * rstd * g0.z + b0.z;
    h[3] = (v0.w - mu) * rstd * g0.w + b0.w;
    h[4] = (v1.x - mu) * rstd * g1.x + b1.x;
    h[5] = (v1.y - mu) * rstd * g1.y + b1.y;
    h[6] = (v1.z - mu) * rstd * g1.z + b1.z;
    h[7] = (v1.w - mu) * rstd * g1.w + b1.w;
    const int q8 = ((t >> 1) & 3) * 8;
    ushort4 H0, H1, L0, L1;
    H0.x = f2bf_rne(h[0]); L0.x = f2bf_rne(h[0] - bf2f(H0.x));
    H0.y = f2bf_rne(h[1]); L0.y = f2bf_rne(h[1] - bf2f(H0.y));
    H0.z = f2bf_rne(h[2]); L0.z = f2bf_rne(h[2] - bf2f(H0.z));
    H0.w = f2bf_rne(h[3]); L0.w = f2bf_rne(h[3] - bf2f(H0.w));
    H1.x = f2bf_rne(h[4]); L1.x = f2bf_rne(h[4] - bf2f(H1.x));
    H1.y = f2bf_rne(h[5]); L1.y = f2bf_rne(h[5] - bf2f(H1.y));
    H1.z = f2bf_rne(h[6]); L1.z = f2bf_rne(h[6] - bf2f(H1.z));
    H1.w = f2bf_rne(h[7]); L1.w = f2bf_rne(h[7] - bf2f(H1.w));
    unsigned short* pa = Ahi + (size_t)t * RIN;
    unsigned short* pb = Alo + (size_t)t * RIN;
    const int dst = (lane >> 2) * 32 + (((lane & 3) * 8) ^ q8);
    *(ushort4*)&pa[dst] = H0;  *(ushort4*)&pa[dst + 4] = H1;
    *(ushort4*)&pb[dst] = L0;  *(ushort4*)&pb[dst + 4] = L1;
    const float fv = feat[(size_t)t * FFEAT + lane];
    const unsigned short fh = f2bf_rne(fv);
    const unsigned short fl = f2bf_rne(fv - bf2f(fh));
    const int fd = DMODEL + (lane & 32) + ((lane & 31) ^ q8);
    pa[fd] = fh; pb[fd] = fl;
    float* orow = out + (size_t)t * DMODEL;
    ((float4*)orow)[lane * 2 + 0] = v0;
    ((float4*)orow)[lane * 2 + 1] = v1;
}

// ---------- fold kernels: tail weights absorbed into B ----------
__global__ __launch_bounds__(128) void k_fold_ps(
    const float* __restrict__ stageW, const float* __restrict__ stageb,
    const float* __restrict__ psW1, const float* __restrict__ psb1,
    float* __restrict__ Dps, float* __restrict__ fbps)
{
    const int g = blockIdx.x, f = blockIdx.y, c = threadIdx.x;
    const float* Wt = psW1 + (size_t)g * RIN * DRH + (size_t)DMODEL * DRH;
    float acc = 0.f;
    if (f < 64) {
        for (int j = 0; j < DFEMB; ++j) acc = fmaf(stageW[f * DFEMB + j], Wt[(size_t)j * DRH + c], acc);
        Dps[((size_t)g * 64 + f) * DRH + c] = acc;
    } else {
        for (int j = 0; j < DFEMB; ++j) acc = fmaf(stageb[j], Wt[(size_t)j * DRH + c], acc);
        fbps[g * DRH + c] = acc + psb1[g * DRH + c];
    }
}

__global__ __launch_bounds__(128) void k_fold_ir(
    const float* __restrict__ gfW, const float* __restrict__ gfb,
    const float* __restrict__ irW1, const float* __restrict__ irb1,
    float* __restrict__ Cir, float* __restrict__ fbir)
{
    const int g = blockIdx.x, f = blockIdx.y, c = threadIdx.x;
    const float* Wt = irW1 + (size_t)g * RIN * DRH + (size_t)DMODEL * DRH;
    float acc = 0.f;
    if (f < 8) {
        for (int j = 0; j < DFEMB; ++j) acc = fmaf(gfW[(size_t)(g * 8 + f) * DFEMB + j], Wt[(size_t)j * DRH + c], acc);
        Cir[((size_t)g * 8 + f) * DRH + c] = acc;
    } else {
        for (int j = 0; j < DFEMB; ++j) acc = fmaf(gfb[g * DFEMB + j], Wt[(size_t)j * DRH + c], acc);
        fbir[g * DRH + c] = acc + irb1[g * DRH + c];
    }
}

// ---------- transpose + hi/lo split, swizzled dest: in[K][N] -> out[N][K'] ----------
__global__ __launch_bounds__(256) void k_bsplitT(
    const float* __restrict__ in, unsigned short* __restrict__ outHi,
    unsigned short* __restrict__ outLo, int K, int N, int outStride, int kOff,
    long inBS, long outBS)
{
    __shared__ float s_t[32][33];
    const int b = blockIdx.y;
    const int tilesN = N >> 5;
    const int ko = (blockIdx.x / tilesN) << 5;
    const int no = (blockIdx.x % tilesN) << 5;
    const int r = threadIdx.x >> 3, c0 = (threadIdx.x & 7) * 4;
    {
        float4 v = *(const float4*)(in + (size_t)b * inBS + (size_t)(ko + r) * N + no + c0);
        s_t[r][c0] = v.x; s_t[r][c0 + 1] = v.y; s_t[r][c0 + 2] = v.z; s_t[r][c0 + 3] = v.w;
    }
    __syncthreads();
    float vv[4];
    #pragma unroll
    for (int j = 0; j < 4; ++j) vv[j] = s_t[c0 + j][r];
    const int col = no + r;
    const int q8 = ((col >> 1) & 3) * 8;
    ushort4 hi, lo;
    hi.x = f2bf_rne(vv[0]); lo.x = f2bf_rne(vv[0] - bf2f(hi.x));
    hi.y = f2bf_rne(vv[1]); lo.y = f2bf_rne(vv[1] - bf2f(hi.y));
    hi.z = f2bf_rne(vv[2]); lo.z = f2bf_rne(vv[2] - bf2f(hi.z));
    hi.w = f2bf_rne(vv[3]); lo.w = f2bf_rne(vv[3] - bf2f(hi.w));
    const size_t off = (size_t)b * outBS + (size_t)col * outStride + kOff + ko + (c0 ^ q8);
    *(ushort4*)(outHi + off) = hi;
    if (outLo) *(ushort4*)(outLo + off) = lo;
}

// ---------- ir tail rows of B: mostly zero, Cir scattered in ----------
__global__ __launch_bounds__(128) void k_irtail(
    const float* __restrict__ Cir, unsigned short* __restrict__ Bhi,
    unsigned short* __restrict__ Blo)
{
    const int g = blockIdx.x, c = threadIdx.x;
    const int col = 1024 + g * DRH + c;
    const int q8 = ((col >> 1) & 3) * 8;
    unsigned short* ph = Bhi + (size_t)col * RIN + DMODEL;
    unsigned short* pl = Blo + (size_t)col * RIN + DMODEL;
    for (int f = 0; f < 64; ++f) {
        float v = ((f >> 3) == g) ? Cir[((size_t)g * 8 + (f & 7)) * DRH + c] : 0.f;
        unsigned short h = f2bf_rne(v), l = f2bf_rne(v - bf2f(h));
        const int d = (f & 32) + ((f & 31) ^ q8);
        ph[d] = h; pl[d] = l;
    }
}

// ---------- Kernel 2: router GEMM [16384x576]@[576x2048], split-bf16 3-pass ----------
// grid (128, 8): 128-token x 256-col tiles; 8 waves, wave-tile 64x64.
__global__ __launch_bounds__(512) void k_rgemm(
    const unsigned short* __restrict__ Ahi, const unsigned short* __restrict__ Alo,
    const unsigned short* __restrict__ Bhi, const unsigned short* __restrict__ Blo,
    const float* __restrict__ fbps, const float* __restrict__ psW2, const float* __restrict__ psb2,
    const float* __restrict__ fbir, const float* __restrict__ irW2, const float* __restrict__ irb2,
    float* __restrict__ glog, float* __restrict__ ilog)
{
    __shared__ unsigned short sAh[128 * 32], sAl[128 * 32];
    __shared__ unsigned short sBh[256 * 32], sBl[256 * 32];
    __shared__ float s_red[2][4][64][2];

    const int tid = threadIdx.x, lane = tid & 63, w = tid >> 6;
    const int t0 = blockIdx.x * 128, bn = blockIdx.y;
    const int wm = w >> 2, wn = w & 3;
    const int arow = lane & 15, koff = (lane >> 4) * 8;
    const int q8r = ((arow >> 1) & 3) * 8;   // swizzle key (same for all frags)

    int aoff[4], boff[4];
    #pragma unroll
    for (int m = 0; m < 4; ++m) aoff[m] = (wm * 64 + m * 16 + arow) * 32 + (koff ^ q8r);
    #pragma unroll
    for (int n = 0; n < 4; ++n) boff[n] = (wn * 64 + n * 16 + arow) * 32 + (koff ^ q8r);

    // staging pointers (pre-swizzled global, linear LDS)
    const int srow = w * 16 + (lane >> 2);
    const int sgr = (lane & 3) * 8;
    const unsigned short* gAh = Ahi + (size_t)(t0 + srow) * RIN + sgr;
    const unsigned short* gAl = Alo + (size_t)(t0 + srow) * RIN + sgr;
    const unsigned short* gBh0 = Bhi + (size_t)(bn * 256 + w * 32 + (lane >> 2)) * RIN + sgr;
    const unsigned short* gBh1 = gBh0 + (size_t)16 * RIN;
    const unsigned short* gBl0 = Blo + (size_t)(bn * 256 + w * 32 + (lane >> 2)) * RIN + sgr;
    const unsigned short* gBl1 = gBl0 + (size_t)16 * RIN;
    unsigned short* dAh = sAh + w * 512;
    unsigned short* dAl = sAl + w * 512;
    unsigned short* dBh0 = sBh + w * 1024;
    unsigned short* dBh1 = sBh + w * 1024 + 512;
    unsigned short* dBl0 = sBl + w * 1024;
    unsigned short* dBl1 = sBl + w * 1024 + 512;

    f32x4 acc[4][4];
    #pragma unroll
    for (int m = 0; m < 4; ++m)
        #pragma unroll
        for (int n = 0; n < 4; ++n) { acc[m][n].x = 0.f; acc[m][n].y = 0.f; acc[m][n].z = 0.f; acc[m][n].w = 0.f; }

    for (int kt = 0; kt < 18; ++kt) {
        const int kk = kt * 32;
        gl_lds16(gAh + kk, dAh);
        gl_lds16(gAl + kk, dAl);
        gl_lds16(gBh0 + kk, dBh0);
        gl_lds16(gBh1 + kk, dBh1);
        gl_lds16(gBl0 + kk, dBl0);
        gl_lds16(gBl1 + kk, dBl1);
        __syncthreads();
        bf16x8 ah[4], al[4];
        #pragma unroll
        for (int m = 0; m < 4; ++m) {
            ah[m] = *(const bf16x8*)&sAh[aoff[m]];
            al[m] = *(const bf16x8*)&sAl[aoff[m]];
        }
        #pragma unroll
        for (int np = 0; np < 2; ++np) {
            bf16x8 bh0 = *(const bf16x8*)&sBh[boff[np * 2 + 0]];
            bf16x8 bh1 = *(const bf16x8*)&sBh[boff[np * 2 + 1]];
            bf16x8 bl0 = *(const bf16x8*)&sBl[boff[np * 2 + 0]];
            bf16x8 bl1 = *(const bf16x8*)&sBl[boff[np * 2 + 1]];
            #pragma unroll
            for (int m = 0; m < 4; ++m) acc[m][np * 2 + 0] = MFMA16(ah[m], bh0, acc[m][np * 2 + 0]);
            #pragma unroll
            for (int m = 0; m < 4; ++m) acc[m][np * 2 + 1] = MFMA16(ah[m], bh1, acc[m][np * 2 + 1]);
            #pragma unroll
            for (int m = 0; m < 4; ++m) acc[m][np * 2 + 0] = MFMA16(ah[m], bl0, acc[m][np * 2 + 0]);
            #pragma unroll
            for (int m = 0; m < 4; ++m) acc[m][np * 2 + 1] = MFMA16(ah[m], bl1, acc[m][np * 2 + 1]);
            #pragma unroll
            for (int m = 0; m < 4; ++m) acc[m][np * 2 + 0] = MFMA16(al[m], bh0, acc[m][np * 2 + 0]);
            #pragma unroll
            for (int m = 0; m < 4; ++m) acc[m][np * 2 + 1] = MFMA16(al[m], bh1, acc[m][np * 2 + 1]);
        }
        __syncthreads();
    }

    // fused second layers
    const int grp = wn >> 1;
    const bool isPS = (bn < 4);
    const int g = isPS ? (bn * 2 + grp) : ((bn - 4) * 2 + grp);
    const int q = lane >> 4;
    if (isPS) {
        float r0[4][4] = {};
        #pragma unroll
        for (int n = 0; n < 4; ++n) {
            const int cg = (wn & 1) * 64 + n * 16 + arow;
            const float b1 = fbps[g * DRH + cg];
            const float w2 = psW2[g * DRH + cg];
            #pragma unroll
            for (int m = 0; m < 4; ++m)
                #pragma unroll
                for (int j = 0; j < 4; ++j)
                    r0[m][j] += gelu_f(acc[m][n][j] + b1) * w2;
        }
        #pragma unroll
        for (int mk = 1; mk < 16; mk <<= 1)
            #pragma unroll
            for (int m = 0; m < 4; ++m)
                #pragma unroll
                for (int j = 0; j < 4; ++j) r0[m][j] += __shfl_xor(r0[m][j], mk);
        if (arow == 0) {
            #pragma unroll
            for (int m = 0; m < 4; ++m)
                #pragma unroll
                for (int j = 0; j < 4; ++j) {
                    s_red[wm][wn][m * 16 + q * 4 + j][0] = r0[m][j];
                    s_red[wm][wn][m * 16 + q * 4 + j][1] = 0.f;
                }
        }
    } else {
        float r0[4][4] = {}, r1[4][4] = {};
        #pragma unroll
        for (int n = 0; n < 4; ++n) {
            const int cg = (wn & 1) * 64 + n * 16 + arow;
            const float b1 = fbir[g * DRH + cg];
            const float w20 = irW2[(size_t)(g * DRH + cg) * NES + 0];
            const float w21 = irW2[(size_t)(g * DRH + cg) * NES + 1];
            #pragma unroll
            for (int m = 0; m < 4; ++m)
                #pragma unroll
                for (int j = 0; j < 4; ++j) {
                    const float v = gelu_f(acc[m][n][j] + b1);
                    r0[m][j] = fmaf(v, w20, r0[m][j]);
                    r1[m][j] = fmaf(v, w21, r1[m][j]);
                }
        }
        #pragma unroll
        for (int mk = 1; mk < 16; mk <<= 1)
            #pragma unroll
            for (int m = 0; m < 4; ++m)
                #pragma unroll
                for (int j = 0; j < 4; ++j) {
                    r0[m][j] += __shfl_xor(r0[m][j], mk);
                    r1[m][j] += __shfl_xor(r1[m][j], mk);
                }
        if (arow == 0) {
            #pragma unroll
            for (int m = 0; m < 4; ++m)
                #pragma unroll
                for (int j = 0; j < 4; ++j) {
                    s_red[wm][wn][m * 16 + q * 4 + j][0] = r0[m][j];
                    s_red[wm][wn][m * 16 + q * 4 + j][1] = r1[m][j];
                }
        }
    }
    __syncthreads();
    if (tid < 256) {
        const int row = tid >> 1, sub = tid & 1;
        const int rl = row & 63, wmm = row >> 6;
        if (isPS) {
            const int gg = bn * 2 + sub;
            glog[(size_t)(t0 + row) * NG + gg] =
                s_red[wmm][sub * 2][rl][0] + s_red[wmm][sub * 2 + 1][rl][0] + psb2[gg];
        } else {
            const int gg = (bn - 4) * 2 + sub;
            const size_t bidx = ((size_t)(t0 + row) * NG + gg) * NES;
            ilog[bidx + 0] = s_red[wmm][sub * 2][rl][0] + s_red[wmm][sub * 2 + 1][rl][0] + irb2[gg * NES + 0];
            ilog[bidx + 1] = s_red[wmm][sub * 2][rl][1] + s_red[wmm][sub * 2 + 1][rl][1] + irb2[gg * NES + 1];
        }
    }
}

// ---------- Kernel 2b: finalize with margin check ----------
#define MARGIN 2e-3f
__global__ __launch_bounds__(256) void hg_finalize2(
    const float* __restrict__ glog_buf, const float* __restrict__ ilog_buf,
    int* __restrict__ counts, int* __restrict__ nfix, int* __restrict__ fix_list,
    int* __restrict__ list_tok, float* __restrict__ list_w)
{
    const int t = blockIdx.x * 256 + threadIdx.x;
    float gl[NG];
    *(float4*)&gl[0] = ((const float4*)(glog_buf + (size_t)t * NG))[0];
    *(float4*)&gl[4] = ((const float4*)(glog_buf + (size_t)t * NG))[1];
    int i1 = 0; float m1 = gl[0];
    #pragma unroll
    for (int g = 1; g < NG; ++g) if (gl[g] > m1) { m1 = gl[g]; i1 = g; }
    int i2 = -1; float m2 = -3.4e38f;
    #pragma unroll
    for (int g = 0; g < NG; ++g) if (g != i1 && gl[g] > m2) { m2 = gl[g]; i2 = g; }
    float m3 = -3.4e38f;
    #pragma unroll
    for (int g = 0; g < NG; ++g) if (g != i1 && g != i2 && gl[g] > m3) m3 = gl[g];

    const float ila0 = ilog_buf[((size_t)t * NG + i1) * NES + 0];
    const float ila1 = ilog_buf[((size_t)t * NG + i1) * NES + 1];
    const float ilb0 = ilog_buf[((size_t)t * NG + i2) * NES + 0];
    const float ilb1 = ilog_buf[((size_t)t * NG + i2) * NES + 1];

    const bool flag = ((m2 - m3) < MARGIN) || (fabsf(ila1 - ila0) < MARGIN)
                   || (fabsf(ilb1 - ilb0) < MARGIN);
    if (flag) {
        const int p = atomicAdd(nfix, 1);
        fix_list[p] = t;
        return;
    }
    const float ex = expf(m2 - m1);
    const float inv = 1.0f / (1.0f + ex);
    const int   gsel[2] = {i1, i2};
    const float wsel[2] = {inv, ex * inv};
    const int   ksel[2] = {(ila1 > ila0) ? 1 : 0, (ilb1 > ilb0) ? 1 : 0};
    #pragma unroll
    for (int s = 0; s < 2; ++s) {
        const int eid = gsel[s] * NES + ksel[s];
        const int pos = atomicAdd(&counts[eid], 1);
        list_tok[(size_t)eid * T_TOKENS + pos] = t;
        list_w[(size_t)eid * T_TOKENS + pos] = wsel[s];
    }
}

// ---------- Kernel 2c: exact fp32 fixup for near-tie tokens ----------
__global__ __launch_bounds__(64) void hg_fixup(
    const float* __restrict__ hidden, const float* __restrict__ feat,
    const float* __restrict__ lng, const float* __restrict__ lnb,
    const float* __restrict__ stageW, const float* __restrict__ stageb,
    const float* __restrict__ gfW, const float* __restrict__ gfb,
    const float* __restrict__ psW1, const float* __restrict__ psb1,
    const float* __restrict__ psW2, const float* __restrict__ psb2,
    const float* __restrict__ irW1, const float* __restrict__ irb1,
    const float* __restrict__ irW2, const float* __restrict__ irb2,
    const int* __restrict__ nfix, const int* __restrict__ fix_list,
    int* __restrict__ counts, int* __restrict__ list_tok, float* __restrict__ list_w)
{
    __shared__ float s_rin[RIN];
    const int lane = threadIdx.x;
    const int nf = nfix[0];
    for (int idx = blockIdx.x; idx < nf; idx += gridDim.x) {
        const int t = fix_list[idx];
        const float* row = hidden + (size_t)t * DMODEL;
        float4 v0 = ((const float4*)row)[lane * 2 + 0];
        float4 v1 = ((const float4*)row)[lane * 2 + 1];
        float s = v0.x + v0.y + v0.z + v0.w + v1.x + v1.y + v1.z + v1.w;
        #pragma unroll
        for (int m = 1; m < 64; m <<= 1) s += __shfl_xor(s, m);
        const float mu = s * (1.0f / DMODEL);
        float sq = 0.f;
        { float d;
          d = v0.x - mu; sq += d * d; d = v0.y - mu; sq += d * d;
          d = v0.z - mu; sq += d * d; d = v0.w - mu; sq += d * d;
          d = v1.x - mu; sq += d * d; d = v1.y - mu; sq += d * d;
          d = v1.z - mu; sq += d * d; d = v1.w - mu; sq += d * d; }
        #pragma unroll
        for (int m = 1; m < 64; m <<= 1) sq += __shfl_xor(sq, m);
        const float rstd = rsqrtf(sq * (1.0f / DMODEL) + 1e-5f);
        {
            float4 g0 = ((const float4*)lng)[lane * 2 + 0];
            float4 g1 = ((const float4*)lng)[lane * 2 + 1];
            float4 b0 = ((const float4*)lnb)[lane * 2 + 0];
            float4 b1 = ((const float4*)lnb)[lane * 2 + 1];
            s_rin[lane * 8 + 0] = (v0.x - mu) * rstd * g0.x + b0.x;
            s_rin[lane * 8 + 1] = (v0.y - mu) * rstd * g0.y + b0.y;
            s_rin[lane * 8 + 2] = (v0.z - mu) * rstd * g0.z + b0.z;
            s_rin[lane * 8 + 3] = (v0.w - mu) * rstd * g0.w + b0.w;
            s_rin[lane * 8 + 4] = (v1.x - mu) * rstd * g1.x + b1.x;
            s_rin[lane * 8 + 5] = (v1.y - mu) * rstd * g1.y + b1.y;
            s_rin[lane * 8 + 6] = (v1.z - mu) * rstd * g1.z + b1.z;
            s_rin[lane * 8 + 7] = (v1.w - mu) * rstd * g1.w + b1.w;
        }
        {
            float se = stageb[lane];
            for (int f = 0; f < FFEAT; ++f)
                se = fmaf(feat[(size_t)t * FFEAT + f], stageW[f * DFEMB + lane], se);
            s_rin[DMODEL + lane] = se;
        }
        __syncthreads();
        float gl[NG];
        for (int g = 0; g < NG; ++g) {
            float a0 = psb1[g * DRH + lane];
            float a1 = psb1[g * DRH + 64 + lane];
            const float* W = psW1 + (size_t)g * RIN * DRH;
            for (int k = 0; k < RIN; ++k) {
                const float r = s_rin[k];
                a0 = fmaf(r, W[(size_t)k * DRH + lane], a0);
                a1 = fmaf(r, W[(size_t)k * DRH + 64 + lane], a1);
            }
            float p = gelu_f(a0) * psW2[g * DRH + lane] + gelu_f(a1) * psW2[g * DRH + 64 + lane];
            #pragma unroll
            for (int m = 1; m < 64; m <<= 1) p += __shfl_xor(p, m);
            gl[g] = p + psb2[g];
        }
        int i1 = 0; float m1 = gl[0];
        #pragma unroll
        for (int g = 1; g < NG; ++g) if (gl[g] > m1) { m1 = gl[g]; i1 = g; }
        int i2 = -1; float m2 = -3.4e38f;
        #pragma unroll
        for (int g = 0; g < NG; ++g) if (g != i1 && gl[g] > m2) { m2 = gl[g]; i2 = g; }
        const float ex = expf(m2 - m1);
        const float inv = 1.0f / (1.0f + ex);
        const int   gsel[2] = {i1, i2};
        const float wsel[2] = {inv, ex * inv};
        for (int sidx = 0; sidx < 2; ++sidx) {
            const int g = gsel[sidx];
            float ge = gfb[g * DFEMB + lane];
            #pragma unroll
            for (int f = 0; f < 8; ++f)
                ge = fmaf(feat[(size_t)t * FFEAT + g * 8 + f],
                          gfW[(size_t)(g * 8 + f) * DFEMB + lane], ge);
            __syncthreads();
            s_rin[DMODEL + lane] = ge;
            __syncthreads();
            float a0 = irb1[g * DRH + lane];
            float a1 = irb1[g * DRH + 64 + lane];
            const float* W = irW1 + (size_t)g * RIN * DRH;
            for (int k = 0; k < RIN; ++k) {
                const float r = s_rin[k];
                a0 = fmaf(r, W[(size_t)k * DRH + lane], a0);
                a1 = fmaf(r, W[(size_t)k * DRH + 64 + lane], a1);
            }
            const float ga0 = gelu_f(a0), ga1 = gelu_f(a1);
            float e0 = ga0 * irW2[(size_t)(g * DRH + lane) * NES + 0]
                     + ga1 * irW2[(size_t)(g * DRH + 64 + lane) * NES + 0];
            float e1 = ga0 * irW2[(size_t)(g * DRH + lane) * NES + 1]
                     + ga1 * irW2[(size_t)(g * DRH + 64 + lane) * NES + 1];
            #pragma unroll
            for (int m = 1; m < 64; m <<= 1) {
                e0 += __shfl_xor(e0, m);
                e1 += __shfl_xor(e1, m);
            }
            if (lane == 0) {
                const int eid = g * NES + ((e1 > e0) ? 1 : 0);
                const int pos = atomicAdd(&counts[eid], 1);
                list_tok[(size_t)eid * T_TOKENS + pos] = t;
                list_w[(size_t)eid * T_TOKENS + pos] = wsel[sidx];
            }
        }
        __syncthreads();
    }
}

// ---------- Kernel 3: experts, 64-token blocks, LDS-staged everything ----------
__global__ __launch_bounds__(256) void k_expert(
    const unsigned short* __restrict__ Ahi,
    const unsigned short* __restrict__ eW1T, const float* __restrict__ eb1,
    const unsigned short* __restrict__ eW2T, const float* __restrict__ eb2,
    const float* __restrict__ alpha_p,
    const int* __restrict__ counts, const int* __restrict__ list_tok,
    const float* __restrict__ list_w, float* __restrict__ out)
{
    __shared__ char smem[65536];
    unsigned short* sEH = (unsigned short*)smem;                 // [64][256] 32KB
    unsigned short* sA  = (unsigned short*)(smem + 32768);       // [64][32]  4KB
    unsigned short* sB1 = (unsigned short*)(smem + 36864);       // [256][32] 16KB
    unsigned short* sB2 = (unsigned short*)(smem + 32768);       // [512][32] 32KB (aliases sA/sB1)
    __shared__ int s_tok[64];
    __shared__ float s_w[64];

    const int e = blockIdx.y;
    const int cnt = counts[e];
    const int base = blockIdx.x * 64;
    if (base >= cnt) return;
    const int nrow = min(64, cnt - base);
    const int tid = threadIdx.x, lane = tid & 63, w = tid >> 6;

    if (tid < 64) {
        const int src = base + ((tid < nrow) ? tid : (nrow - 1));
        s_tok[tid] = list_tok[(size_t)e * T_TOKENS + src];
        s_w[tid] = (tid < nrow) ? list_w[(size_t)e * T_TOKENS + base + tid] : 0.f;
    }
    __syncthreads();

    const int srow = w * 16 + (lane >> 2);
    const int stok = s_tok[srow];
    const int qcor = ((srow >> 1) & 3) ^ ((stok >> 1) & 3);
    const unsigned short* gA = Ahi + (size_t)stok * RIN + 8 * ((lane & 3) ^ qcor);
    unsigned short* dA = sA + w * 512;
    const int sgr = (lane & 3) * 8;
    const unsigned short* gB1[4];
    #pragma unroll
    for (int i = 0; i < 4; ++i)
        gB1[i] = eW1T + (size_t)e * DHID * DMODEL + (size_t)(w * 64 + i * 16 + (lane >> 2)) * DMODEL + sgr;

    const int arow = lane & 15, koff = (lane >> 4) * 8;
    const int q8r = ((arow >> 1) & 3) * 8;
    int aoff[4], b1off[4];
    #pragma unroll
    for (int m = 0; m < 4; ++m) aoff[m] = (m * 16 + arow) * 32 + (koff ^ q8r);
    #pragma unroll
    for (int n = 0; n < 4; ++n) b1off[n] = (w * 64 + n * 16 + arow) * 32 + (koff ^ q8r);

    f32x4 acc1[4][4];
    #pragma unroll
    for (int m = 0; m < 4; ++m)
        #pragma unroll
        for (int n = 0; n < 4; ++n) { acc1[m][n].x = 0.f; acc1[m][n].y = 0.f; acc1[m][n].z = 0.f; acc1[m][n].w = 0.f; }

    for (int kt = 0; kt < 16; ++kt) {
        const int kk = kt * 32;
        gl_lds16(gA + kk, dA);
        #pragma unroll
        for (int i = 0; i < 4; ++i) gl_lds16(gB1[i] + kk, sB1 + w * 2048 + i * 512);
        __syncthreads();
        bf16x8 a[4];
        #pragma unroll
        for (int m = 0; m < 4; ++m) a[m] = *(const bf16x8*)&sA[aoff[m]];
        #pragma unroll
        for (int n = 0; n < 4; ++n) {
            bf16x8 b = *(const bf16x8*)&sB1[b1off[n]];
            #pragma unroll
            for (int m = 0; m < 4; ++m) acc1[m][n] = MFMA16(a[m], b, acc1[m][n]);
        }
        __syncthreads();
    }

    // eh = gelu(acc1 + b1) -> sEH (swizzled by row)
    const int q = lane >> 4;
    #pragma unroll
    for (int m = 0; m < 4; ++m)
        #pragma unroll
        for (int n = 0; n < 4; ++n) {
            const int col = w * 64 + n * 16 + arow;
            const float bv = eb1[e * DHID + col];
            #pragma unroll
            for (int j = 0; j < 4; ++j) {
                const int rr = m * 16 + q * 4 + j;
                const int d = rr * 256 + (col & 0xE0) + ((col & 31) ^ (((rr >> 1) & 3) * 8));
                sEH[d] = f2bf_rne(gelu_f(acc1[m][n][j] + bv));
            }
        }
    __syncthreads();

    // GEMM2: [64x256]@[256x512]
    const unsigned short* gB2[8];
    #pragma unroll
    for (int i = 0; i < 8; ++i)
        gB2[i] = eW2T + (size_t)e * DMODEL * DHID + (size_t)(w * 128 + i * 16 + (lane >> 2)) * DHID + sgr;
    int a2base[4], b2off[8];
    #pragma unroll
    for (int m = 0; m < 4; ++m) a2base[m] = (m * 16 + arow) * 256 + (koff ^ q8r);
    #pragma unroll
    for (int n = 0; n < 8; ++n) b2off[n] = (w * 128 + n * 16 + arow) * 32 + (koff ^ q8r);

    f32x4 acc2[4][8];
    #pragma unroll
    for (int m = 0; m < 4; ++m)
        #pragma unroll
        for (int n = 0; n < 8; ++n) { acc2[m][n].x = 0.f; acc2[m][n].y = 0.f; acc2[m][n].z = 0.f; acc2[m][n].w = 0.f; }

    for (int kt = 0; kt < 8; ++kt) {
        #pragma unroll
        for (int i = 0; i < 8; ++i) gl_lds16(gB2[i] + kt * 32, sB2 + w * 4096 + i * 512);
        __syncthreads();
        bf16x8 a[4];
        #pragma unroll
        for (int m = 0; m < 4; ++m) a[m] = *(const bf16x8*)&sEH[a2base[m] + kt * 32];
        #pragma unroll
        for (int n = 0; n < 8; ++n) {
            bf16x8 b = *(const bf16x8*)&sB2[b2off[n]];
            #pragma unroll
            for (int m = 0; m < 4; ++m) acc2[m][n] = MFMA16(a[m], b, acc2[m][n]);
        }
        __syncthreads();
    }

    const float alpha = alpha_p[0];
    #pragma unroll
    for (int m = 0; m < 4; ++m)
        #pragma unroll
        for (int n = 0; n < 8; ++n) {
            const int col = w * 128 + n * 16 + arow;
            const float b2v = eb2[e * DMODEL + col];
            #pragma unroll
            for (int j = 0; j < 4; ++j) {
                const int r = m * 16 + q * 4 + j;
                if (r < nrow)
                    atomicAdd(out + (size_t)s_tok[r] * DMODEL + col,
                              s_w[r] * alpha * (acc2[m][n][j] + b2v));
            }
        }
}

// ---------- launch ----------
extern "C" void kernel_launch(void* const* d_in, const int* in_sizes, int n_in,
                              void* d_out, int out_size, void* d_ws, size_t ws_size,
                              hipStream_t stream) {
    const float* hidden = (const float*)d_in[0];
    const float* feat   = (const float*)d_in[1];
    const float* ln_g   = (const float*)d_in[2];
    const float* ln_b   = (const float*)d_in[3];
    const float* stageW = (const float*)d_in[4];
    const float* stageb = (const float*)d_in[5];
    const float* gfW    = (const float*)d_in[6];
    const float* gfb    = (const float*)d_in[7];
    const float* psW1   = (const float*)d_in[8];
    const float* psb1   = (const float*)d_in[9];
    const float* psW2   = (const float*)d_in[10];
    const float* psb2   = (const float*)d_in[11];
    const float* irW1   = (const float*)d_in[12];
    const float* irb1   = (const float*)d_in[13];
    const float* irW2   = (const float*)d_in[14];
    const float* irb2   = (const float*)d_in[15];
    const float* eW1    = (const float*)d_in[16];
    const float* eb1    = (const float*)d_in[17];
    const float* eW2    = (const float*)d_in[18];
    const float* eb2    = (const float*)d_in[19];
    const float* alpha  = (const float*)d_in[20];

    float* out = (float*)d_out;

    char* p = (char*)d_ws;
    unsigned short* Ahi = (unsigned short*)p; p += (size_t)T_TOKENS * RIN * 2;
    unsigned short* Alo = (unsigned short*)p; p += (size_t)T_TOKENS * RIN * 2;
    unsigned short* Bhi = (unsigned short*)p; p += (size_t)2048 * RIN * 2;
    unsigned short* Blo = (unsigned short*)p; p += (size_t)2048 * RIN * 2;
    unsigned short* eW1T = (unsigned short*)p; p += (size_t)NE * DHID * DMODEL * 2;
    unsigned short* eW2T = (unsigned short*)p; p += (size_t)NE * DMODEL * DHID * 2;
    float* Dps = (float*)p;   p += (size_t)NG * 64 * DRH * 4;
    float* Cir = (float*)p;   p += (size_t)NG * 8 * DRH * 4;
    float* fbps = (float*)p;  p += (size_t)NG * DRH * 4;
    float* fbir = (float*)p;  p += (size_t)NG * DRH * 4;
    float* glog_buf = (float*)p; p += (size_t)T_TOKENS * NG * 4;
    float* ilog_buf = (float*)p; p += (size_t)T_TOKENS * NG * NES * 4;
    int* counts = (int*)p;    p += 128;
    int* nfix = counts + 16;
    int* fix_list = (int*)p;  p += (size_t)T_TOKENS * 4;
    int* list_tok = (int*)p;  p += (size_t)NE * T_TOKENS * 4;
    float* list_w = (float*)p; p += (size_t)NE * T_TOKENS * 4;

    hipMemsetAsync(counts, 0, 128, stream);

    k_prep<<<T_TOKENS / 4, 256, 0, stream>>>(hidden, feat, ln_g, ln_b, Ahi, Alo, out);

    k_fold_ps<<<dim3(NG, 65), 128, 0, stream>>>(stageW, stageb, psW1, psb1, Dps, fbps);
    k_fold_ir<<<dim3(NG, 9), 128, 0, stream>>>(gfW, gfb, irW1, irb1, Cir, fbir);

    // B build: ps main rows 0-511, ir main rows 0-511, ps tail (Dps), ir tail (Cir)
    k_bsplitT<<<dim3(64, NG), 256, 0, stream>>>(
        psW1, Bhi, Blo, 512, DRH, RIN, 0, (long)RIN * DRH, (long)DRH * RIN);
    k_bsplitT<<<dim3(64, NG), 256, 0, stream>>>(
        irW1, Bhi + (size_t)1024 * RIN, Blo + (size_t)1024 * RIN,
        512, DRH, RIN, 0, (long)RIN * DRH, (long)DRH * RIN);
    k_bsplitT<<<dim3(8, NG), 256, 0, stream>>>(
        Dps, Bhi, Blo, 64, DRH, RIN, 512, (long)64 * DRH, (long)DRH * RIN);
    k_irtail<<<NG, 128, 0, stream>>>(Cir, Bhi, Blo);

    // expert weights
    k_bsplitT<<<dim3(128, NE), 256, 0, stream>>>(
        eW1, eW1T, nullptr, DMODEL, DHID, DMODEL, 0, (long)DMODEL * DHID, (long)DHID * DMODEL);
    k_bsplitT<<<dim3(128, NE), 256, 0, stream>>>(
        eW2, eW2T, nullptr, DHID, DMODEL, DHID, 0, (long)DHID * DMODEL, (long)DMODEL * DHID);

    k_rgemm<<<dim3(T_TOKENS / 128, 8), 512, 0, stream>>>(
        Ahi, Alo, Bhi, Blo, fbps, psW2, psb2, fbir, irW2, irb2, glog_buf, ilog_buf);

    hg_finalize2<<<T_TOKENS / 256, 256, 0, stream>>>(
        glog_buf, ilog_buf, counts, nfix, fix_list, list_tok, list_w);

    hg_fixup<<<128, 64, 0, stream>>>(
        hidden, feat, ln_g, ln_b, stageW, stageb, gfW, gfb,
        psW1, psb1, psW2, psb2, irW1, irb1, irW2, irb2,
        nfix, fix_list, counts, list_tok, list_w);

    k_expert<<<dim3(T_TOKENS / 64, NE), 256, 0, stream>>>(
        Ahi, eW1T, eb1, eW2T, eb2, alpha, counts, list_tok, list_w, out);
}

// Round 5
// 653.840 us; speedup vs baseline: 3.3847x; 1.2735x over previous
//
#include <hip/hip_runtime.h>
#include <hip/hip_bf16.h>

#define T_TOKENS 16384
#define DMODEL 512
#define FFEAT 64
#define DFEMB 64
#define RIN 576
#define DRH 128
#define NG 8
#define NES 2
#define NE 16
#define DHID 256

typedef float f32x4 __attribute__((ext_vector_type(4)));
typedef short bf16x8 __attribute__((ext_vector_type(8)));
#define MFMA16(a, b, c) __builtin_amdgcn_mfma_f32_16x16x32_bf16((a), (b), (c), 0, 0, 0)

__device__ __forceinline__ float gelu_f(float x) {
    return 0.5f * x * (1.0f + erff(x * 0.7071067811865476f));
}
__device__ __forceinline__ unsigned short f2bf_rne(float x) {
    union { float f; unsigned u; } v; v.f = x;
    unsigned r = v.u + 0x7fffu + ((v.u >> 16) & 1u);
    return (unsigned short)(r >> 16);
}
__device__ __forceinline__ float bf2f(unsigned short h) {
    union { unsigned u; float f; } v; v.u = ((unsigned)h) << 16;
    return v.f;
}
__device__ __forceinline__ void gl_lds16(const unsigned short* g, unsigned short* l) {
    __builtin_amdgcn_global_load_lds(
        (const __attribute__((address_space(1))) unsigned int*)g,
        (__attribute__((address_space(3))) unsigned int*)l, 16, 0, 0);
}

// ---------- Kernel 1: LN + bf16 swizzled A + out = hidden ----------
__global__ __launch_bounds__(256) void k_prep(
    const float* __restrict__ hidden, const float* __restrict__ feat,
    const float* __restrict__ lng, const float* __restrict__ lnb,
    unsigned short* __restrict__ Ahi, float* __restrict__ out)
{
    const int t = blockIdx.x * 4 + (threadIdx.x >> 6);
    const int lane = threadIdx.x & 63;
    const float* row = hidden + (size_t)t * DMODEL;
    float4 v0 = ((const float4*)row)[lane * 2 + 0];
    float4 v1 = ((const float4*)row)[lane * 2 + 1];
    float s = v0.x + v0.y + v0.z + v0.w + v1.x + v1.y + v1.z + v1.w;
    #pragma unroll
    for (int m = 1; m < 64; m <<= 1) s += __shfl_xor(s, m);
    const float mu = s * (1.0f / DMODEL);
    float sq = 0.f;
    { float d;
      d = v0.x - mu; sq += d * d; d = v0.y - mu; sq += d * d;
      d = v0.z - mu; sq += d * d; d = v0.w - mu; sq += d * d;
      d = v1.x - mu; sq += d * d; d = v1.y - mu; sq += d * d;
      d = v1.z - mu; sq += d * d; d = v1.w - mu; sq += d * d; }
    #pragma unroll
    for (int m = 1; m < 64; m <<= 1) sq += __shfl_xor(sq, m);
    const float rstd = rsqrtf(sq * (1.0f / DMODEL) + 1e-5f);
    float4 g0 = ((const float4*)lng)[lane * 2 + 0];
    float4 g1 = ((const float4*)lng)[lane * 2 + 1];
    float4 b0 = ((const float4*)lnb)[lane * 2 + 0];
    float4 b1 = ((const float4*)lnb)[lane * 2 + 1];
    float h[8];
    h[0] = (v0.x - mu) * rstd * g0.x + b0.x;
    h[1] = (v0.y - mu) * rstd * g0.y + b0.y;
    h[2] = (v0.z - mu) * rstd * g0.z + b0.z;
    h[3] = (v0.w - mu) * rstd * g0.w + b0.w;
    h[4] = (v1.x - mu) * rstd * g1.x + b1.x;
    h[5] = (v1.y - mu) * rstd * g1.y + b1.y;
    h[6] = (v1.z - mu) * rstd * g1.z + b1.z;
    h[7] = (v1.w - mu) * rstd * g1.w + b1.w;
    const int q8 = ((t >> 1) & 3) * 8;
    ushort4 H0, H1;
    H0.x = f2bf_rne(h[0]); H0.y = f2bf_rne(h[1]);
    H0.z = f2bf_rne(h[2]); H0.w = f2bf_rne(h[3]);
    H1.x = f2bf_rne(h[4]); H1.y = f2bf_rne(h[5]);
    H1.z = f2bf_rne(h[6]); H1.w = f2bf_rne(h[7]);
    unsigned short* pa = Ahi + (size_t)t * RIN;
    const int dst = (lane >> 2) * 32 + (((lane & 3) * 8) ^ q8);
    *(ushort4*)&pa[dst] = H0;  *(ushort4*)&pa[dst + 4] = H1;
    const float fv = feat[(size_t)t * FFEAT + lane];
    const int fd = DMODEL + (lane & 32) + ((lane & 31) ^ q8);
    pa[fd] = f2bf_rne(fv);
    float* orow = out + (size_t)t * DMODEL;
    ((float4*)orow)[lane * 2 + 0] = v0;
    ((float4*)orow)[lane * 2 + 1] = v1;
}

// ---------- fold kernels ----------
__global__ __launch_bounds__(128) void k_fold_ps(
    const float* __restrict__ stageW, const float* __restrict__ stageb,
    const float* __restrict__ psW1, const float* __restrict__ psb1,
    float* __restrict__ Dps, float* __restrict__ fbps)
{
    const int g = blockIdx.x, f = blockIdx.y, c = threadIdx.x;
    const float* Wt = psW1 + (size_t)g * RIN * DRH + (size_t)DMODEL * DRH;
    float acc = 0.f;
    if (f < 64) {
        for (int j = 0; j < DFEMB; ++j) acc = fmaf(stageW[f * DFEMB + j], Wt[(size_t)j * DRH + c], acc);
        Dps[((size_t)g * 64 + f) * DRH + c] = acc;
    } else {
        for (int j = 0; j < DFEMB; ++j) acc = fmaf(stageb[j], Wt[(size_t)j * DRH + c], acc);
        fbps[g * DRH + c] = acc + psb1[g * DRH + c];
    }
}

__global__ __launch_bounds__(128) void k_fold_ir(
    const float* __restrict__ gfW, const float* __restrict__ gfb,
    const float* __restrict__ irW1, const float* __restrict__ irb1,
    float* __restrict__ Cir, float* __restrict__ fbir)
{
    const int g = blockIdx.x, f = blockIdx.y, c = threadIdx.x;
    const float* Wt = irW1 + (size_t)g * RIN * DRH + (size_t)DMODEL * DRH;
    float acc = 0.f;
    if (f < 8) {
        for (int j = 0; j < DFEMB; ++j) acc = fmaf(gfW[(size_t)(g * 8 + f) * DFEMB + j], Wt[(size_t)j * DRH + c], acc);
        Cir[((size_t)g * 8 + f) * DRH + c] = acc;
    } else {
        for (int j = 0; j < DFEMB; ++j) acc = fmaf(gfb[g * DFEMB + j], Wt[(size_t)j * DRH + c], acc);
        fbir[g * DRH + c] = acc + irb1[g * DRH + c];
    }
}

// ---------- transpose + bf16, swizzled dest: in[K][N] -> out[N][K'] ----------
__global__ __launch_bounds__(256) void k_bsplitT(
    const float* __restrict__ in, unsigned short* __restrict__ outHi,
    int K, int N, int outStride, int kOff, long inBS, long outBS)
{
    __shared__ float s_t[32][33];
    const int b = blockIdx.y;
    const int tilesN = N >> 5;
    const int ko = (blockIdx.x / tilesN) << 5;
    const int no = (blockIdx.x % tilesN) << 5;
    const int r = threadIdx.x >> 3, c0 = (threadIdx.x & 7) * 4;
    {
        float4 v = *(const float4*)(in + (size_t)b * inBS + (size_t)(ko + r) * N + no + c0);
        s_t[r][c0] = v.x; s_t[r][c0 + 1] = v.y; s_t[r][c0 + 2] = v.z; s_t[r][c0 + 3] = v.w;
    }
    __syncthreads();
    float vv[4];
    #pragma unroll
    for (int j = 0; j < 4; ++j) vv[j] = s_t[c0 + j][r];
    const int col = no + r;
    const int q8 = ((col >> 1) & 3) * 8;
    ushort4 hi;
    hi.x = f2bf_rne(vv[0]); hi.y = f2bf_rne(vv[1]);
    hi.z = f2bf_rne(vv[2]); hi.w = f2bf_rne(vv[3]);
    *(ushort4*)(outHi + (size_t)b * outBS + (size_t)col * outStride + kOff + ko + (c0 ^ q8)) = hi;
}

// ---------- ir tail rows of B ----------
__global__ __launch_bounds__(128) void k_irtail(
    const float* __restrict__ Cir, unsigned short* __restrict__ Bhi)
{
    const int g = blockIdx.x, c = threadIdx.x;
    const int col = 1024 + g * DRH + c;
    const int q8 = ((col >> 1) & 3) * 8;
    unsigned short* ph = Bhi + (size_t)col * RIN + DMODEL;
    for (int f = 0; f < 64; ++f) {
        float v = ((f >> 3) == g) ? Cir[((size_t)g * 8 + (f & 7)) * DRH + c] : 0.f;
        const int d = (f & 32) + ((f & 31) ^ q8);
        ph[d] = f2bf_rne(v);
    }
}

// ---------- Kernel 2: router GEMM [16384x576]@[576x2048], single-pass bf16 ----------
__global__ __launch_bounds__(512) void k_rgemm(
    const unsigned short* __restrict__ Ahi, const unsigned short* __restrict__ Bhi,
    const float* __restrict__ fbps, const float* __restrict__ psW2, const float* __restrict__ psb2,
    const float* __restrict__ fbir, const float* __restrict__ irW2, const float* __restrict__ irb2,
    float* __restrict__ glog, float* __restrict__ ilog)
{
    __shared__ unsigned short sAh[128 * 32];
    __shared__ unsigned short sBh[256 * 32];
    __shared__ float s_red[2][4][64][2];

    const int tid = threadIdx.x, lane = tid & 63, w = tid >> 6;
    const int t0 = blockIdx.x * 128, bn = blockIdx.y;
    const int wm = w >> 2, wn = w & 3;
    const int arow = lane & 15, koff = (lane >> 4) * 8;
    const int q8r = ((arow >> 1) & 3) * 8;

    int aoff[4], boff[4];
    #pragma unroll
    for (int m = 0; m < 4; ++m) aoff[m] = (wm * 64 + m * 16 + arow) * 32 + (koff ^ q8r);
    #pragma unroll
    for (int n = 0; n < 4; ++n) boff[n] = (wn * 64 + n * 16 + arow) * 32 + (koff ^ q8r);

    const int srow = w * 16 + (lane >> 2);
    const int sgr = (lane & 3) * 8;
    const unsigned short* gAh = Ahi + (size_t)(t0 + srow) * RIN + sgr;
    const unsigned short* gBh0 = Bhi + (size_t)(bn * 256 + w * 32 + (lane >> 2)) * RIN + sgr;
    const unsigned short* gBh1 = gBh0 + (size_t)16 * RIN;
    unsigned short* dAh = sAh + w * 512;
    unsigned short* dBh0 = sBh + w * 1024;
    unsigned short* dBh1 = sBh + w * 1024 + 512;

    f32x4 acc[4][4];
    #pragma unroll
    for (int m = 0; m < 4; ++m)
        #pragma unroll
        for (int n = 0; n < 4; ++n) { acc[m][n].x = 0.f; acc[m][n].y = 0.f; acc[m][n].z = 0.f; acc[m][n].w = 0.f; }

    for (int kt = 0; kt < 18; ++kt) {
        const int kk = kt * 32;
        gl_lds16(gAh + kk, dAh);
        gl_lds16(gBh0 + kk, dBh0);
        gl_lds16(gBh1 + kk, dBh1);
        __syncthreads();
        bf16x8 ah[4];
        #pragma unroll
        for (int m = 0; m < 4; ++m) ah[m] = *(const bf16x8*)&sAh[aoff[m]];
        #pragma unroll
        for (int n = 0; n < 4; ++n) {
            bf16x8 b = *(const bf16x8*)&sBh[boff[n]];
            #pragma unroll
            for (int m = 0; m < 4; ++m) acc[m][n] = MFMA16(ah[m], b, acc[m][n]);
        }
        __syncthreads();
    }

    // fused second layers
    const int grp = wn >> 1;
    const bool isPS = (bn < 4);
    const int g = isPS ? (bn * 2 + grp) : ((bn - 4) * 2 + grp);
    const int q = lane >> 4;
    if (isPS) {
        float r0[4][4] = {};
        #pragma unroll
        for (int n = 0; n < 4; ++n) {
            const int cg = (wn & 1) * 64 + n * 16 + arow;
            const float b1 = fbps[g * DRH + cg];
            const float w2 = psW2[g * DRH + cg];
            #pragma unroll
            for (int m = 0; m < 4; ++m)
                #pragma unroll
                for (int j = 0; j < 4; ++j)
                    r0[m][j] += gelu_f(acc[m][n][j] + b1) * w2;
        }
        #pragma unroll
        for (int mk = 1; mk < 16; mk <<= 1)
            #pragma unroll
            for (int m = 0; m < 4; ++m)
                #pragma unroll
                for (int j = 0; j < 4; ++j) r0[m][j] += __shfl_xor(r0[m][j], mk);
        if (arow == 0) {
            #pragma unroll
            for (int m = 0; m < 4; ++m)
                #pragma unroll
                for (int j = 0; j < 4; ++j) {
                    s_red[wm][wn][m * 16 + q * 4 + j][0] = r0[m][j];
                    s_red[wm][wn][m * 16 + q * 4 + j][1] = 0.f;
                }
        }
    } else {
        float r0[4][4] = {}, r1[4][4] = {};
        #pragma unroll
        for (int n = 0; n < 4; ++n) {
            const int cg = (wn & 1) * 64 + n * 16 + arow;
            const float b1 = fbir[g * DRH + cg];
            const float w20 = irW2[(size_t)(g * DRH + cg) * NES + 0];
            const float w21 = irW2[(size_t)(g * DRH + cg) * NES + 1];
            #pragma unroll
            for (int m = 0; m < 4; ++m)
                #pragma unroll
                for (int j = 0; j < 4; ++j) {
                    const float v = gelu_f(acc[m][n][j] + b1);
                    r0[m][j] = fmaf(v, w20, r0[m][j]);
                    r1[m][j] = fmaf(v, w21, r1[m][j]);
                }
        }
        #pragma unroll
        for (int mk = 1; mk < 16; mk <<= 1)
            #pragma unroll
            for (int m = 0; m < 4; ++m)
                #pragma unroll
                for (int j = 0; j < 4; ++j) {
                    r0[m][j] += __shfl_xor(r0[m][j], mk);
                    r1[m][j] += __shfl_xor(r1[m][j], mk);
                }
        if (arow == 0) {
            #pragma unroll
            for (int m = 0; m < 4; ++m)
                #pragma unroll
                for (int j = 0; j < 4; ++j) {
                    s_red[wm][wn][m * 16 + q * 4 + j][0] = r0[m][j];
                    s_red[wm][wn][m * 16 + q * 4 + j][1] = r1[m][j];
                }
        }
    }
    __syncthreads();
    if (tid < 256) {
        const int row = tid >> 1, sub = tid & 1;
        const int rl = row & 63, wmm = row >> 6;
        if (isPS) {
            const int gg = bn * 2 + sub;
            glog[(size_t)(t0 + row) * NG + gg] =
                s_red[wmm][sub * 2][rl][0] + s_red[wmm][sub * 2 + 1][rl][0] + psb2[gg];
        } else {
            const int gg = (bn - 4) * 2 + sub;
            const size_t bidx = ((size_t)(t0 + row) * NG + gg) * NES;
            ilog[bidx + 0] = s_red[wmm][sub * 2][rl][0] + s_red[wmm][sub * 2 + 1][rl][0] + irb2[gg * NES + 0];
            ilog[bidx + 1] = s_red[wmm][sub * 2][rl][1] + s_red[wmm][sub * 2 + 1][rl][1] + irb2[gg * NES + 1];
        }
    }
}

// ---------- Kernel 2b: finalize with margin check ----------
#define MARGIN 2.5e-2f
__global__ __launch_bounds__(256) void hg_finalize2(
    const float* __restrict__ glog_buf, const float* __restrict__ ilog_buf,
    int* __restrict__ counts, int* __restrict__ nfix, int* __restrict__ fix_list,
    int* __restrict__ list_tok, float* __restrict__ list_w)
{
    const int t = blockIdx.x * 256 + threadIdx.x;
    float gl[NG];
    *(float4*)&gl[0] = ((const float4*)(glog_buf + (size_t)t * NG))[0];
    *(float4*)&gl[4] = ((const float4*)(glog_buf + (size_t)t * NG))[1];
    int i1 = 0; float m1 = gl[0];
    #pragma unroll
    for (int g = 1; g < NG; ++g) if (gl[g] > m1) { m1 = gl[g]; i1 = g; }
    int i2 = -1; float m2 = -3.4e38f;
    #pragma unroll
    for (int g = 0; g < NG; ++g) if (g != i1 && gl[g] > m2) { m2 = gl[g]; i2 = g; }
    float m3 = -3.4e38f;
    #pragma unroll
    for (int g = 0; g < NG; ++g) if (g != i1 && g != i2 && gl[g] > m3) m3 = gl[g];

    const float ila0 = ilog_buf[((size_t)t * NG + i1) * NES + 0];
    const float ila1 = ilog_buf[((size_t)t * NG + i1) * NES + 1];
    const float ilb0 = ilog_buf[((size_t)t * NG + i2) * NES + 0];
    const float ilb1 = ilog_buf[((size_t)t * NG + i2) * NES + 1];

    const bool flag = ((m2 - m3) < MARGIN) || (fabsf(ila1 - ila0) < MARGIN)
                   || (fabsf(ilb1 - ilb0) < MARGIN);
    if (flag) {
        const int p = atomicAdd(nfix, 1);
        fix_list[p] = t;
        return;
    }
    const float ex = expf(m2 - m1);
    const float inv = 1.0f / (1.0f + ex);
    const int   gsel[2] = {i1, i2};
    const float wsel[2] = {inv, ex * inv};
    const int   ksel[2] = {(ila1 > ila0) ? 1 : 0, (ilb1 > ilb0) ? 1 : 0};
    #pragma unroll
    for (int s = 0; s < 2; ++s) {
        const int eid = gsel[s] * NES + ksel[s];
        const int pos = atomicAdd(&counts[eid], 1);
        list_tok[(size_t)eid * T_TOKENS + pos] = t;
        list_w[(size_t)eid * T_TOKENS + pos] = wsel[s];
    }
}

// ---------- Kernel 2c: exact fp32 fixup, 4-wave parallel per token ----------
__global__ __launch_bounds__(256) void hg_fixup(
    const float* __restrict__ hidden, const float* __restrict__ feat,
    const float* __restrict__ lng, const float* __restrict__ lnb,
    const float* __restrict__ stageW, const float* __restrict__ stageb,
    const float* __restrict__ gfW, const float* __restrict__ gfb,
    const float* __restrict__ psW1, const float* __restrict__ psb1,
    const float* __restrict__ psW2, const float* __restrict__ psb2,
    const float* __restrict__ irW1, const float* __restrict__ irb1,
    const float* __restrict__ irW2, const float* __restrict__ irb2,
    const int* __restrict__ nfix, const int* __restrict__ fix_list,
    int* __restrict__ counts, int* __restrict__ list_tok, float* __restrict__ list_w)
{
    __shared__ float s_rin[RIN];
    __shared__ float s_tail[2][DFEMB];
    __shared__ float s_gl[NG];
    __shared__ float s_part[4][2];
    __shared__ int s_sel[2];
    __shared__ float s_wsel[2];

    const int tid = threadIdx.x, lane = tid & 63, w = tid >> 6;
    const int nf = nfix[0];
    for (int idx = blockIdx.x; idx < nf; idx += gridDim.x) {
        const int t = fix_list[idx];
        if (w == 0) {
            const float* row = hidden + (size_t)t * DMODEL;
            float4 v0 = ((const float4*)row)[lane * 2 + 0];
            float4 v1 = ((const float4*)row)[lane * 2 + 1];
            float s = v0.x + v0.y + v0.z + v0.w + v1.x + v1.y + v1.z + v1.w;
            #pragma unroll
            for (int m = 1; m < 64; m <<= 1) s += __shfl_xor(s, m);
            const float mu = s * (1.0f / DMODEL);
            float sq = 0.f;
            { float d;
              d = v0.x - mu; sq += d * d; d = v0.y - mu; sq += d * d;
              d = v0.z - mu; sq += d * d; d = v0.w - mu; sq += d * d;
              d = v1.x - mu; sq += d * d; d = v1.y - mu; sq += d * d;
              d = v1.z - mu; sq += d * d; d = v1.w - mu; sq += d * d; }
            #pragma unroll
            for (int m = 1; m < 64; m <<= 1) sq += __shfl_xor(sq, m);
            const float rstd = rsqrtf(sq * (1.0f / DMODEL) + 1e-5f);
            float4 g0 = ((const float4*)lng)[lane * 2 + 0];
            float4 g1 = ((const float4*)lng)[lane * 2 + 1];
            float4 b0 = ((const float4*)lnb)[lane * 2 + 0];
            float4 b1 = ((const float4*)lnb)[lane * 2 + 1];
            s_rin[lane * 8 + 0] = (v0.x - mu) * rstd * g0.x + b0.x;
            s_rin[lane * 8 + 1] = (v0.y - mu) * rstd * g0.y + b0.y;
            s_rin[lane * 8 + 2] = (v0.z - mu) * rstd * g0.z + b0.z;
            s_rin[lane * 8 + 3] = (v0.w - mu) * rstd * g0.w + b0.w;
            s_rin[lane * 8 + 4] = (v1.x - mu) * rstd * g1.x + b1.x;
            s_rin[lane * 8 + 5] = (v1.y - mu) * rstd * g1.y + b1.y;
            s_rin[lane * 8 + 6] = (v1.z - mu) * rstd * g1.z + b1.z;
            s_rin[lane * 8 + 7] = (v1.w - mu) * rstd * g1.w + b1.w;
        } else if (w == 1) {
            float se = stageb[lane];
            for (int f = 0; f < FFEAT; ++f)
                se = fmaf(feat[(size_t)t * FFEAT + f], stageW[f * DFEMB + lane], se);
            s_rin[DMODEL + lane] = se;
        }
        __syncthreads();

        // glog: wave w -> groups 2w, 2w+1 (lane owns cols lane, 64+lane)
        #pragma unroll
        for (int gi = 0; gi < 2; ++gi) {
            const int g = w * 2 + gi;
            float a0 = psb1[g * DRH + lane];
            float a1 = psb1[g * DRH + 64 + lane];
            const float* W = psW1 + (size_t)g * RIN * DRH;
            for (int k = 0; k < RIN; ++k) {
                const float r = s_rin[k];
                a0 = fmaf(r, W[(size_t)k * DRH + lane], a0);
                a1 = fmaf(r, W[(size_t)k * DRH + 64 + lane], a1);
            }
            float p = gelu_f(a0) * psW2[g * DRH + lane] + gelu_f(a1) * psW2[g * DRH + 64 + lane];
            #pragma unroll
            for (int m = 1; m < 64; m <<= 1) p += __shfl_xor(p, m);
            if (lane == 0) s_gl[g] = p + psb2[g];
        }
        __syncthreads();

        if (tid == 0) {
            int i1 = 0; float m1 = s_gl[0];
            #pragma unroll
            for (int g = 1; g < NG; ++g) if (s_gl[g] > m1) { m1 = s_gl[g]; i1 = g; }
            int i2 = -1; float m2 = -3.4e38f;
            #pragma unroll
            for (int g = 0; g < NG; ++g) if (g != i1 && s_gl[g] > m2) { m2 = s_gl[g]; i2 = g; }
            const float ex = expf(m2 - m1);
            const float inv = 1.0f / (1.0f + ex);
            s_sel[0] = i1; s_sel[1] = i2;
            s_wsel[0] = inv; s_wsel[1] = ex * inv;
        }
        __syncthreads();

        const int pr = w >> 1;          // selected-group pair index
        const int gsel = s_sel[pr];
        if ((w & 1) == 0) {             // waves 0,2 compute gemb for their pair
            float ge = gfb[gsel * DFEMB + lane];
            #pragma unroll
            for (int f = 0; f < 8; ++f)
                ge = fmaf(feat[(size_t)t * FFEAT + gsel * 8 + f],
                          gfW[(size_t)(gsel * 8 + f) * DFEMB + lane], ge);
            s_tail[pr][lane] = ge;
        }
        __syncthreads();

        {
            const int col = (w & 1) * 64 + lane;
            float a = irb1[gsel * DRH + col];
            const float* W = irW1 + (size_t)gsel * RIN * DRH + col;
            for (int k = 0; k < DMODEL; ++k)
                a = fmaf(s_rin[k], W[(size_t)k * DRH], a);
            for (int k = 0; k < DFEMB; ++k)
                a = fmaf(s_tail[pr][k], W[(size_t)(DMODEL + k) * DRH], a);
            const float v = gelu_f(a);
            float e0 = v * irW2[(size_t)(gsel * DRH + col) * NES + 0];
            float e1 = v * irW2[(size_t)(gsel * DRH + col) * NES + 1];
            #pragma unroll
            for (int m = 1; m < 64; m <<= 1) {
                e0 += __shfl_xor(e0, m);
                e1 += __shfl_xor(e1, m);
            }
            if (lane == 0) { s_part[w][0] = e0; s_part[w][1] = e1; }
        }
        __syncthreads();

        if (tid == 0) {
            #pragma unroll
            for (int p2 = 0; p2 < 2; ++p2) {
                const float e0 = s_part[p2 * 2][0] + s_part[p2 * 2 + 1][0];
                const float e1 = s_part[p2 * 2][1] + s_part[p2 * 2 + 1][1];
                const int eid = s_sel[p2] * NES + ((e1 > e0) ? 1 : 0);
                const int pos = atomicAdd(&counts[eid], 1);
                list_tok[(size_t)eid * T_TOKENS + pos] = t;
                list_w[(size_t)eid * T_TOKENS + pos] = s_wsel[p2];
            }
        }
        __syncthreads();
    }
}

// ---------- Kernel 3: experts ----------
__global__ __launch_bounds__(256) void k_expert(
    const unsigned short* __restrict__ Ahi,
    const unsigned short* __restrict__ eW1T, const float* __restrict__ eb1,
    const unsigned short* __restrict__ eW2T, const float* __restrict__ eb2,
    const float* __restrict__ alpha_p,
    const int* __restrict__ counts, const int* __restrict__ list_tok,
    const float* __restrict__ list_w, float* __restrict__ out)
{
    __shared__ char smem[65536];
    unsigned short* sEH = (unsigned short*)smem;
    unsigned short* sA  = (unsigned short*)(smem + 32768);
    unsigned short* sB1 = (unsigned short*)(smem + 36864);
    unsigned short* sB2 = (unsigned short*)(smem + 32768);
    __shared__ int s_tok[64];
    __shared__ float s_w[64];

    const int e = blockIdx.y;
    const int cnt = counts[e];
    const int base = blockIdx.x * 64;
    if (base >= cnt) return;
    const int nrow = min(64, cnt - base);
    const int tid = threadIdx.x, lane = tid & 63, w = tid >> 6;

    if (tid < 64) {
        const int src = base + ((tid < nrow) ? tid : (nrow - 1));
        s_tok[tid] = list_tok[(size_t)e * T_TOKENS + src];
        s_w[tid] = (tid < nrow) ? list_w[(size_t)e * T_TOKENS + base + tid] : 0.f;
    }
    __syncthreads();

    const int srow = w * 16 + (lane >> 2);
    const int stok = s_tok[srow];
    const int qcor = ((srow >> 1) & 3) ^ ((stok >> 1) & 3);
    const unsigned short* gA = Ahi + (size_t)stok * RIN + 8 * ((lane & 3) ^ qcor);
    unsigned short* dA = sA + w * 512;
    const int sgr = (lane & 3) * 8;
    const unsigned short* gB1[4];
    #pragma unroll
    for (int i = 0; i < 4; ++i)
        gB1[i] = eW1T + (size_t)e * DHID * DMODEL + (size_t)(w * 64 + i * 16 + (lane >> 2)) * DMODEL + sgr;

    const int arow = lane & 15, koff = (lane >> 4) * 8;
    const int q8r = ((arow >> 1) & 3) * 8;
    int aoff[4], b1off[4];
    #pragma unroll
    for (int m = 0; m < 4; ++m) aoff[m] = (m * 16 + arow) * 32 + (koff ^ q8r);
    #pragma unroll
    for (int n = 0; n < 4; ++n) b1off[n] = (w * 64 + n * 16 + arow) * 32 + (koff ^ q8r);

    f32x4 acc1[4][4];
    #pragma unroll
    for (int m = 0; m < 4; ++m)
        #pragma unroll
        for (int n = 0; n < 4; ++n) { acc1[m][n].x = 0.f; acc1[m][n].y = 0.f; acc1[m][n].z = 0.f; acc1[m][n].w = 0.f; }

    for (int kt = 0; kt < 16; ++kt) {
        const int kk = kt * 32;
        gl_lds16(gA + kk, dA);
        #pragma unroll
        for (int i = 0; i < 4; ++i) gl_lds16(gB1[i] + kk, sB1 + w * 2048 + i * 512);
        __syncthreads();
        bf16x8 a[4];
        #pragma unroll
        for (int m = 0; m < 4; ++m) a[m] = *(const bf16x8*)&sA[aoff[m]];
        #pragma unroll
        for (int n = 0; n < 4; ++n) {
            bf16x8 b = *(const bf16x8*)&sB1[b1off[n]];
            #pragma unroll
            for (int m = 0; m < 4; ++m) acc1[m][n] = MFMA16(a[m], b, acc1[m][n]);
        }
        __syncthreads();
    }

    const int q = lane >> 4;
    #pragma unroll
    for (int m = 0; m < 4; ++m)
        #pragma unroll
        for (int n = 0; n < 4; ++n) {
            const int col = w * 64 + n * 16 + arow;
            const float bv = eb1[e * DHID + col];
            #pragma unroll
            for (int j = 0; j < 4; ++j) {
                const int rr = m * 16 + q * 4 + j;
                const int d = rr * 256 + (col & 0xE0) + ((col & 31) ^ (((rr >> 1) & 3) * 8));
                sEH[d] = f2bf_rne(gelu_f(acc1[m][n][j] + bv));
            }
        }
    __syncthreads();

    const unsigned short* gB2[8];
    #pragma unroll
    for (int i = 0; i < 8; ++i)
        gB2[i] = eW2T + (size_t)e * DMODEL * DHID + (size_t)(w * 128 + i * 16 + (lane >> 2)) * DHID + sgr;
    int a2base[4], b2off[8];
    #pragma unroll
    for (int m = 0; m < 4; ++m) a2base[m] = (m * 16 + arow) * 256 + (koff ^ q8r);
    #pragma unroll
    for (int n = 0; n < 8; ++n) b2off[n] = (w * 128 + n * 16 + arow) * 32 + (koff ^ q8r);

    f32x4 acc2[4][8];
    #pragma unroll
    for (int m = 0; m < 4; ++m)
        #pragma unroll
        for (int n = 0; n < 8; ++n) { acc2[m][n].x = 0.f; acc2[m][n].y = 0.f; acc2[m][n].z = 0.f; acc2[m][n].w = 0.f; }

    for (int kt = 0; kt < 8; ++kt) {
        #pragma unroll
        for (int i = 0; i < 8; ++i) gl_lds16(gB2[i] + kt * 32, sB2 + w * 4096 + i * 512);
        __syncthreads();
        bf16x8 a[4];
        #pragma unroll
        for (int m = 0; m < 4; ++m) a[m] = *(const bf16x8*)&sEH[a2base[m] + kt * 32];
        #pragma unroll
        for (int n = 0; n < 8; ++n) {
            bf16x8 b = *(const bf16x8*)&sB2[b2off[n]];
            #pragma unroll
            for (int m = 0; m < 4; ++m) acc2[m][n] = MFMA16(a[m], b, acc2[m][n]);
        }
        __syncthreads();
    }

    const float alpha = alpha_p[0];
    #pragma unroll
    for (int m = 0; m < 4; ++m)
        #pragma unroll
        for (int n = 0; n < 8; ++n) {
            const int col = w * 128 + n * 16 + arow;
            const float b2v = eb2[e * DMODEL + col];
            #pragma unroll
            for (int j = 0; j < 4; ++j) {
                const int r = m * 16 + q * 4 + j;
                if (r < nrow)
                    atomicAdd(out + (size_t)s_tok[r] * DMODEL + col,
                              s_w[r] * alpha * (acc2[m][n][j] + b2v));
            }
        }
}

// ---------- launch ----------
extern "C" void kernel_launch(void* const* d_in, const int* in_sizes, int n_in,
                              void* d_out, int out_size, void* d_ws, size_t ws_size,
                              hipStream_t stream) {
    const float* hidden = (const float*)d_in[0];
    const float* feat   = (const float*)d_in[1];
    const float* ln_g   = (const float*)d_in[2];
    const float* ln_b   = (const float*)d_in[3];
    const float* stageW = (const float*)d_in[4];
    const float* stageb = (const float*)d_in[5];
    const float* gfW    = (const float*)d_in[6];
    const float* gfb    = (const float*)d_in[7];
    const float* psW1   = (const float*)d_in[8];
    const float* psb1   = (const float*)d_in[9];
    const float* psW2   = (const float*)d_in[10];
    const float* psb2   = (const float*)d_in[11];
    const float* irW1   = (const float*)d_in[12];
    const float* irb1   = (const float*)d_in[13];
    const float* irW2   = (const float*)d_in[14];
    const float* irb2   = (const float*)d_in[15];
    const float* eW1    = (const float*)d_in[16];
    const float* eb1    = (const float*)d_in[17];
    const float* eW2    = (const float*)d_in[18];
    const float* eb2    = (const float*)d_in[19];
    const float* alpha  = (const float*)d_in[20];

    float* out = (float*)d_out;

    char* p = (char*)d_ws;
    unsigned short* Ahi = (unsigned short*)p; p += (size_t)T_TOKENS * RIN * 2;
    unsigned short* Bhi = (unsigned short*)p; p += (size_t)2048 * RIN * 2;
    unsigned short* eW1T = (unsigned short*)p; p += (size_t)NE * DHID * DMODEL * 2;
    unsigned short* eW2T = (unsigned short*)p; p += (size_t)NE * DMODEL * DHID * 2;
    float* Dps = (float*)p;   p += (size_t)NG * 64 * DRH * 4;
    float* Cir = (float*)p;   p += (size_t)NG * 8 * DRH * 4;
    float* fbps = (float*)p;  p += (size_t)NG * DRH * 4;
    float* fbir = (float*)p;  p += (size_t)NG * DRH * 4;
    float* glog_buf = (float*)p; p += (size_t)T_TOKENS * NG * 4;
    float* ilog_buf = (float*)p; p += (size_t)T_TOKENS * NG * NES * 4;
    int* counts = (int*)p;    p += 128;
    int* nfix = counts + 16;
    int* fix_list = (int*)p;  p += (size_t)T_TOKENS * 4;
    int* list_tok = (int*)p;  p += (size_t)NE * T_TOKENS * 4;
    float* list_w = (float*)p; p += (size_t)NE * T_TOKENS * 4;

    hipMemsetAsync(counts, 0, 128, stream);

    k_prep<<<T_TOKENS / 4, 256, 0, stream>>>(hidden, feat, ln_g, ln_b, Ahi, out);

    k_fold_ps<<<dim3(NG, 65), 128, 0, stream>>>(stageW, stageb, psW1, psb1, Dps, fbps);
    k_fold_ir<<<dim3(NG, 9), 128, 0, stream>>>(gfW, gfb, irW1, irb1, Cir, fbir);

    k_bsplitT<<<dim3(64, NG), 256, 0, stream>>>(
        psW1, Bhi, 512, DRH, RIN, 0, (long)RIN * DRH, (long)DRH * RIN);
    k_bsplitT<<<dim3(64, NG), 256, 0, stream>>>(
        irW1, Bhi + (size_t)1024 * RIN, 512, DRH, RIN, 0, (long)RIN * DRH, (long)DRH * RIN);
    k_bsplitT<<<dim3(8, NG), 256, 0, stream>>>(
        Dps, Bhi, 64, DRH, RIN, 512, (long)64 * DRH, (long)DRH * RIN);
    k_irtail<<<NG, 128, 0, stream>>>(Cir, Bhi);

    k_bsplitT<<<dim3(128, NE), 256, 0, stream>>>(
        eW1, eW1T, DMODEL, DHID, DMODEL, 0, (long)DMODEL * DHID, (long)DHID * DMODEL);
    k_bsplitT<<<dim3(128, NE), 256, 0, stream>>>(
        eW2, eW2T, DHID, DMODEL, DHID, 0, (long)DHID * DMODEL, (long)DMODEL * DHID);

    k_rgemm<<<dim3(T_TOKENS / 128, 8), 512, 0, stream>>>(
        Ahi, Bhi, fbps, psW2, psb2, fbir, irW2, irb2, glog_buf, ilog_buf);

    hg_finalize2<<<T_TOKENS / 256, 256, 0, stream>>>(
        glog_buf, ilog_buf, counts, nfix, fix_list, list_tok, list_w);

    hg_fixup<<<1024, 256, 0, stream>>>(
        hidden, feat, ln_g, ln_b, stageW, stageb, gfW, gfb,
        psW1, psb1, psW2, psb2, irW1, irb1, irW2, irb2,
        nfix, fix_list, counts, list_tok, list_w);

    k_expert<<<dim3(T_TOKENS / 64, NE), 256, 0, stream>>>(
        Ahi, eW1T, eb1, eW2T, eb2, alpha, counts, list_tok, list_w, out);
}

// Round 6
// 523.923 us; speedup vs baseline: 4.2240x; 1.2480x over previous
//
#include <hip/hip_runtime.h>
#include <hip/hip_bf16.h>

#define T_TOKENS 16384
#define DMODEL 512
#define FFEAT 64
#define DFEMB 64
#define RIN 576
#define DRH 128
#define NG 8
#define NES 2
#define NE 16
#define DHID 256

typedef float f32x4 __attribute__((ext_vector_type(4)));
typedef _Float16 f16x8 __attribute__((ext_vector_type(8)));
#define MFMA16F(a, b, c) __builtin_amdgcn_mfma_f32_16x16x32_f16((a), (b), (c), 0, 0, 0)

__device__ __forceinline__ float gelu_f(float x) {
    return 0.5f * x * (1.0f + erff(x * 0.7071067811865476f));
}
__device__ __forceinline__ unsigned short f2h(float x) {
    _Float16 h = (_Float16)x;
    union { _Float16 f; unsigned short u; } v; v.f = h;
    return v.u;
}
__device__ __forceinline__ void gl_lds16(const unsigned short* g, unsigned short* l) {
    __builtin_amdgcn_global_load_lds(
        (const __attribute__((address_space(1))) unsigned int*)g,
        (__attribute__((address_space(3))) unsigned int*)l, 16, 0, 0);
}

// ---------- Kernel 1: LN + fp16 swizzled A + out = hidden ----------
__global__ __launch_bounds__(256) void k_prep(
    const float* __restrict__ hidden, const float* __restrict__ feat,
    const float* __restrict__ lng, const float* __restrict__ lnb,
    unsigned short* __restrict__ Ahi, float* __restrict__ out)
{
    const int t = blockIdx.x * 4 + (threadIdx.x >> 6);
    const int lane = threadIdx.x & 63;
    const float* row = hidden + (size_t)t * DMODEL;
    float4 v0 = ((const float4*)row)[lane * 2 + 0];
    float4 v1 = ((const float4*)row)[lane * 2 + 1];
    float s = v0.x + v0.y + v0.z + v0.w + v1.x + v1.y + v1.z + v1.w;
    #pragma unroll
    for (int m = 1; m < 64; m <<= 1) s += __shfl_xor(s, m);
    const float mu = s * (1.0f / DMODEL);
    float sq = 0.f;
    { float d;
      d = v0.x - mu; sq += d * d; d = v0.y - mu; sq += d * d;
      d = v0.z - mu; sq += d * d; d = v0.w - mu; sq += d * d;
      d = v1.x - mu; sq += d * d; d = v1.y - mu; sq += d * d;
      d = v1.z - mu; sq += d * d; d = v1.w - mu; sq += d * d; }
    #pragma unroll
    for (int m = 1; m < 64; m <<= 1) sq += __shfl_xor(sq, m);
    const float rstd = rsqrtf(sq * (1.0f / DMODEL) + 1e-5f);
    float4 g0 = ((const float4*)lng)[lane * 2 + 0];
    float4 g1 = ((const float4*)lng)[lane * 2 + 1];
    float4 b0 = ((const float4*)lnb)[lane * 2 + 0];
    float4 b1 = ((const float4*)lnb)[lane * 2 + 1];
    float h[8];
    h[0] = (v0.x - mu) * rstd * g0.x + b0.x;
    h[1] = (v0.y - mu) * rstd * g0.y + b0.y;
    h[2] = (v0.z - mu) * rstd * g0.z + b0.z;
    h[3] = (v0.w - mu) * rstd * g0.w + b0.w;
    h[4] = (v1.x - mu) * rstd * g1.x + b1.x;
    h[5] = (v1.y - mu) * rstd * g1.y + b1.y;
    h[6] = (v1.z - mu) * rstd * g1.z + b1.z;
    h[7] = (v1.w - mu) * rstd * g1.w + b1.w;
    const int q8 = ((t >> 1) & 3) * 8;
    ushort4 H0, H1;
    H0.x = f2h(h[0]); H0.y = f2h(h[1]); H0.z = f2h(h[2]); H0.w = f2h(h[3]);
    H1.x = f2h(h[4]); H1.y = f2h(h[5]); H1.z = f2h(h[6]); H1.w = f2h(h[7]);
    unsigned short* pa = Ahi + (size_t)t * RIN;
    const int dst = (lane >> 2) * 32 + (((lane & 3) * 8) ^ q8);
    *(ushort4*)&pa[dst] = H0;  *(ushort4*)&pa[dst + 4] = H1;
    const float fv = feat[(size_t)t * FFEAT + lane];
    const int fd = DMODEL + (lane & 32) + ((lane & 31) ^ q8);
    pa[fd] = f2h(fv);
    float* orow = out + (size_t)t * DMODEL;
    ((float4*)orow)[lane * 2 + 0] = v0;
    ((float4*)orow)[lane * 2 + 1] = v1;
}

// ---------- fold kernels ----------
__global__ __launch_bounds__(128) void k_fold_ps(
    const float* __restrict__ stageW, const float* __restrict__ stageb,
    const float* __restrict__ psW1, const float* __restrict__ psb1,
    float* __restrict__ Dps, float* __restrict__ fbps)
{
    const int g = blockIdx.x, f = blockIdx.y, c = threadIdx.x;
    const float* Wt = psW1 + (size_t)g * RIN * DRH + (size_t)DMODEL * DRH;
    float acc = 0.f;
    if (f < 64) {
        for (int j = 0; j < DFEMB; ++j) acc = fmaf(stageW[f * DFEMB + j], Wt[(size_t)j * DRH + c], acc);
        Dps[((size_t)g * 64 + f) * DRH + c] = acc;
    } else {
        for (int j = 0; j < DFEMB; ++j) acc = fmaf(stageb[j], Wt[(size_t)j * DRH + c], acc);
        fbps[g * DRH + c] = acc + psb1[g * DRH + c];
    }
}

__global__ __launch_bounds__(128) void k_fold_ir(
    const float* __restrict__ gfW, const float* __restrict__ gfb,
    const float* __restrict__ irW1, const float* __restrict__ irb1,
    float* __restrict__ Cir, float* __restrict__ fbir)
{
    const int g = blockIdx.x, f = blockIdx.y, c = threadIdx.x;
    const float* Wt = irW1 + (size_t)g * RIN * DRH + (size_t)DMODEL * DRH;
    float acc = 0.f;
    if (f < 8) {
        for (int j = 0; j < DFEMB; ++j) acc = fmaf(gfW[(size_t)(g * 8 + f) * DFEMB + j], Wt[(size_t)j * DRH + c], acc);
        Cir[((size_t)g * 8 + f) * DRH + c] = acc;
    } else {
        for (int j = 0; j < DFEMB; ++j) acc = fmaf(gfb[g * DFEMB + j], Wt[(size_t)j * DRH + c], acc);
        fbir[g * DRH + c] = acc + irb1[g * DRH + c];
    }
}

// ---------- transpose + fp16, swizzled dest: in[K][N] -> out[N][K'] ----------
__global__ __launch_bounds__(256) void k_bsplitT(
    const float* __restrict__ in, unsigned short* __restrict__ outHi,
    int K, int N, int outStride, int kOff, long inBS, long outBS)
{
    __shared__ float s_t[32][33];
    const int b = blockIdx.y;
    const int tilesN = N >> 5;
    const int ko = (blockIdx.x / tilesN) << 5;
    const int no = (blockIdx.x % tilesN) << 5;
    const int r = threadIdx.x >> 3, c0 = (threadIdx.x & 7) * 4;
    {
        float4 v = *(const float4*)(in + (size_t)b * inBS + (size_t)(ko + r) * N + no + c0);
        s_t[r][c0] = v.x; s_t[r][c0 + 1] = v.y; s_t[r][c0 + 2] = v.z; s_t[r][c0 + 3] = v.w;
    }
    __syncthreads();
    float vv[4];
    #pragma unroll
    for (int j = 0; j < 4; ++j) vv[j] = s_t[c0 + j][r];
    const int col = no + r;
    const int q8 = ((col >> 1) & 3) * 8;
    ushort4 hi;
    hi.x = f2h(vv[0]); hi.y = f2h(vv[1]); hi.z = f2h(vv[2]); hi.w = f2h(vv[3]);
    *(ushort4*)(outHi + (size_t)b * outBS + (size_t)col * outStride + kOff + ko + (c0 ^ q8)) = hi;
}

// ---------- ir tail rows of B ----------
__global__ __launch_bounds__(128) void k_irtail(
    const float* __restrict__ Cir, unsigned short* __restrict__ Bhi)
{
    const int g = blockIdx.x, c = threadIdx.x;
    const int col = 1024 + g * DRH + c;
    const int q8 = ((col >> 1) & 3) * 8;
    unsigned short* ph = Bhi + (size_t)col * RIN + DMODEL;
    for (int f = 0; f < 64; ++f) {
        float v = ((f >> 3) == g) ? Cir[((size_t)g * 8 + (f & 7)) * DRH + c] : 0.f;
        const int d = (f & 32) + ((f & 31) ^ q8);
        ph[d] = f2h(v);
    }
}

// ---------- Kernel 2: router GEMM [16384x576]@[576x2048], fp16 single-pass ----------
__global__ __launch_bounds__(512) void k_rgemm(
    const unsigned short* __restrict__ Ahi, const unsigned short* __restrict__ Bhi,
    const float* __restrict__ fbps, const float* __restrict__ psW2, const float* __restrict__ psb2,
    const float* __restrict__ fbir, const float* __restrict__ irW2, const float* __restrict__ irb2,
    float* __restrict__ glog, float* __restrict__ ilog)
{
    __shared__ unsigned short sAh[128 * 32];
    __shared__ unsigned short sBh[256 * 32];
    __shared__ float s_red[2][4][64][2];

    const int tid = threadIdx.x, lane = tid & 63, w = tid >> 6;
    const int t0 = blockIdx.x * 128, bn = blockIdx.y;
    const int wm = w >> 2, wn = w & 3;
    const int arow = lane & 15, koff = (lane >> 4) * 8;
    const int q8r = ((arow >> 1) & 3) * 8;

    int aoff[4], boff[4];
    #pragma unroll
    for (int m = 0; m < 4; ++m) aoff[m] = (wm * 64 + m * 16 + arow) * 32 + (koff ^ q8r);
    #pragma unroll
    for (int n = 0; n < 4; ++n) boff[n] = (wn * 64 + n * 16 + arow) * 32 + (koff ^ q8r);

    const int srow = w * 16 + (lane >> 2);
    const int sgr = (lane & 3) * 8;
    const unsigned short* gAh = Ahi + (size_t)(t0 + srow) * RIN + sgr;
    const unsigned short* gBh0 = Bhi + (size_t)(bn * 256 + w * 32 + (lane >> 2)) * RIN + sgr;
    const unsigned short* gBh1 = gBh0 + (size_t)16 * RIN;
    unsigned short* dAh = sAh + w * 512;
    unsigned short* dBh0 = sBh + w * 1024;
    unsigned short* dBh1 = sBh + w * 1024 + 512;

    f32x4 acc[4][4];
    #pragma unroll
    for (int m = 0; m < 4; ++m)
        #pragma unroll
        for (int n = 0; n < 4; ++n) { acc[m][n].x = 0.f; acc[m][n].y = 0.f; acc[m][n].z = 0.f; acc[m][n].w = 0.f; }

    for (int kt = 0; kt < 18; ++kt) {
        const int kk = kt * 32;
        gl_lds16(gAh + kk, dAh);
        gl_lds16(gBh0 + kk, dBh0);
        gl_lds16(gBh1 + kk, dBh1);
        __syncthreads();
        f16x8 ah[4];
        #pragma unroll
        for (int m = 0; m < 4; ++m) ah[m] = *(const f16x8*)&sAh[aoff[m]];
        #pragma unroll
        for (int n = 0; n < 4; ++n) {
            f16x8 b = *(const f16x8*)&sBh[boff[n]];
            #pragma unroll
            for (int m = 0; m < 4; ++m) acc[m][n] = MFMA16F(ah[m], b, acc[m][n]);
        }
        __syncthreads();
    }

    // fused second layers
    const int grp = wn >> 1;
    const bool isPS = (bn < 4);
    const int g = isPS ? (bn * 2 + grp) : ((bn - 4) * 2 + grp);
    const int q = lane >> 4;
    if (isPS) {
        float r0[4][4] = {};
        #pragma unroll
        for (int n = 0; n < 4; ++n) {
            const int cg = (wn & 1) * 64 + n * 16 + arow;
            const float b1 = fbps[g * DRH + cg];
            const float w2 = psW2[g * DRH + cg];
            #pragma unroll
            for (int m = 0; m < 4; ++m)
                #pragma unroll
                for (int j = 0; j < 4; ++j)
                    r0[m][j] += gelu_f(acc[m][n][j] + b1) * w2;
        }
        #pragma unroll
        for (int mk = 1; mk < 16; mk <<= 1)
            #pragma unroll
            for (int m = 0; m < 4; ++m)
                #pragma unroll
                for (int j = 0; j < 4; ++j) r0[m][j] += __shfl_xor(r0[m][j], mk);
        if (arow == 0) {
            #pragma unroll
            for (int m = 0; m < 4; ++m)
                #pragma unroll
                for (int j = 0; j < 4; ++j) {
                    s_red[wm][wn][m * 16 + q * 4 + j][0] = r0[m][j];
                    s_red[wm][wn][m * 16 + q * 4 + j][1] = 0.f;
                }
        }
    } else {
        float r0[4][4] = {}, r1[4][4] = {};
        #pragma unroll
        for (int n = 0; n < 4; ++n) {
            const int cg = (wn & 1) * 64 + n * 16 + arow;
            const float b1 = fbir[g * DRH + cg];
            const float w20 = irW2[(size_t)(g * DRH + cg) * NES + 0];
            const float w21 = irW2[(size_t)(g * DRH + cg) * NES + 1];
            #pragma unroll
            for (int m = 0; m < 4; ++m)
                #pragma unroll
                for (int j = 0; j < 4; ++j) {
                    const float v = gelu_f(acc[m][n][j] + b1);
                    r0[m][j] = fmaf(v, w20, r0[m][j]);
                    r1[m][j] = fmaf(v, w21, r1[m][j]);
                }
        }
        #pragma unroll
        for (int mk = 1; mk < 16; mk <<= 1)
            #pragma unroll
            for (int m = 0; m < 4; ++m)
                #pragma unroll
                for (int j = 0; j < 4; ++j) {
                    r0[m][j] += __shfl_xor(r0[m][j], mk);
                    r1[m][j] += __shfl_xor(r1[m][j], mk);
                }
        if (arow == 0) {
            #pragma unroll
            for (int m = 0; m < 4; ++m)
                #pragma unroll
                for (int j = 0; j < 4; ++j) {
                    s_red[wm][wn][m * 16 + q * 4 + j][0] = r0[m][j];
                    s_red[wm][wn][m * 16 + q * 4 + j][1] = r1[m][j];
                }
        }
    }
    __syncthreads();
    if (tid < 256) {
        const int row = tid >> 1, sub = tid & 1;
        const int rl = row & 63, wmm = row >> 6;
        if (isPS) {
            const int gg = bn * 2 + sub;
            glog[(size_t)(t0 + row) * NG + gg] =
                s_red[wmm][sub * 2][rl][0] + s_red[wmm][sub * 2 + 1][rl][0] + psb2[gg];
        } else {
            const int gg = (bn - 4) * 2 + sub;
            const size_t bidx = ((size_t)(t0 + row) * NG + gg) * NES;
            ilog[bidx + 0] = s_red[wmm][sub * 2][rl][0] + s_red[wmm][sub * 2 + 1][rl][0] + irb2[gg * NES + 0];
            ilog[bidx + 1] = s_red[wmm][sub * 2][rl][1] + s_red[wmm][sub * 2 + 1][rl][1] + irb2[gg * NES + 1];
        }
    }
}

// ---------- Kernel 2b: finalize with margin check ----------
#define MARGIN 8e-3f
__global__ __launch_bounds__(256) void hg_finalize2(
    const float* __restrict__ glog_buf, const float* __restrict__ ilog_buf,
    int* __restrict__ counts, int* __restrict__ nfix, int* __restrict__ fix_list,
    int* __restrict__ list_tok, float* __restrict__ list_w)
{
    const int t = blockIdx.x * 256 + threadIdx.x;
    float gl[NG];
    *(float4*)&gl[0] = ((const float4*)(glog_buf + (size_t)t * NG))[0];
    *(float4*)&gl[4] = ((const float4*)(glog_buf + (size_t)t * NG))[1];
    int i1 = 0; float m1 = gl[0];
    #pragma unroll
    for (int g = 1; g < NG; ++g) if (gl[g] > m1) { m1 = gl[g]; i1 = g; }
    int i2 = -1; float m2 = -3.4e38f;
    #pragma unroll
    for (int g = 0; g < NG; ++g) if (g != i1 && gl[g] > m2) { m2 = gl[g]; i2 = g; }
    float m3 = -3.4e38f;
    #pragma unroll
    for (int g = 0; g < NG; ++g) if (g != i1 && g != i2 && gl[g] > m3) m3 = gl[g];

    const float ila0 = ilog_buf[((size_t)t * NG + i1) * NES + 0];
    const float ila1 = ilog_buf[((size_t)t * NG + i1) * NES + 1];
    const float ilb0 = ilog_buf[((size_t)t * NG + i2) * NES + 0];
    const float ilb1 = ilog_buf[((size_t)t * NG + i2) * NES + 1];

    const bool flag = ((m2 - m3) < MARGIN) || (fabsf(ila1 - ila0) < MARGIN)
                   || (fabsf(ilb1 - ilb0) < MARGIN);
    if (flag) {
        const int p = atomicAdd(nfix, 1);
        fix_list[p] = t;
        return;
    }
    const float ex = expf(m2 - m1);
    const float inv = 1.0f / (1.0f + ex);
    const int   gsel[2] = {i1, i2};
    const float wsel[2] = {inv, ex * inv};
    const int   ksel[2] = {(ila1 > ila0) ? 1 : 0, (ilb1 > ilb0) ? 1 : 0};
    #pragma unroll
    for (int s = 0; s < 2; ++s) {
        const int eid = gsel[s] * NES + ksel[s];
        const int pos = atomicAdd(&counts[eid], 1);
        list_tok[(size_t)eid * T_TOKENS + pos] = t;
        list_w[(size_t)eid * T_TOKENS + pos] = wsel[s];
    }
}

// ---------- Kernel 2c: exact fp32 fixup, 4-wave parallel, unrolled ----------
__global__ __launch_bounds__(256) void hg_fixup(
    const float* __restrict__ hidden, const float* __restrict__ feat,
    const float* __restrict__ lng, const float* __restrict__ lnb,
    const float* __restrict__ stageW, const float* __restrict__ stageb,
    const float* __restrict__ gfW, const float* __restrict__ gfb,
    const float* __restrict__ psW1, const float* __restrict__ psb1,
    const float* __restrict__ psW2, const float* __restrict__ psb2,
    const float* __restrict__ irW1, const float* __restrict__ irb1,
    const float* __restrict__ irW2, const float* __restrict__ irb2,
    const int* __restrict__ nfix, const int* __restrict__ fix_list,
    int* __restrict__ counts, int* __restrict__ list_tok, float* __restrict__ list_w)
{
    __shared__ float s_rin[RIN];
    __shared__ float s_tail[2][DFEMB];
    __shared__ float s_gl[NG];
    __shared__ float s_part[4][2];
    __shared__ int s_sel[2];
    __shared__ float s_wsel[2];

    const int tid = threadIdx.x, lane = tid & 63, w = tid >> 6;
    const int nf = nfix[0];
    for (int idx = blockIdx.x; idx < nf; idx += gridDim.x) {
        const int t = fix_list[idx];
        if (w == 0) {
            const float* row = hidden + (size_t)t * DMODEL;
            float4 v0 = ((const float4*)row)[lane * 2 + 0];
            float4 v1 = ((const float4*)row)[lane * 2 + 1];
            float s = v0.x + v0.y + v0.z + v0.w + v1.x + v1.y + v1.z + v1.w;
            #pragma unroll
            for (int m = 1; m < 64; m <<= 1) s += __shfl_xor(s, m);
            const float mu = s * (1.0f / DMODEL);
            float sq = 0.f;
            { float d;
              d = v0.x - mu; sq += d * d; d = v0.y - mu; sq += d * d;
              d = v0.z - mu; sq += d * d; d = v0.w - mu; sq += d * d;
              d = v1.x - mu; sq += d * d; d = v1.y - mu; sq += d * d;
              d = v1.z - mu; sq += d * d; d = v1.w - mu; sq += d * d; }
            #pragma unroll
            for (int m = 1; m < 64; m <<= 1) sq += __shfl_xor(sq, m);
            const float rstd = rsqrtf(sq * (1.0f / DMODEL) + 1e-5f);
            float4 g0 = ((const float4*)lng)[lane * 2 + 0];
            float4 g1 = ((const float4*)lng)[lane * 2 + 1];
            float4 b0 = ((const float4*)lnb)[lane * 2 + 0];
            float4 b1 = ((const float4*)lnb)[lane * 2 + 1];
            s_rin[lane * 8 + 0] = (v0.x - mu) * rstd * g0.x + b0.x;
            s_rin[lane * 8 + 1] = (v0.y - mu) * rstd * g0.y + b0.y;
            s_rin[lane * 8 + 2] = (v0.z - mu) * rstd * g0.z + b0.z;
            s_rin[lane * 8 + 3] = (v0.w - mu) * rstd * g0.w + b0.w;
            s_rin[lane * 8 + 4] = (v1.x - mu) * rstd * g1.x + b1.x;
            s_rin[lane * 8 + 5] = (v1.y - mu) * rstd * g1.y + b1.y;
            s_rin[lane * 8 + 6] = (v1.z - mu) * rstd * g1.z + b1.z;
            s_rin[lane * 8 + 7] = (v1.w - mu) * rstd * g1.w + b1.w;
        } else if (w == 1) {
            float se = stageb[lane];
            #pragma unroll 8
            for (int f = 0; f < FFEAT; ++f)
                se = fmaf(feat[(size_t)t * FFEAT + f], stageW[f * DFEMB + lane], se);
            s_rin[DMODEL + lane] = se;
        }
        __syncthreads();

        // glog: wave w -> groups 2w, 2w+1 (lane owns cols lane, 64+lane)
        #pragma unroll
        for (int gi = 0; gi < 2; ++gi) {
            const int g = w * 2 + gi;
            float a0 = psb1[g * DRH + lane];
            float a1 = psb1[g * DRH + 64 + lane];
            const float* W = psW1 + (size_t)g * RIN * DRH;
            #pragma unroll 8
            for (int k = 0; k < RIN; ++k) {
                const float r = s_rin[k];
                a0 = fmaf(r, W[(size_t)k * DRH + lane], a0);
                a1 = fmaf(r, W[(size_t)k * DRH + 64 + lane], a1);
            }
            float p = gelu_f(a0) * psW2[g * DRH + lane] + gelu_f(a1) * psW2[g * DRH + 64 + lane];
            #pragma unroll
            for (int m = 1; m < 64; m <<= 1) p += __shfl_xor(p, m);
            if (lane == 0) s_gl[g] = p + psb2[g];
        }
        __syncthreads();

        if (tid == 0) {
            int i1 = 0; float m1 = s_gl[0];
            #pragma unroll
            for (int g = 1; g < NG; ++g) if (s_gl[g] > m1) { m1 = s_gl[g]; i1 = g; }
            int i2 = -1; float m2 = -3.4e38f;
            #pragma unroll
            for (int g = 0; g < NG; ++g) if (g != i1 && s_gl[g] > m2) { m2 = s_gl[g]; i2 = g; }
            const float ex = expf(m2 - m1);
            const float inv = 1.0f / (1.0f + ex);
            s_sel[0] = i1; s_sel[1] = i2;
            s_wsel[0] = inv; s_wsel[1] = ex * inv;
        }
        __syncthreads();

        const int pr = w >> 1;
        const int gsel = s_sel[pr];
        if ((w & 1) == 0) {
            float ge = gfb[gsel * DFEMB + lane];
            #pragma unroll
            for (int f = 0; f < 8; ++f)
                ge = fmaf(feat[(size_t)t * FFEAT + gsel * 8 + f],
                          gfW[(size_t)(gsel * 8 + f) * DFEMB + lane], ge);
            s_tail[pr][lane] = ge;
        }
        __syncthreads();

        {
            const int col = (w & 1) * 64 + lane;
            float a = irb1[gsel * DRH + col];
            const float* W = irW1 + (size_t)gsel * RIN * DRH + col;
            #pragma unroll 8
            for (int k = 0; k < DMODEL; ++k)
                a = fmaf(s_rin[k], W[(size_t)k * DRH], a);
            #pragma unroll 8
            for (int k = 0; k < DFEMB; ++k)
                a = fmaf(s_tail[pr][k], W[(size_t)(DMODEL + k) * DRH], a);
            const float v = gelu_f(a);
            float e0 = v * irW2[(size_t)(gsel * DRH + col) * NES + 0];
            float e1 = v * irW2[(size_t)(gsel * DRH + col) * NES + 1];
            #pragma unroll
            for (int m = 1; m < 64; m <<= 1) {
                e0 += __shfl_xor(e0, m);
                e1 += __shfl_xor(e1, m);
            }
            if (lane == 0) { s_part[w][0] = e0; s_part[w][1] = e1; }
        }
        __syncthreads();

        if (tid == 0) {
            #pragma unroll
            for (int p2 = 0; p2 < 2; ++p2) {
                const float e0 = s_part[p2 * 2][0] + s_part[p2 * 2 + 1][0];
                const float e1 = s_part[p2 * 2][1] + s_part[p2 * 2 + 1][1];
                const int eid = s_sel[p2] * NES + ((e1 > e0) ? 1 : 0);
                const int pos = atomicAdd(&counts[eid], 1);
                list_tok[(size_t)eid * T_TOKENS + pos] = t;
                list_w[(size_t)eid * T_TOKENS + pos] = s_wsel[p2];
            }
        }
        __syncthreads();
    }
}

// ---------- Kernel 3: experts (fp16) ----------
__global__ __launch_bounds__(256) void k_expert(
    const unsigned short* __restrict__ Ahi,
    const unsigned short* __restrict__ eW1T, const float* __restrict__ eb1,
    const unsigned short* __restrict__ eW2T, const float* __restrict__ eb2,
    const float* __restrict__ alpha_p,
    const int* __restrict__ counts, const int* __restrict__ list_tok,
    const float* __restrict__ list_w, float* __restrict__ out)
{
    __shared__ char smem[65536];
    unsigned short* sEH = (unsigned short*)smem;
    unsigned short* sA  = (unsigned short*)(smem + 32768);
    unsigned short* sB1 = (unsigned short*)(smem + 36864);
    unsigned short* sB2 = (unsigned short*)(smem + 32768);
    __shared__ int s_tok[64];
    __shared__ float s_w[64];

    const int e = blockIdx.y;
    const int cnt = counts[e];
    const int base = blockIdx.x * 64;
    if (base >= cnt) return;
    const int nrow = min(64, cnt - base);
    const int tid = threadIdx.x, lane = tid & 63, w = tid >> 6;

    if (tid < 64) {
        const int src = base + ((tid < nrow) ? tid : (nrow - 1));
        s_tok[tid] = list_tok[(size_t)e * T_TOKENS + src];
        s_w[tid] = (tid < nrow) ? list_w[(size_t)e * T_TOKENS + base + tid] : 0.f;
    }
    __syncthreads();

    const int srow = w * 16 + (lane >> 2);
    const int stok = s_tok[srow];
    const int qcor = ((srow >> 1) & 3) ^ ((stok >> 1) & 3);
    const unsigned short* gA = Ahi + (size_t)stok * RIN + 8 * ((lane & 3) ^ qcor);
    unsigned short* dA = sA + w * 512;
    const int sgr = (lane & 3) * 8;
    const unsigned short* gB1[4];
    #pragma unroll
    for (int i = 0; i < 4; ++i)
        gB1[i] = eW1T + (size_t)e * DHID * DMODEL + (size_t)(w * 64 + i * 16 + (lane >> 2)) * DMODEL + sgr;

    const int arow = lane & 15, koff = (lane >> 4) * 8;
    const int q8r = ((arow >> 1) & 3) * 8;
    int aoff[4], b1off[4];
    #pragma unroll
    for (int m = 0; m < 4; ++m) aoff[m] = (m * 16 + arow) * 32 + (koff ^ q8r);
    #pragma unroll
    for (int n = 0; n < 4; ++n) b1off[n] = (w * 64 + n * 16 + arow) * 32 + (koff ^ q8r);

    f32x4 acc1[4][4];
    #pragma unroll
    for (int m = 0; m < 4; ++m)
        #pragma unroll
        for (int n = 0; n < 4; ++n) { acc1[m][n].x = 0.f; acc1[m][n].y = 0.f; acc1[m][n].z = 0.f; acc1[m][n].w = 0.f; }

    for (int kt = 0; kt < 16; ++kt) {
        const int kk = kt * 32;
        gl_lds16(gA + kk, dA);
        #pragma unroll
        for (int i = 0; i < 4; ++i) gl_lds16(gB1[i] + kk, sB1 + w * 2048 + i * 512);
        __syncthreads();
        f16x8 a[4];
        #pragma unroll
        for (int m = 0; m < 4; ++m) a[m] = *(const f16x8*)&sA[aoff[m]];
        #pragma unroll
        for (int n = 0; n < 4; ++n) {
            f16x8 b = *(const f16x8*)&sB1[b1off[n]];
            #pragma unroll
            for (int m = 0; m < 4; ++m) acc1[m][n] = MFMA16F(a[m], b, acc1[m][n]);
        }
        __syncthreads();
    }

    const int q = lane >> 4;
    #pragma unroll
    for (int m = 0; m < 4; ++m)
        #pragma unroll
        for (int n = 0; n < 4; ++n) {
            const int col = w * 64 + n * 16 + arow;
            const float bv = eb1[e * DHID + col];
            #pragma unroll
            for (int j = 0; j < 4; ++j) {
                const int rr = m * 16 + q * 4 + j;
                const int d = rr * 256 + (col & 0xE0) + ((col & 31) ^ (((rr >> 1) & 3) * 8));
                sEH[d] = f2h(gelu_f(acc1[m][n][j] + bv));
            }
        }
    __syncthreads();

    const unsigned short* gB2[8];
    #pragma unroll
    for (int i = 0; i < 8; ++i)
        gB2[i] = eW2T + (size_t)e * DMODEL * DHID + (size_t)(w * 128 + i * 16 + (lane >> 2)) * DHID + sgr;
    int a2base[4], b2off[8];
    #pragma unroll
    for (int m = 0; m < 4; ++m) a2base[m] = (m * 16 + arow) * 256 + (koff ^ q8r);
    #pragma unroll
    for (int n = 0; n < 8; ++n) b2off[n] = (w * 128 + n * 16 + arow) * 32 + (koff ^ q8r);

    f32x4 acc2[4][8];
    #pragma unroll
    for (int m = 0; m < 4; ++m)
        #pragma unroll
        for (int n = 0; n < 8; ++n) { acc2[m][n].x = 0.f; acc2[m][n].y = 0.f; acc2[m][n].z = 0.f; acc2[m][n].w = 0.f; }

    for (int kt = 0; kt < 8; ++kt) {
        #pragma unroll
        for (int i = 0; i < 8; ++i) gl_lds16(gB2[i] + kt * 32, sB2 + w * 4096 + i * 512);
        __syncthreads();
        f16x8 a[4];
        #pragma unroll
        for (int m = 0; m < 4; ++m) a[m] = *(const f16x8*)&sEH[a2base[m] + kt * 32];
        #pragma unroll
        for (int n = 0; n < 8; ++n) {
            f16x8 b = *(const f16x8*)&sB2[b2off[n]];
            #pragma unroll
            for (int m = 0; m < 4; ++m) acc2[m][n] = MFMA16F(a[m], b, acc2[m][n]);
        }
        __syncthreads();
    }

    const float alpha = alpha_p[0];
    #pragma unroll
    for (int m = 0; m < 4; ++m)
        #pragma unroll
        for (int n = 0; n < 8; ++n) {
            const int col = w * 128 + n * 16 + arow;
            const float b2v = eb2[e * DMODEL + col];
            #pragma unroll
            for (int j = 0; j < 4; ++j) {
                const int r = m * 16 + q * 4 + j;
                if (r < nrow)
                    atomicAdd(out + (size_t)s_tok[r] * DMODEL + col,
                              s_w[r] * alpha * (acc2[m][n][j] + b2v));
            }
        }
}

// ---------- launch ----------
extern "C" void kernel_launch(void* const* d_in, const int* in_sizes, int n_in,
                              void* d_out, int out_size, void* d_ws, size_t ws_size,
                              hipStream_t stream) {
    const float* hidden = (const float*)d_in[0];
    const float* feat   = (const float*)d_in[1];
    const float* ln_g   = (const float*)d_in[2];
    const float* ln_b   = (const float*)d_in[3];
    const float* stageW = (const float*)d_in[4];
    const float* stageb = (const float*)d_in[5];
    const float* gfW    = (const float*)d_in[6];
    const float* gfb    = (const float*)d_in[7];
    const float* psW1   = (const float*)d_in[8];
    const float* psb1   = (const float*)d_in[9];
    const float* psW2   = (const float*)d_in[10];
    const float* psb2   = (const float*)d_in[11];
    const float* irW1   = (const float*)d_in[12];
    const float* irb1   = (const float*)d_in[13];
    const float* irW2   = (const float*)d_in[14];
    const float* irb2   = (const float*)d_in[15];
    const float* eW1    = (const float*)d_in[16];
    const float* eb1    = (const float*)d_in[17];
    const float* eW2    = (const float*)d_in[18];
    const float* eb2    = (const float*)d_in[19];
    const float* alpha  = (const float*)d_in[20];

    float* out = (float*)d_out;

    char* p = (char*)d_ws;
    unsigned short* Ahi = (unsigned short*)p; p += (size_t)T_TOKENS * RIN * 2;
    unsigned short* Bhi = (unsigned short*)p; p += (size_t)2048 * RIN * 2;
    unsigned short* eW1T = (unsigned short*)p; p += (size_t)NE * DHID * DMODEL * 2;
    unsigned short* eW2T = (unsigned short*)p; p += (size_t)NE * DMODEL * DHID * 2;
    float* Dps = (float*)p;   p += (size_t)NG * 64 * DRH * 4;
    float* Cir = (float*)p;   p += (size_t)NG * 8 * DRH * 4;
    float* fbps = (float*)p;  p += (size_t)NG * DRH * 4;
    float* fbir = (float*)p;  p += (size_t)NG * DRH * 4;
    float* glog_buf = (float*)p; p += (size_t)T_TOKENS * NG * 4;
    float* ilog_buf = (float*)p; p += (size_t)T_TOKENS * NG * NES * 4;
    int* counts = (int*)p;    p += 128;
    int* nfix = counts + 16;
    int* fix_list = (int*)p;  p += (size_t)T_TOKENS * 4;
    int* list_tok = (int*)p;  p += (size_t)NE * T_TOKENS * 4;
    float* list_w = (float*)p; p += (size_t)NE * T_TOKENS * 4;

    hipMemsetAsync(counts, 0, 128, stream);

    k_prep<<<T_TOKENS / 4, 256, 0, stream>>>(hidden, feat, ln_g, ln_b, Ahi, out);

    k_fold_ps<<<dim3(NG, 65), 128, 0, stream>>>(stageW, stageb, psW1, psb1, Dps, fbps);
    k_fold_ir<<<dim3(NG, 9), 128, 0, stream>>>(gfW, gfb, irW1, irb1, Cir, fbir);

    k_bsplitT<<<dim3(64, NG), 256, 0, stream>>>(
        psW1, Bhi, 512, DRH, RIN, 0, (long)RIN * DRH, (long)DRH * RIN);
    k_bsplitT<<<dim3(64, NG), 256, 0, stream>>>(
        irW1, Bhi + (size_t)1024 * RIN, 512, DRH, RIN, 0, (long)RIN * DRH, (long)DRH * RIN);
    k_bsplitT<<<dim3(8, NG), 256, 0, stream>>>(
        Dps, Bhi, 64, DRH, RIN, 512, (long)64 * DRH, (long)DRH * RIN);
    k_irtail<<<NG, 128, 0, stream>>>(Cir, Bhi);

    k_bsplitT<<<dim3(128, NE), 256, 0, stream>>>(
        eW1, eW1T, DMODEL, DHID, DMODEL, 0, (long)DMODEL * DHID, (long)DHID * DMODEL);
    k_bsplitT<<<dim3(128, NE), 256, 0, stream>>>(
        eW2, eW2T, DHID, DMODEL, DHID, 0, (long)DHID * DMODEL, (long)DMODEL * DHID);

    k_rgemm<<<dim3(T_TOKENS / 128, 8), 512, 0, stream>>>(
        Ahi, Bhi, fbps, psW2, psb2, fbir, irW2, irb2, glog_buf, ilog_buf);

    hg_finalize2<<<T_TOKENS / 256, 256, 0, stream>>>(
        glog_buf, ilog_buf, counts, nfix, fix_list, list_tok, list_w);

    hg_fixup<<<1024, 256, 0, stream>>>(
        hidden, feat, ln_g, ln_b, stageW, stageb, gfW, gfb,
        psW1, psb1, psW2, psb2, irW1, irb1, irW2, irb2,
        nfix, fix_list, counts, list_tok, list_w);

    k_expert<<<dim3(T_TOKENS / 64, NE), 256, 0, stream>>>(
        Ahi, eW1T, eb1, eW2T, eb2, alpha, counts, list_tok, list_w, out);
}

// Round 7
// 493.751 us; speedup vs baseline: 4.4822x; 1.0611x over previous
//
#include <hip/hip_runtime.h>
#include <hip/hip_bf16.h>

#define T_TOKENS 16384
#define DMODEL 512
#define FFEAT 64
#define DFEMB 64
#define RIN 576
#define DRH 128
#define NG 8
#define NES 2
#define NE 16
#define DHID 256

typedef float f32x4 __attribute__((ext_vector_type(4)));
typedef _Float16 f16x8 __attribute__((ext_vector_type(8)));
#define MFMA16F(a, b, c) __builtin_amdgcn_mfma_f32_16x16x32_f16((a), (b), (c), 0, 0, 0)

__device__ __forceinline__ float gelu_f(float x) {
    return 0.5f * x * (1.0f + erff(x * 0.7071067811865476f));
}
__device__ __forceinline__ unsigned short f2h(float x) {
    _Float16 h = (_Float16)x;
    union { _Float16 f; unsigned short u; } v; v.f = h;
    return v.u;
}
__device__ __forceinline__ float h2f(unsigned short u) {
    union { unsigned short u; _Float16 f; } v; v.u = u;
    return (float)v.f;
}
__device__ __forceinline__ void gl_lds16(const unsigned short* g, unsigned short* l) {
    __builtin_amdgcn_global_load_lds(
        (const __attribute__((address_space(1))) unsigned int*)g,
        (__attribute__((address_space(3))) unsigned int*)l, 16, 0, 0);
}

// ---------- Kernel 1: LN + fp16 swizzled A ----------
__global__ __launch_bounds__(256) void k_prep(
    const float* __restrict__ hidden, const float* __restrict__ feat,
    const float* __restrict__ lng, const float* __restrict__ lnb,
    unsigned short* __restrict__ Ahi)
{
    const int t = blockIdx.x * 4 + (threadIdx.x >> 6);
    const int lane = threadIdx.x & 63;
    const float* row = hidden + (size_t)t * DMODEL;
    float4 v0 = ((const float4*)row)[lane * 2 + 0];
    float4 v1 = ((const float4*)row)[lane * 2 + 1];
    float s = v0.x + v0.y + v0.z + v0.w + v1.x + v1.y + v1.z + v1.w;
    #pragma unroll
    for (int m = 1; m < 64; m <<= 1) s += __shfl_xor(s, m);
    const float mu = s * (1.0f / DMODEL);
    float sq = 0.f;
    { float d;
      d = v0.x - mu; sq += d * d; d = v0.y - mu; sq += d * d;
      d = v0.z - mu; sq += d * d; d = v0.w - mu; sq += d * d;
      d = v1.x - mu; sq += d * d; d = v1.y - mu; sq += d * d;
      d = v1.z - mu; sq += d * d; d = v1.w - mu; sq += d * d; }
    #pragma unroll
    for (int m = 1; m < 64; m <<= 1) sq += __shfl_xor(sq, m);
    const float rstd = rsqrtf(sq * (1.0f / DMODEL) + 1e-5f);
    float4 g0 = ((const float4*)lng)[lane * 2 + 0];
    float4 g1 = ((const float4*)lng)[lane * 2 + 1];
    float4 b0 = ((const float4*)lnb)[lane * 2 + 0];
    float4 b1 = ((const float4*)lnb)[lane * 2 + 1];
    float h[8];
    h[0] = (v0.x - mu) * rstd * g0.x + b0.x;
    h[1] = (v0.y - mu) * rstd * g0.y + b0.y;
    h[2] = (v0.z - mu) * rstd * g0.z + b0.z;
    h[3] = (v0.w - mu) * rstd * g0.w + b0.w;
    h[4] = (v1.x - mu) * rstd * g1.x + b1.x;
    h[5] = (v1.y - mu) * rstd * g1.y + b1.y;
    h[6] = (v1.z - mu) * rstd * g1.z + b1.z;
    h[7] = (v1.w - mu) * rstd * g1.w + b1.w;
    const int q8 = ((t >> 1) & 3) * 8;
    ushort4 H0, H1;
    H0.x = f2h(h[0]); H0.y = f2h(h[1]); H0.z = f2h(h[2]); H0.w = f2h(h[3]);
    H1.x = f2h(h[4]); H1.y = f2h(h[5]); H1.z = f2h(h[6]); H1.w = f2h(h[7]);
    unsigned short* pa = Ahi + (size_t)t * RIN;
    const int dst = (lane >> 2) * 32 + (((lane & 3) * 8) ^ q8);
    *(ushort4*)&pa[dst] = H0;  *(ushort4*)&pa[dst + 4] = H1;
    const float fv = feat[(size_t)t * FFEAT + lane];
    const int fd = DMODEL + (lane & 32) + ((lane & 31) ^ q8);
    pa[fd] = f2h(fv);
}

// ---------- fold kernels ----------
__global__ __launch_bounds__(128) void k_fold_ps(
    const float* __restrict__ stageW, const float* __restrict__ stageb,
    const float* __restrict__ psW1, const float* __restrict__ psb1,
    float* __restrict__ Dps, float* __restrict__ fbps)
{
    const int g = blockIdx.x, f = blockIdx.y, c = threadIdx.x;
    const float* Wt = psW1 + (size_t)g * RIN * DRH + (size_t)DMODEL * DRH;
    float acc = 0.f;
    if (f < 64) {
        for (int j = 0; j < DFEMB; ++j) acc = fmaf(stageW[f * DFEMB + j], Wt[(size_t)j * DRH + c], acc);
        Dps[((size_t)g * 64 + f) * DRH + c] = acc;
    } else {
        for (int j = 0; j < DFEMB; ++j) acc = fmaf(stageb[j], Wt[(size_t)j * DRH + c], acc);
        fbps[g * DRH + c] = acc + psb1[g * DRH + c];
    }
}

__global__ __launch_bounds__(128) void k_fold_ir(
    const float* __restrict__ gfW, const float* __restrict__ gfb,
    const float* __restrict__ irW1, const float* __restrict__ irb1,
    float* __restrict__ Cir, float* __restrict__ fbir)
{
    const int g = blockIdx.x, f = blockIdx.y, c = threadIdx.x;
    const float* Wt = irW1 + (size_t)g * RIN * DRH + (size_t)DMODEL * DRH;
    float acc = 0.f;
    if (f < 8) {
        for (int j = 0; j < DFEMB; ++j) acc = fmaf(gfW[(size_t)(g * 8 + f) * DFEMB + j], Wt[(size_t)j * DRH + c], acc);
        Cir[((size_t)g * 8 + f) * DRH + c] = acc;
    } else {
        for (int j = 0; j < DFEMB; ++j) acc = fmaf(gfb[g * DFEMB + j], Wt[(size_t)j * DRH + c], acc);
        fbir[g * DRH + c] = acc + irb1[g * DRH + c];
    }
}

// ---------- transpose + fp16, swizzled dest: in[K][N] -> out[N][K'] ----------
__global__ __launch_bounds__(256) void k_bsplitT(
    const float* __restrict__ in, unsigned short* __restrict__ outHi,
    int K, int N, int outStride, int kOff, long inBS, long outBS)
{
    __shared__ float s_t[32][33];
    const int b = blockIdx.y;
    const int tilesN = N >> 5;
    const int ko = (blockIdx.x / tilesN) << 5;
    const int no = (blockIdx.x % tilesN) << 5;
    const int r = threadIdx.x >> 3, c0 = (threadIdx.x & 7) * 4;
    {
        float4 v = *(const float4*)(in + (size_t)b * inBS + (size_t)(ko + r) * N + no + c0);
        s_t[r][c0] = v.x; s_t[r][c0 + 1] = v.y; s_t[r][c0 + 2] = v.z; s_t[r][c0 + 3] = v.w;
    }
    __syncthreads();
    float vv[4];
    #pragma unroll
    for (int j = 0; j < 4; ++j) vv[j] = s_t[c0 + j][r];
    const int col = no + r;
    const int q8 = ((col >> 1) & 3) * 8;
    ushort4 hi;
    hi.x = f2h(vv[0]); hi.y = f2h(vv[1]); hi.z = f2h(vv[2]); hi.w = f2h(vv[3]);
    *(ushort4*)(outHi + (size_t)b * outBS + (size_t)col * outStride + kOff + ko + (c0 ^ q8)) = hi;
}

// ---------- ir tail rows of B ----------
__global__ __launch_bounds__(128) void k_irtail(
    const float* __restrict__ Cir, unsigned short* __restrict__ Bhi)
{
    const int g = blockIdx.x, c = threadIdx.x;
    const int col = 1024 + g * DRH + c;
    const int q8 = ((col >> 1) & 3) * 8;
    unsigned short* ph = Bhi + (size_t)col * RIN + DMODEL;
    for (int f = 0; f < 64; ++f) {
        float v = ((f >> 3) == g) ? Cir[((size_t)g * 8 + (f & 7)) * DRH + c] : 0.f;
        const int d = (f & 32) + ((f & 31) ^ q8);
        ph[d] = f2h(v);
    }
}

// ---------- Kernel 2: router GEMM [16384x576]@[576x2048], fp16 single-pass ----------
__global__ __launch_bounds__(512) void k_rgemm(
    const unsigned short* __restrict__ Ahi, const unsigned short* __restrict__ Bhi,
    const float* __restrict__ fbps, const float* __restrict__ psW2, const float* __restrict__ psb2,
    const float* __restrict__ fbir, const float* __restrict__ irW2, const float* __restrict__ irb2,
    float* __restrict__ glog, float* __restrict__ ilog)
{
    __shared__ unsigned short sAh[128 * 32];
    __shared__ unsigned short sBh[256 * 32];
    __shared__ float s_red[2][4][64][2];

    const int tid = threadIdx.x, lane = tid & 63, w = tid >> 6;
    const int t0 = blockIdx.x * 128, bn = blockIdx.y;
    const int wm = w >> 2, wn = w & 3;
    const int arow = lane & 15, koff = (lane >> 4) * 8;
    const int q8r = ((arow >> 1) & 3) * 8;

    int aoff[4], boff[4];
    #pragma unroll
    for (int m = 0; m < 4; ++m) aoff[m] = (wm * 64 + m * 16 + arow) * 32 + (koff ^ q8r);
    #pragma unroll
    for (int n = 0; n < 4; ++n) boff[n] = (wn * 64 + n * 16 + arow) * 32 + (koff ^ q8r);

    const int srow = w * 16 + (lane >> 2);
    const int sgr = (lane & 3) * 8;
    const unsigned short* gAh = Ahi + (size_t)(t0 + srow) * RIN + sgr;
    const unsigned short* gBh0 = Bhi + (size_t)(bn * 256 + w * 32 + (lane >> 2)) * RIN + sgr;
    const unsigned short* gBh1 = gBh0 + (size_t)16 * RIN;
    unsigned short* dAh = sAh + w * 512;
    unsigned short* dBh0 = sBh + w * 1024;
    unsigned short* dBh1 = sBh + w * 1024 + 512;

    f32x4 acc[4][4];
    #pragma unroll
    for (int m = 0; m < 4; ++m)
        #pragma unroll
        for (int n = 0; n < 4; ++n) { acc[m][n].x = 0.f; acc[m][n].y = 0.f; acc[m][n].z = 0.f; acc[m][n].w = 0.f; }

    for (int kt = 0; kt < 18; ++kt) {
        const int kk = kt * 32;
        gl_lds16(gAh + kk, dAh);
        gl_lds16(gBh0 + kk, dBh0);
        gl_lds16(gBh1 + kk, dBh1);
        __syncthreads();
        f16x8 ah[4];
        #pragma unroll
        for (int m = 0; m < 4; ++m) ah[m] = *(const f16x8*)&sAh[aoff[m]];
        #pragma unroll
        for (int n = 0; n < 4; ++n) {
            f16x8 b = *(const f16x8*)&sBh[boff[n]];
            #pragma unroll
            for (int m = 0; m < 4; ++m) acc[m][n] = MFMA16F(ah[m], b, acc[m][n]);
        }
        __syncthreads();
    }

    // fused second layers
    const int grp = wn >> 1;
    const bool isPS = (bn < 4);
    const int g = isPS ? (bn * 2 + grp) : ((bn - 4) * 2 + grp);
    const int q = lane >> 4;
    if (isPS) {
        float r0[4][4] = {};
        #pragma unroll
        for (int n = 0; n < 4; ++n) {
            const int cg = (wn & 1) * 64 + n * 16 + arow;
            const float b1 = fbps[g * DRH + cg];
            const float w2 = psW2[g * DRH + cg];
            #pragma unroll
            for (int m = 0; m < 4; ++m)
                #pragma unroll
                for (int j = 0; j < 4; ++j)
                    r0[m][j] += gelu_f(acc[m][n][j] + b1) * w2;
        }
        #pragma unroll
        for (int mk = 1; mk < 16; mk <<= 1)
            #pragma unroll
            for (int m = 0; m < 4; ++m)
                #pragma unroll
                for (int j = 0; j < 4; ++j) r0[m][j] += __shfl_xor(r0[m][j], mk);
        if (arow == 0) {
            #pragma unroll
            for (int m = 0; m < 4; ++m)
                #pragma unroll
                for (int j = 0; j < 4; ++j) {
                    s_red[wm][wn][m * 16 + q * 4 + j][0] = r0[m][j];
                    s_red[wm][wn][m * 16 + q * 4 + j][1] = 0.f;
                }
        }
    } else {
        float r0[4][4] = {}, r1[4][4] = {};
        #pragma unroll
        for (int n = 0; n < 4; ++n) {
            const int cg = (wn & 1) * 64 + n * 16 + arow;
            const float b1 = fbir[g * DRH + cg];
            const float w20 = irW2[(size_t)(g * DRH + cg) * NES + 0];
            const float w21 = irW2[(size_t)(g * DRH + cg) * NES + 1];
            #pragma unroll
            for (int m = 0; m < 4; ++m)
                #pragma unroll
                for (int j = 0; j < 4; ++j) {
                    const float v = gelu_f(acc[m][n][j] + b1);
                    r0[m][j] = fmaf(v, w20, r0[m][j]);
                    r1[m][j] = fmaf(v, w21, r1[m][j]);
                }
        }
        #pragma unroll
        for (int mk = 1; mk < 16; mk <<= 1)
            #pragma unroll
            for (int m = 0; m < 4; ++m)
                #pragma unroll
                for (int j = 0; j < 4; ++j) {
                    r0[m][j] += __shfl_xor(r0[m][j], mk);
                    r1[m][j] += __shfl_xor(r1[m][j], mk);
                }
        if (arow == 0) {
            #pragma unroll
            for (int m = 0; m < 4; ++m)
                #pragma unroll
                for (int j = 0; j < 4; ++j) {
                    s_red[wm][wn][m * 16 + q * 4 + j][0] = r0[m][j];
                    s_red[wm][wn][m * 16 + q * 4 + j][1] = r1[m][j];
                }
        }
    }
    __syncthreads();
    if (tid < 256) {
        const int row = tid >> 1, sub = tid & 1;
        const int rl = row & 63, wmm = row >> 6;
        if (isPS) {
            const int gg = bn * 2 + sub;
            glog[(size_t)(t0 + row) * NG + gg] =
                s_red[wmm][sub * 2][rl][0] + s_red[wmm][sub * 2 + 1][rl][0] + psb2[gg];
        } else {
            const int gg = (bn - 4) * 2 + sub;
            const size_t bidx = ((size_t)(t0 + row) * NG + gg) * NES;
            ilog[bidx + 0] = s_red[wmm][sub * 2][rl][0] + s_red[wmm][sub * 2 + 1][rl][0] + irb2[gg * NES + 0];
            ilog[bidx + 1] = s_red[wmm][sub * 2][rl][1] + s_red[wmm][sub * 2 + 1][rl][1] + irb2[gg * NES + 1];
        }
    }
}

// ---------- Kernel 2b: finalize with margin check ----------
#define MARGIN 8e-3f
__global__ __launch_bounds__(256) void hg_finalize2(
    const float* __restrict__ glog_buf, const float* __restrict__ ilog_buf,
    int* __restrict__ counts, int* __restrict__ nfix, int* __restrict__ fix_list,
    int* __restrict__ list_tok, float* __restrict__ list_w, int* __restrict__ list_slot)
{
    const int t = blockIdx.x * 256 + threadIdx.x;
    float gl[NG];
    *(float4*)&gl[0] = ((const float4*)(glog_buf + (size_t)t * NG))[0];
    *(float4*)&gl[4] = ((const float4*)(glog_buf + (size_t)t * NG))[1];
    int i1 = 0; float m1 = gl[0];
    #pragma unroll
    for (int g = 1; g < NG; ++g) if (gl[g] > m1) { m1 = gl[g]; i1 = g; }
    int i2 = -1; float m2 = -3.4e38f;
    #pragma unroll
    for (int g = 0; g < NG; ++g) if (g != i1 && gl[g] > m2) { m2 = gl[g]; i2 = g; }
    float m3 = -3.4e38f;
    #pragma unroll
    for (int g = 0; g < NG; ++g) if (g != i1 && g != i2 && gl[g] > m3) m3 = gl[g];

    const float ila0 = ilog_buf[((size_t)t * NG + i1) * NES + 0];
    const float ila1 = ilog_buf[((size_t)t * NG + i1) * NES + 1];
    const float ilb0 = ilog_buf[((size_t)t * NG + i2) * NES + 0];
    const float ilb1 = ilog_buf[((size_t)t * NG + i2) * NES + 1];

    const bool flag = ((m2 - m3) < MARGIN) || (fabsf(ila1 - ila0) < MARGIN)
                   || (fabsf(ilb1 - ilb0) < MARGIN);
    if (flag) {
        const int p = atomicAdd(nfix, 1);
        fix_list[p] = t;
        return;
    }
    const float ex = expf(m2 - m1);
    const float inv = 1.0f / (1.0f + ex);
    const int   gsel[2] = {i1, i2};
    const float wsel[2] = {inv, ex * inv};
    const int   ksel[2] = {(ila1 > ila0) ? 1 : 0, (ilb1 > ilb0) ? 1 : 0};
    #pragma unroll
    for (int s = 0; s < 2; ++s) {
        const int eid = gsel[s] * NES + ksel[s];
        const int pos = atomicAdd(&counts[eid], 1);
        list_tok[(size_t)eid * T_TOKENS + pos] = t;
        list_w[(size_t)eid * T_TOKENS + pos] = wsel[s];
        list_slot[(size_t)eid * T_TOKENS + pos] = s;
    }
}

// ---------- Kernel 2c: exact fp32 fixup, 4-wave parallel, unrolled ----------
__global__ __launch_bounds__(256) void hg_fixup(
    const float* __restrict__ hidden, const float* __restrict__ feat,
    const float* __restrict__ lng, const float* __restrict__ lnb,
    const float* __restrict__ stageW, const float* __restrict__ stageb,
    const float* __restrict__ gfW, const float* __restrict__ gfb,
    const float* __restrict__ psW1, const float* __restrict__ psb1,
    const float* __restrict__ psW2, const float* __restrict__ psb2,
    const float* __restrict__ irW1, const float* __restrict__ irb1,
    const float* __restrict__ irW2, const float* __restrict__ irb2,
    const int* __restrict__ nfix, const int* __restrict__ fix_list,
    int* __restrict__ counts, int* __restrict__ list_tok, float* __restrict__ list_w,
    int* __restrict__ list_slot)
{
    __shared__ float s_rin[RIN];
    __shared__ float s_tail[2][DFEMB];
    __shared__ float s_gl[NG];
    __shared__ float s_part[4][2];
    __shared__ int s_sel[2];
    __shared__ float s_wsel[2];

    const int tid = threadIdx.x, lane = tid & 63, w = tid >> 6;
    const int nf = nfix[0];
    for (int idx = blockIdx.x; idx < nf; idx += gridDim.x) {
        const int t = fix_list[idx];
        if (w == 0) {
            const float* row = hidden + (size_t)t * DMODEL;
            float4 v0 = ((const float4*)row)[lane * 2 + 0];
            float4 v1 = ((const float4*)row)[lane * 2 + 1];
            float s = v0.x + v0.y + v0.z + v0.w + v1.x + v1.y + v1.z + v1.w;
            #pragma unroll
            for (int m = 1; m < 64; m <<= 1) s += __shfl_xor(s, m);
            const float mu = s * (1.0f / DMODEL);
            float sq = 0.f;
            { float d;
              d = v0.x - mu; sq += d * d; d = v0.y - mu; sq += d * d;
              d = v0.z - mu; sq += d * d; d = v0.w - mu; sq += d * d;
              d = v1.x - mu; sq += d * d; d = v1.y - mu; sq += d * d;
              d = v1.z - mu; sq += d * d; d = v1.w - mu; sq += d * d; }
            #pragma unroll
            for (int m = 1; m < 64; m <<= 1) sq += __shfl_xor(sq, m);
            const float rstd = rsqrtf(sq * (1.0f / DMODEL) + 1e-5f);
            float4 g0 = ((const float4*)lng)[lane * 2 + 0];
            float4 g1 = ((const float4*)lng)[lane * 2 + 1];
            float4 b0 = ((const float4*)lnb)[lane * 2 + 0];
            float4 b1 = ((const float4*)lnb)[lane * 2 + 1];
            s_rin[lane * 8 + 0] = (v0.x - mu) * rstd * g0.x + b0.x;
            s_rin[lane * 8 + 1] = (v0.y - mu) * rstd * g0.y + b0.y;
            s_rin[lane * 8 + 2] = (v0.z - mu) * rstd * g0.z + b0.z;
            s_rin[lane * 8 + 3] = (v0.w - mu) * rstd * g0.w + b0.w;
            s_rin[lane * 8 + 4] = (v1.x - mu) * rstd * g1.x + b1.x;
            s_rin[lane * 8 + 5] = (v1.y - mu) * rstd * g1.y + b1.y;
            s_rin[lane * 8 + 6] = (v1.z - mu) * rstd * g1.z + b1.z;
            s_rin[lane * 8 + 7] = (v1.w - mu) * rstd * g1.w + b1.w;
        } else if (w == 1) {
            float se = stageb[lane];
            #pragma unroll 8
            for (int f = 0; f < FFEAT; ++f)
                se = fmaf(feat[(size_t)t * FFEAT + f], stageW[f * DFEMB + lane], se);
            s_rin[DMODEL + lane] = se;
        }
        __syncthreads();

        #pragma unroll
        for (int gi = 0; gi < 2; ++gi) {
            const int g = w * 2 + gi;
            float a0 = psb1[g * DRH + lane];
            float a1 = psb1[g * DRH + 64 + lane];
            const float* W = psW1 + (size_t)g * RIN * DRH;
            #pragma unroll 8
            for (int k = 0; k < RIN; ++k) {
                const float r = s_rin[k];
                a0 = fmaf(r, W[(size_t)k * DRH + lane], a0);
                a1 = fmaf(r, W[(size_t)k * DRH + 64 + lane], a1);
            }
            float p = gelu_f(a0) * psW2[g * DRH + lane] + gelu_f(a1) * psW2[g * DRH + 64 + lane];
            #pragma unroll
            for (int m = 1; m < 64; m <<= 1) p += __shfl_xor(p, m);
            if (lane == 0) s_gl[g] = p + psb2[g];
        }
        __syncthreads();

        if (tid == 0) {
            int i1 = 0; float m1 = s_gl[0];
            #pragma unroll
            for (int g = 1; g < NG; ++g) if (s_gl[g] > m1) { m1 = s_gl[g]; i1 = g; }
            int i2 = -1; float m2 = -3.4e38f;
            #pragma unroll
            for (int g = 0; g < NG; ++g) if (g != i1 && s_gl[g] > m2) { m2 = s_gl[g]; i2 = g; }
            const float ex = expf(m2 - m1);
            const float inv = 1.0f / (1.0f + ex);
            s_sel[0] = i1; s_sel[1] = i2;
            s_wsel[0] = inv; s_wsel[1] = ex * inv;
        }
        __syncthreads();

        const int pr = w >> 1;
        const int gsel = s_sel[pr];
        if ((w & 1) == 0) {
            float ge = gfb[gsel * DFEMB + lane];
            #pragma unroll
            for (int f = 0; f < 8; ++f)
                ge = fmaf(feat[(size_t)t * FFEAT + gsel * 8 + f],
                          gfW[(size_t)(gsel * 8 + f) * DFEMB + lane], ge);
            s_tail[pr][lane] = ge;
        }
        __syncthreads();

        {
            const int col = (w & 1) * 64 + lane;
            float a = irb1[gsel * DRH + col];
            const float* W = irW1 + (size_t)gsel * RIN * DRH + col;
            #pragma unroll 8
            for (int k = 0; k < DMODEL; ++k)
                a = fmaf(s_rin[k], W[(size_t)k * DRH], a);
            #pragma unroll 8
            for (int k = 0; k < DFEMB; ++k)
                a = fmaf(s_tail[pr][k], W[(size_t)(DMODEL + k) * DRH], a);
            const float v = gelu_f(a);
            float e0 = v * irW2[(size_t)(gsel * DRH + col) * NES + 0];
            float e1 = v * irW2[(size_t)(gsel * DRH + col) * NES + 1];
            #pragma unroll
            for (int m = 1; m < 64; m <<= 1) {
                e0 += __shfl_xor(e0, m);
                e1 += __shfl_xor(e1, m);
            }
            if (lane == 0) { s_part[w][0] = e0; s_part[w][1] = e1; }
        }
        __syncthreads();

        if (tid == 0) {
            #pragma unroll
            for (int p2 = 0; p2 < 2; ++p2) {
                const float e0 = s_part[p2 * 2][0] + s_part[p2 * 2 + 1][0];
                const float e1 = s_part[p2 * 2][1] + s_part[p2 * 2 + 1][1];
                const int eid = s_sel[p2] * NES + ((e1 > e0) ? 1 : 0);
                const int pos = atomicAdd(&counts[eid], 1);
                list_tok[(size_t)eid * T_TOKENS + pos] = t;
                list_w[(size_t)eid * T_TOKENS + pos] = s_wsel[p2];
                list_slot[(size_t)eid * T_TOKENS + pos] = p2;
            }
        }
        __syncthreads();
    }
}

// ---------- Kernel 3: experts (fp16), contrib stores instead of atomics ----------
__global__ __launch_bounds__(256) void k_expert(
    const unsigned short* __restrict__ Ahi,
    const unsigned short* __restrict__ eW1T, const float* __restrict__ eb1,
    const unsigned short* __restrict__ eW2T, const float* __restrict__ eb2,
    const float* __restrict__ alpha_p,
    const int* __restrict__ counts, const int* __restrict__ list_tok,
    const float* __restrict__ list_w, const int* __restrict__ list_slot,
    unsigned short* __restrict__ contrib)
{
    __shared__ char smem[65536];
    unsigned short* sEH = (unsigned short*)smem;
    unsigned short* sA  = (unsigned short*)(smem + 32768);
    unsigned short* sB1 = (unsigned short*)(smem + 36864);
    unsigned short* sB2 = (unsigned short*)(smem + 32768);
    __shared__ int s_tok[64];
    __shared__ float s_w[64];
    __shared__ int s_pair[64];

    const int e = blockIdx.y;
    const int cnt = counts[e];
    const int base = blockIdx.x * 64;
    if (base >= cnt) return;
    const int nrow = min(64, cnt - base);
    const int tid = threadIdx.x, lane = tid & 63, w = tid >> 6;

    if (tid < 64) {
        const int src = base + ((tid < nrow) ? tid : (nrow - 1));
        s_tok[tid] = list_tok[(size_t)e * T_TOKENS + src];
        s_w[tid] = (tid < nrow) ? list_w[(size_t)e * T_TOKENS + base + tid] : 0.f;
        s_pair[tid] = s_tok[tid] * 2 + list_slot[(size_t)e * T_TOKENS + src];
    }
    __syncthreads();

    const int srow = w * 16 + (lane >> 2);
    const int stok = s_tok[srow];
    const int qcor = ((srow >> 1) & 3) ^ ((stok >> 1) & 3);
    const unsigned short* gA = Ahi + (size_t)stok * RIN + 8 * ((lane & 3) ^ qcor);
    unsigned short* dA = sA + w * 512;
    const int sgr = (lane & 3) * 8;
    const unsigned short* gB1[4];
    #pragma unroll
    for (int i = 0; i < 4; ++i)
        gB1[i] = eW1T + (size_t)e * DHID * DMODEL + (size_t)(w * 64 + i * 16 + (lane >> 2)) * DMODEL + sgr;

    const int arow = lane & 15, koff = (lane >> 4) * 8;
    const int q8r = ((arow >> 1) & 3) * 8;
    int aoff[4], b1off[4];
    #pragma unroll
    for (int m = 0; m < 4; ++m) aoff[m] = (m * 16 + arow) * 32 + (koff ^ q8r);
    #pragma unroll
    for (int n = 0; n < 4; ++n) b1off[n] = (w * 64 + n * 16 + arow) * 32 + (koff ^ q8r);

    f32x4 acc1[4][4];
    #pragma unroll
    for (int m = 0; m < 4; ++m)
        #pragma unroll
        for (int n = 0; n < 4; ++n) { acc1[m][n].x = 0.f; acc1[m][n].y = 0.f; acc1[m][n].z = 0.f; acc1[m][n].w = 0.f; }

    for (int kt = 0; kt < 16; ++kt) {
        const int kk = kt * 32;
        gl_lds16(gA + kk, dA);
        #pragma unroll
        for (int i = 0; i < 4; ++i) gl_lds16(gB1[i] + kk, sB1 + w * 2048 + i * 512);
        __syncthreads();
        f16x8 a[4];
        #pragma unroll
        for (int m = 0; m < 4; ++m) a[m] = *(const f16x8*)&sA[aoff[m]];
        #pragma unroll
        for (int n = 0; n < 4; ++n) {
            f16x8 b = *(const f16x8*)&sB1[b1off[n]];
            #pragma unroll
            for (int m = 0; m < 4; ++m) acc1[m][n] = MFMA16F(a[m], b, acc1[m][n]);
        }
        __syncthreads();
    }

    const int q = lane >> 4;
    #pragma unroll
    for (int m = 0; m < 4; ++m)
        #pragma unroll
        for (int n = 0; n < 4; ++n) {
            const int col = w * 64 + n * 16 + arow;
            const float bv = eb1[e * DHID + col];
            #pragma unroll
            for (int j = 0; j < 4; ++j) {
                const int rr = m * 16 + q * 4 + j;
                const int d = rr * 256 + (col & 0xE0) + ((col & 31) ^ (((rr >> 1) & 3) * 8));
                sEH[d] = f2h(gelu_f(acc1[m][n][j] + bv));
            }
        }
    __syncthreads();

    const unsigned short* gB2[8];
    #pragma unroll
    for (int i = 0; i < 8; ++i)
        gB2[i] = eW2T + (size_t)e * DMODEL * DHID + (size_t)(w * 128 + i * 16 + (lane >> 2)) * DHID + sgr;
    int a2base[4], b2off[8];
    #pragma unroll
    for (int m = 0; m < 4; ++m) a2base[m] = (m * 16 + arow) * 256 + (koff ^ q8r);
    #pragma unroll
    for (int n = 0; n < 8; ++n) b2off[n] = (w * 128 + n * 16 + arow) * 32 + (koff ^ q8r);

    f32x4 acc2[4][8];
    #pragma unroll
    for (int m = 0; m < 4; ++m)
        #pragma unroll
        for (int n = 0; n < 8; ++n) { acc2[m][n].x = 0.f; acc2[m][n].y = 0.f; acc2[m][n].z = 0.f; acc2[m][n].w = 0.f; }

    for (int kt = 0; kt < 8; ++kt) {
        #pragma unroll
        for (int i = 0; i < 8; ++i) gl_lds16(gB2[i] + kt * 32, sB2 + w * 4096 + i * 512);
        __syncthreads();
        f16x8 a[4];
        #pragma unroll
        for (int m = 0; m < 4; ++m) a[m] = *(const f16x8*)&sEH[a2base[m] + kt * 32];
        #pragma unroll
        for (int n = 0; n < 8; ++n) {
            f16x8 b = *(const f16x8*)&sB2[b2off[n]];
            #pragma unroll
            for (int m = 0; m < 4; ++m) acc2[m][n] = MFMA16F(a[m], b, acc2[m][n]);
        }
        __syncthreads();
    }

    const float alpha = alpha_p[0];
    #pragma unroll
    for (int m = 0; m < 4; ++m)
        #pragma unroll
        for (int n = 0; n < 8; ++n) {
            const int col = w * 128 + n * 16 + arow;
            const float b2v = eb2[e * DMODEL + col];
            #pragma unroll
            for (int j = 0; j < 4; ++j) {
                const int r = m * 16 + q * 4 + j;
                if (r < nrow)
                    contrib[(size_t)s_pair[r] * DMODEL + col] =
                        f2h(s_w[r] * alpha * (acc2[m][n][j] + b2v));
            }
        }
}

// ---------- Kernel 4: combine out = hidden + c0 + c1 ----------
__global__ __launch_bounds__(256) void k_combine(
    const float* __restrict__ hidden, const unsigned short* __restrict__ contrib,
    float* __restrict__ out)
{
    const size_t gid = (size_t)blockIdx.x * 256 + threadIdx.x;  // one 8-float chunk
    const int t = (int)(gid >> 6);
    const int c = (int)(gid & 63) * 8;
    const float* hp = hidden + (size_t)t * DMODEL + c;
    float4 h0 = ((const float4*)hp)[0];
    float4 h1 = ((const float4*)hp)[1];
    const unsigned short* c0p = contrib + ((size_t)t * 2 + 0) * DMODEL + c;
    const unsigned short* c1p = contrib + ((size_t)t * 2 + 1) * DMODEL + c;
    ushort4 a0 = ((const ushort4*)c0p)[0], a1 = ((const ushort4*)c0p)[1];
    ushort4 b0 = ((const ushort4*)c1p)[0], b1 = ((const ushort4*)c1p)[1];
    float4 o0, o1;
    o0.x = h0.x + h2f(a0.x) + h2f(b0.x);
    o0.y = h0.y + h2f(a0.y) + h2f(b0.y);
    o0.z = h0.z + h2f(a0.z) + h2f(b0.z);
    o0.w = h0.w + h2f(a0.w) + h2f(b0.w);
    o1.x = h1.x + h2f(a1.x) + h2f(b1.x);
    o1.y = h1.y + h2f(a1.y) + h2f(b1.y);
    o1.z = h1.z + h2f(a1.z) + h2f(b1.z);
    o1.w = h1.w + h2f(a1.w) + h2f(b1.w);
    float* op = out + (size_t)t * DMODEL + c;
    ((float4*)op)[0] = o0;
    ((float4*)op)[1] = o1;
}

// ---------- launch ----------
extern "C" void kernel_launch(void* const* d_in, const int* in_sizes, int n_in,
                              void* d_out, int out_size, void* d_ws, size_t ws_size,
                              hipStream_t stream) {
    const float* hidden = (const float*)d_in[0];
    const float* feat   = (const float*)d_in[1];
    const float* ln_g   = (const float*)d_in[2];
    const float* ln_b   = (const float*)d_in[3];
    const float* stageW = (const float*)d_in[4];
    const float* stageb = (const float*)d_in[5];
    const float* gfW    = (const float*)d_in[6];
    const float* gfb    = (const float*)d_in[7];
    const float* psW1   = (const float*)d_in[8];
    const float* psb1   = (const float*)d_in[9];
    const float* psW2   = (const float*)d_in[10];
    const float* psb2   = (const float*)d_in[11];
    const float* irW1   = (const float*)d_in[12];
    const float* irb1   = (const float*)d_in[13];
    const float* irW2   = (const float*)d_in[14];
    const float* irb2   = (const float*)d_in[15];
    const float* eW1    = (const float*)d_in[16];
    const float* eb1    = (const float*)d_in[17];
    const float* eW2    = (const float*)d_in[18];
    const float* eb2    = (const float*)d_in[19];
    const float* alpha  = (const float*)d_in[20];

    float* out = (float*)d_out;

    char* p = (char*)d_ws;
    unsigned short* Ahi = (unsigned short*)p; p += (size_t)T_TOKENS * RIN * 2;
    unsigned short* Bhi = (unsigned short*)p; p += (size_t)2048 * RIN * 2;
    unsigned short* eW1T = (unsigned short*)p; p += (size_t)NE * DHID * DMODEL * 2;
    unsigned short* eW2T = (unsigned short*)p; p += (size_t)NE * DMODEL * DHID * 2;
    unsigned short* contrib = (unsigned short*)p; p += (size_t)T_TOKENS * 2 * DMODEL * 2;
    float* Dps = (float*)p;   p += (size_t)NG * 64 * DRH * 4;
    float* Cir = (float*)p;   p += (size_t)NG * 8 * DRH * 4;
    float* fbps = (float*)p;  p += (size_t)NG * DRH * 4;
    float* fbir = (float*)p;  p += (size_t)NG * DRH * 4;
    float* glog_buf = (float*)p; p += (size_t)T_TOKENS * NG * 4;
    float* ilog_buf = (float*)p; p += (size_t)T_TOKENS * NG * NES * 4;
    int* counts = (int*)p;    p += 128;
    int* nfix = counts + 16;
    int* fix_list = (int*)p;  p += (size_t)T_TOKENS * 4;
    int* list_tok = (int*)p;  p += (size_t)NE * T_TOKENS * 4;
    float* list_w = (float*)p; p += (size_t)NE * T_TOKENS * 4;
    int* list_slot = (int*)p; p += (size_t)NE * T_TOKENS * 4;

    hipMemsetAsync(counts, 0, 128, stream);

    k_prep<<<T_TOKENS / 4, 256, 0, stream>>>(hidden, feat, ln_g, ln_b, Ahi);

    k_fold_ps<<<dim3(NG, 65), 128, 0, stream>>>(stageW, stageb, psW1, psb1, Dps, fbps);
    k_fold_ir<<<dim3(NG, 9), 128, 0, stream>>>(gfW, gfb, irW1, irb1, Cir, fbir);

    k_bsplitT<<<dim3(64, NG), 256, 0, stream>>>(
        psW1, Bhi, 512, DRH, RIN, 0, (long)RIN * DRH, (long)DRH * RIN);
    k_bsplitT<<<dim3(64, NG), 256, 0, stream>>>(
        irW1, Bhi + (size_t)1024 * RIN, 512, DRH, RIN, 0, (long)RIN * DRH, (long)DRH * RIN);
    k_bsplitT<<<dim3(8, NG), 256, 0, stream>>>(
        Dps, Bhi, 64, DRH, RIN, 512, (long)64 * DRH, (long)DRH * RIN);
    k_irtail<<<NG, 128, 0, stream>>>(Cir, Bhi);

    k_bsplitT<<<dim3(128, NE), 256, 0, stream>>>(
        eW1, eW1T, DMODEL, DHID, DMODEL, 0, (long)DMODEL * DHID, (long)DHID * DMODEL);
    k_bsplitT<<<dim3(128, NE), 256, 0, stream>>>(
        eW2, eW2T, DHID, DMODEL, DHID, 0, (long)DHID * DMODEL, (long)DMODEL * DHID);

    k_rgemm<<<dim3(T_TOKENS / 128, 8), 512, 0, stream>>>(
        Ahi, Bhi, fbps, psW2, psb2, fbir, irW2, irb2, glog_buf, ilog_buf);

    hg_finalize2<<<T_TOKENS / 256, 256, 0, stream>>>(
        glog_buf, ilog_buf, counts, nfix, fix_list, list_tok, list_w, list_slot);

    hg_fixup<<<1024, 256, 0, stream>>>(
        hidden, feat, ln_g, ln_b, stageW, stageb, gfW, gfb,
        psW1, psb1, psW2, psb2, irW1, irb1, irW2, irb2,
        nfix, fix_list, counts, list_tok, list_w, list_slot);

    k_expert<<<dim3(T_TOKENS / 64, NE), 256, 0, stream>>>(
        Ahi, eW1T, eb1, eW2T, eb2, alpha, counts, list_tok, list_w, list_slot, contrib);

    k_combine<<<(T_TOKENS * DMODEL / 8) / 256, 256, 0, stream>>>(hidden, contrib, out);
}

// Round 9
// 448.957 us; speedup vs baseline: 4.9293x; 1.0998x over previous
//
#include <hip/hip_runtime.h>
#include <hip/hip_bf16.h>

#define T_TOKENS 16384
#define DMODEL 512
#define FFEAT 64
#define DFEMB 64
#define RIN 576
#define DRH 128
#define NG 8
#define NES 2
#define NE 16
#define DHID 256

typedef float f32x4 __attribute__((ext_vector_type(4)));
typedef _Float16 f16x8 __attribute__((ext_vector_type(8)));
#define MFMA16F(a, b, c) __builtin_amdgcn_mfma_f32_16x16x32_f16((a), (b), (c), 0, 0, 0)

__device__ __forceinline__ float gelu_f(float x) {
    return 0.5f * x * (1.0f + erff(x * 0.7071067811865476f));
}
__device__ __forceinline__ unsigned short f2h(float x) {
    _Float16 h = (_Float16)x;
    union { _Float16 f; unsigned short u; } v; v.f = h;
    return v.u;
}
__device__ __forceinline__ float h2f(unsigned short u) {
    union { unsigned short u; _Float16 f; } v; v.u = u;
    return (float)v.f;
}
__device__ __forceinline__ void gl_lds16(const unsigned short* g, unsigned short* l) {
    __builtin_amdgcn_global_load_lds(
        (const __attribute__((address_space(1))) unsigned int*)g,
        (__attribute__((address_space(3))) unsigned int*)l, 16, 0, 0);
}

// ---------- Kernel 1: LN + fp16 swizzled A ----------
__global__ __launch_bounds__(256) void k_prep(
    const float* __restrict__ hidden, const float* __restrict__ feat,
    const float* __restrict__ lng, const float* __restrict__ lnb,
    unsigned short* __restrict__ Ahi)
{
    const int t = blockIdx.x * 4 + (threadIdx.x >> 6);
    const int lane = threadIdx.x & 63;
    const float* row = hidden + (size_t)t * DMODEL;
    float4 v0 = ((const float4*)row)[lane * 2 + 0];
    float4 v1 = ((const float4*)row)[lane * 2 + 1];
    float s = v0.x + v0.y + v0.z + v0.w + v1.x + v1.y + v1.z + v1.w;
    #pragma unroll
    for (int m = 1; m < 64; m <<= 1) s += __shfl_xor(s, m);
    const float mu = s * (1.0f / DMODEL);
    float sq = 0.f;
    { float d;
      d = v0.x - mu; sq += d * d; d = v0.y - mu; sq += d * d;
      d = v0.z - mu; sq += d * d; d = v0.w - mu; sq += d * d;
      d = v1.x - mu; sq += d * d; d = v1.y - mu; sq += d * d;
      d = v1.z - mu; sq += d * d; d = v1.w - mu; sq += d * d; }
    #pragma unroll
    for (int m = 1; m < 64; m <<= 1) sq += __shfl_xor(sq, m);
    const float rstd = rsqrtf(sq * (1.0f / DMODEL) + 1e-5f);
    float4 g0 = ((const float4*)lng)[lane * 2 + 0];
    float4 g1 = ((const float4*)lng)[lane * 2 + 1];
    float4 b0 = ((const float4*)lnb)[lane * 2 + 0];
    float4 b1 = ((const float4*)lnb)[lane * 2 + 1];
    float h[8];
    h[0] = (v0.x - mu) * rstd * g0.x + b0.x;
    h[1] = (v0.y - mu) * rstd * g0.y + b0.y;
    h[2] = (v0.z - mu) * rstd * g0.z + b0.z;
    h[3] = (v0.w - mu) * rstd * g0.w + b0.w;
    h[4] = (v1.x - mu) * rstd * g1.x + b1.x;
    h[5] = (v1.y - mu) * rstd * g1.y + b1.y;
    h[6] = (v1.z - mu) * rstd * g1.z + b1.z;
    h[7] = (v1.w - mu) * rstd * g1.w + b1.w;
    const int q8 = ((t >> 1) & 3) * 8;
    ushort4 H0, H1;
    H0.x = f2h(h[0]); H0.y = f2h(h[1]); H0.z = f2h(h[2]); H0.w = f2h(h[3]);
    H1.x = f2h(h[4]); H1.y = f2h(h[5]); H1.z = f2h(h[6]); H1.w = f2h(h[7]);
    unsigned short* pa = Ahi + (size_t)t * RIN;
    const int dst = (lane >> 2) * 32 + (((lane & 3) * 8) ^ q8);
    *(ushort4*)&pa[dst] = H0;  *(ushort4*)&pa[dst + 4] = H1;
    const float fv = feat[(size_t)t * FFEAT + lane];
    const int fd = DMODEL + (lane & 32) + ((lane & 31) ^ q8);
    pa[fd] = f2h(fv);
}

// ---------- fold kernels ----------
__global__ __launch_bounds__(128) void k_fold_ps(
    const float* __restrict__ stageW, const float* __restrict__ stageb,
    const float* __restrict__ psW1, const float* __restrict__ psb1,
    float* __restrict__ Dps, float* __restrict__ fbps)
{
    const int g = blockIdx.x, f = blockIdx.y, c = threadIdx.x;
    const float* Wt = psW1 + (size_t)g * RIN * DRH + (size_t)DMODEL * DRH;
    float acc = 0.f;
    if (f < 64) {
        for (int j = 0; j < DFEMB; ++j) acc = fmaf(stageW[f * DFEMB + j], Wt[(size_t)j * DRH + c], acc);
        Dps[((size_t)g * 64 + f) * DRH + c] = acc;
    } else {
        for (int j = 0; j < DFEMB; ++j) acc = fmaf(stageb[j], Wt[(size_t)j * DRH + c], acc);
        fbps[g * DRH + c] = acc + psb1[g * DRH + c];
    }
}

__global__ __launch_bounds__(128) void k_fold_ir(
    const float* __restrict__ gfW, const float* __restrict__ gfb,
    const float* __restrict__ irW1, const float* __restrict__ irb1,
    float* __restrict__ Cir, float* __restrict__ fbir)
{
    const int g = blockIdx.x, f = blockIdx.y, c = threadIdx.x;
    const float* Wt = irW1 + (size_t)g * RIN * DRH + (size_t)DMODEL * DRH;
    float acc = 0.f;
    if (f < 8) {
        for (int j = 0; j < DFEMB; ++j) acc = fmaf(gfW[(size_t)(g * 8 + f) * DFEMB + j], Wt[(size_t)j * DRH + c], acc);
        Cir[((size_t)g * 8 + f) * DRH + c] = acc;
    } else {
        for (int j = 0; j < DFEMB; ++j) acc = fmaf(gfb[g * DFEMB + j], Wt[(size_t)j * DRH + c], acc);
        fbir[g * DRH + c] = acc + irb1[g * DRH + c];
    }
}

// ---------- transpose + fp16, swizzled dest: in[K][N] -> out[N][K'] ----------
__global__ __launch_bounds__(256) void k_bsplitT(
    const float* __restrict__ in, unsigned short* __restrict__ outHi,
    int K, int N, int outStride, int kOff, long inBS, long outBS)
{
    __shared__ float s_t[32][33];
    const int b = blockIdx.y;
    const int tilesN = N >> 5;
    const int ko = (blockIdx.x / tilesN) << 5;
    const int no = (blockIdx.x % tilesN) << 5;
    const int r = threadIdx.x >> 3, c0 = (threadIdx.x & 7) * 4;
    {
        float4 v = *(const float4*)(in + (size_t)b * inBS + (size_t)(ko + r) * N + no + c0);
        s_t[r][c0] = v.x; s_t[r][c0 + 1] = v.y; s_t[r][c0 + 2] = v.z; s_t[r][c0 + 3] = v.w;
    }
    __syncthreads();
    float vv[4];
    #pragma unroll
    for (int j = 0; j < 4; ++j) vv[j] = s_t[c0 + j][r];
    const int col = no + r;
    const int q8 = ((col >> 1) & 3) * 8;
    ushort4 hi;
    hi.x = f2h(vv[0]); hi.y = f2h(vv[1]); hi.z = f2h(vv[2]); hi.w = f2h(vv[3]);
    *(ushort4*)(outHi + (size_t)b * outBS + (size_t)col * outStride + kOff + ko + (c0 ^ q8)) = hi;
}

// ---------- ir tail rows of B ----------
__global__ __launch_bounds__(128) void k_irtail(
    const float* __restrict__ Cir, unsigned short* __restrict__ Bhi)
{
    const int g = blockIdx.x, c = threadIdx.x;
    const int col = 1024 + g * DRH + c;
    const int q8 = ((col >> 1) & 3) * 8;
    unsigned short* ph = Bhi + (size_t)col * RIN + DMODEL;
    for (int f = 0; f < 64; ++f) {
        float v = ((f >> 3) == g) ? Cir[((size_t)g * 8 + (f & 7)) * DRH + c] : 0.f;
        const int d = (f & 32) + ((f & 31) ^ q8);
        ph[d] = f2h(v);
    }
}

// ---------- Kernel 2: router GEMM, fp16, double-buffered pipeline ----------
__global__ __launch_bounds__(512) void k_rgemm(
    const unsigned short* __restrict__ Ahi, const unsigned short* __restrict__ Bhi,
    const float* __restrict__ fbps, const float* __restrict__ psW2, const float* __restrict__ psb2,
    const float* __restrict__ fbir, const float* __restrict__ irW2, const float* __restrict__ irb2,
    float* __restrict__ glog, float* __restrict__ ilog)
{
    __shared__ unsigned short sAh[2][128 * 32];
    __shared__ unsigned short sBh[2][256 * 32];
    __shared__ float s_red[2][4][64][2];

    const int tid = threadIdx.x, lane = tid & 63, w = tid >> 6;
    const int t0 = blockIdx.x * 128, bn = blockIdx.y;
    const int wm = w >> 2, wn = w & 3;
    const int arow = lane & 15, koff = (lane >> 4) * 8;
    const int q8r = ((arow >> 1) & 3) * 8;

    int aoff[4], boff[4];
    #pragma unroll
    for (int m = 0; m < 4; ++m) aoff[m] = (wm * 64 + m * 16 + arow) * 32 + (koff ^ q8r);
    #pragma unroll
    for (int n = 0; n < 4; ++n) boff[n] = (wn * 64 + n * 16 + arow) * 32 + (koff ^ q8r);

    const int srow = w * 16 + (lane >> 2);
    const int sgr = (lane & 3) * 8;
    const unsigned short* gAh = Ahi + (size_t)(t0 + srow) * RIN + sgr;
    const unsigned short* gBh0 = Bhi + (size_t)(bn * 256 + w * 32 + (lane >> 2)) * RIN + sgr;
    const unsigned short* gBh1 = gBh0 + (size_t)16 * RIN;

    f32x4 acc[4][4];
    #pragma unroll
    for (int m = 0; m < 4; ++m)
        #pragma unroll
        for (int n = 0; n < 4; ++n) { acc[m][n].x = 0.f; acc[m][n].y = 0.f; acc[m][n].z = 0.f; acc[m][n].w = 0.f; }

    auto STAGE = [&](int b, int kt) {
        const int kk = kt * 32;
        gl_lds16(gAh + kk, &sAh[b][w * 512]);
        gl_lds16(gBh0 + kk, &sBh[b][w * 1024]);
        gl_lds16(gBh1 + kk, &sBh[b][w * 1024 + 512]);
    };

    STAGE(0, 0);
    __syncthreads();
    int buf = 0;
    for (int kt = 0; kt < 18; ++kt) {
        if (kt + 1 < 18) STAGE(buf ^ 1, kt + 1);
        f16x8 ah[4];
        #pragma unroll
        for (int m = 0; m < 4; ++m) ah[m] = *(const f16x8*)&sAh[buf][aoff[m]];
        #pragma unroll
        for (int n = 0; n < 4; ++n) {
            f16x8 b = *(const f16x8*)&sBh[buf][boff[n]];
            #pragma unroll
            for (int m = 0; m < 4; ++m) acc[m][n] = MFMA16F(ah[m], b, acc[m][n]);
        }
        __syncthreads();
        buf ^= 1;
    }

    // fused second layers
    const int grp = wn >> 1;
    const bool isPS = (bn < 4);
    const int g = isPS ? (bn * 2 + grp) : ((bn - 4) * 2 + grp);
    const int q = lane >> 4;
    if (isPS) {
        float r0[4][4] = {};
        #pragma unroll
        for (int n = 0; n < 4; ++n) {
            const int cg = (wn & 1) * 64 + n * 16 + arow;
            const float b1 = fbps[g * DRH + cg];
            const float w2 = psW2[g * DRH + cg];
            #pragma unroll
            for (int m = 0; m < 4; ++m)
                #pragma unroll
                for (int j = 0; j < 4; ++j)
                    r0[m][j] += gelu_f(acc[m][n][j] + b1) * w2;
        }
        #pragma unroll
        for (int mk = 1; mk < 16; mk <<= 1)
            #pragma unroll
            for (int m = 0; m < 4; ++m)
                #pragma unroll
                for (int j = 0; j < 4; ++j) r0[m][j] += __shfl_xor(r0[m][j], mk);
        if (arow == 0) {
            #pragma unroll
            for (int m = 0; m < 4; ++m)
                #pragma unroll
                for (int j = 0; j < 4; ++j) {
                    s_red[wm][wn][m * 16 + q * 4 + j][0] = r0[m][j];
                    s_red[wm][wn][m * 16 + q * 4 + j][1] = 0.f;
                }
        }
    } else {
        float r0[4][4] = {}, r1[4][4] = {};
        #pragma unroll
        for (int n = 0; n < 4; ++n) {
            const int cg = (wn & 1) * 64 + n * 16 + arow;
            const float b1 = fbir[g * DRH + cg];
            const float w20 = irW2[(size_t)(g * DRH + cg) * NES + 0];
            const float w21 = irW2[(size_t)(g * DRH + cg) * NES + 1];
            #pragma unroll
            for (int m = 0; m < 4; ++m)
                #pragma unroll
                for (int j = 0; j < 4; ++j) {
                    const float v = gelu_f(acc[m][n][j] + b1);
                    r0[m][j] = fmaf(v, w20, r0[m][j]);
                    r1[m][j] = fmaf(v, w21, r1[m][j]);
                }
        }
        #pragma unroll
        for (int mk = 1; mk < 16; mk <<= 1)
            #pragma unroll
            for (int m = 0; m < 4; ++m)
                #pragma unroll
                for (int j = 0; j < 4; ++j) {
                    r0[m][j] += __shfl_xor(r0[m][j], mk);
                    r1[m][j] += __shfl_xor(r1[m][j], mk);
                }
        if (arow == 0) {
            #pragma unroll
            for (int m = 0; m < 4; ++m)
                #pragma unroll
                for (int j = 0; j < 4; ++j) {
                    s_red[wm][wn][m * 16 + q * 4 + j][0] = r0[m][j];
                    s_red[wm][wn][m * 16 + q * 4 + j][1] = r1[m][j];
                }
        }
    }
    __syncthreads();
    if (tid < 256) {
        const int row = tid >> 1, sub = tid & 1;
        const int rl = row & 63, wmm = row >> 6;
        if (isPS) {
            const int gg = bn * 2 + sub;
            glog[(size_t)(t0 + row) * NG + gg] =
                s_red[wmm][sub * 2][rl][0] + s_red[wmm][sub * 2 + 1][rl][0] + psb2[gg];
        } else {
            const int gg = (bn - 4) * 2 + sub;
            const size_t bidx = ((size_t)(t0 + row) * NG + gg) * NES;
            ilog[bidx + 0] = s_red[wmm][sub * 2][rl][0] + s_red[wmm][sub * 2 + 1][rl][0] + irb2[gg * NES + 0];
            ilog[bidx + 1] = s_red[wmm][sub * 2][rl][1] + s_red[wmm][sub * 2 + 1][rl][1] + irb2[gg * NES + 1];
        }
    }
}

// ---------- Kernel 2b: finalize with margin check ----------
#define MARGIN 8e-3f
__global__ __launch_bounds__(256) void hg_finalize2(
    const float* __restrict__ glog_buf, const float* __restrict__ ilog_buf,
    int* __restrict__ counts, int* __restrict__ nfix, int* __restrict__ fix_list,
    int* __restrict__ list_tok, float* __restrict__ list_w, int* __restrict__ list_slot)
{
    const int t = blockIdx.x * 256 + threadIdx.x;
    float gl[NG];
    *(float4*)&gl[0] = ((const float4*)(glog_buf + (size_t)t * NG))[0];
    *(float4*)&gl[4] = ((const float4*)(glog_buf + (size_t)t * NG))[1];
    int i1 = 0; float m1 = gl[0];
    #pragma unroll
    for (int g = 1; g < NG; ++g) if (gl[g] > m1) { m1 = gl[g]; i1 = g; }
    int i2 = -1; float m2 = -3.4e38f;
    #pragma unroll
    for (int g = 0; g < NG; ++g) if (g != i1 && gl[g] > m2) { m2 = gl[g]; i2 = g; }
    float m3 = -3.4e38f;
    #pragma unroll
    for (int g = 0; g < NG; ++g) if (g != i1 && g != i2 && gl[g] > m3) m3 = gl[g];

    const float ila0 = ilog_buf[((size_t)t * NG + i1) * NES + 0];
    const float ila1 = ilog_buf[((size_t)t * NG + i1) * NES + 1];
    const float ilb0 = ilog_buf[((size_t)t * NG + i2) * NES + 0];
    const float ilb1 = ilog_buf[((size_t)t * NG + i2) * NES + 1];

    const bool flag = ((m2 - m3) < MARGIN) || (fabsf(ila1 - ila0) < MARGIN)
                   || (fabsf(ilb1 - ilb0) < MARGIN);
    if (flag) {
        const int p = atomicAdd(nfix, 1);
        fix_list[p] = t;
        return;
    }
    const float ex = expf(m2 - m1);
    const float inv = 1.0f / (1.0f + ex);
    const int   gsel[2] = {i1, i2};
    const float wsel[2] = {inv, ex * inv};
    const int   ksel[2] = {(ila1 > ila0) ? 1 : 0, (ilb1 > ilb0) ? 1 : 0};
    #pragma unroll
    for (int s = 0; s < 2; ++s) {
        const int eid = gsel[s] * NES + ksel[s];
        const int pos = atomicAdd(&counts[eid], 1);
        list_tok[(size_t)eid * T_TOKENS + pos] = t;
        list_w[(size_t)eid * T_TOKENS + pos] = wsel[s];
        list_slot[(size_t)eid * T_TOKENS + pos] = s;
    }
}

// ---------- Kernel 2c: exact fp32 fixup, 4-wave parallel, unrolled ----------
__global__ __launch_bounds__(256) void hg_fixup(
    const float* __restrict__ hidden, const float* __restrict__ feat,
    const float* __restrict__ lng, const float* __restrict__ lnb,
    const float* __restrict__ stageW, const float* __restrict__ stageb,
    const float* __restrict__ gfW, const float* __restrict__ gfb,
    const float* __restrict__ psW1, const float* __restrict__ psb1,
    const float* __restrict__ psW2, const float* __restrict__ psb2,
    const float* __restrict__ irW1, const float* __restrict__ irb1,
    const float* __restrict__ irW2, const float* __restrict__ irb2,
    const int* __restrict__ nfix, const int* __restrict__ fix_list,
    int* __restrict__ counts, int* __restrict__ list_tok, float* __restrict__ list_w,
    int* __restrict__ list_slot)
{
    __shared__ float s_rin[RIN];
    __shared__ float s_tail[2][DFEMB];
    __shared__ float s_gl[NG];
    __shared__ float s_part[4][2];
    __shared__ int s_sel[2];
    __shared__ float s_wsel[2];

    const int tid = threadIdx.x, lane = tid & 63, w = tid >> 6;
    const int nf = nfix[0];
    for (int idx = blockIdx.x; idx < nf; idx += gridDim.x) {
        const int t = fix_list[idx];
        if (w == 0) {
            const float* row = hidden + (size_t)t * DMODEL;
            float4 v0 = ((const float4*)row)[lane * 2 + 0];
            float4 v1 = ((const float4*)row)[lane * 2 + 1];
            float s = v0.x + v0.y + v0.z + v0.w + v1.x + v1.y + v1.z + v1.w;
            #pragma unroll
            for (int m = 1; m < 64; m <<= 1) s += __shfl_xor(s, m);
            const float mu = s * (1.0f / DMODEL);
            float sq = 0.f;
            { float d;
              d = v0.x - mu; sq += d * d; d = v0.y - mu; sq += d * d;
              d = v0.z - mu; sq += d * d; d = v0.w - mu; sq += d * d;
              d = v1.x - mu; sq += d * d; d = v1.y - mu; sq += d * d;
              d = v1.z - mu; sq += d * d; d = v1.w - mu; sq += d * d; }
            #pragma unroll
            for (int m = 1; m < 64; m <<= 1) sq += __shfl_xor(sq, m);
            const float rstd = rsqrtf(sq * (1.0f / DMODEL) + 1e-5f);
            float4 g0 = ((const float4*)lng)[lane * 2 + 0];
            float4 g1 = ((const float4*)lng)[lane * 2 + 1];
            float4 b0 = ((const float4*)lnb)[lane * 2 + 0];
            float4 b1 = ((const float4*)lnb)[lane * 2 + 1];
            s_rin[lane * 8 + 0] = (v0.x - mu) * rstd * g0.x + b0.x;
            s_rin[lane * 8 + 1] = (v0.y - mu) * rstd * g0.y + b0.y;
            s_rin[lane * 8 + 2] = (v0.z - mu) * rstd * g0.z + b0.z;
            s_rin[lane * 8 + 3] = (v0.w - mu) * rstd * g0.w + b0.w;
            s_rin[lane * 8 + 4] = (v1.x - mu) * rstd * g1.x + b1.x;
            s_rin[lane * 8 + 5] = (v1.y - mu) * rstd * g1.y + b1.y;
            s_rin[lane * 8 + 6] = (v1.z - mu) * rstd * g1.z + b1.z;
            s_rin[lane * 8 + 7] = (v1.w - mu) * rstd * g1.w + b1.w;
        } else if (w == 1) {
            float se = stageb[lane];
            #pragma unroll 8
            for (int f = 0; f < FFEAT; ++f)
                se = fmaf(feat[(size_t)t * FFEAT + f], stageW[f * DFEMB + lane], se);
            s_rin[DMODEL + lane] = se;
        }
        __syncthreads();

        #pragma unroll
        for (int gi = 0; gi < 2; ++gi) {
            const int g = w * 2 + gi;
            float a0 = psb1[g * DRH + lane];
            float a1 = psb1[g * DRH + 64 + lane];
            const float* W = psW1 + (size_t)g * RIN * DRH;
            #pragma unroll 8
            for (int k = 0; k < RIN; ++k) {
                const float r = s_rin[k];
                a0 = fmaf(r, W[(size_t)k * DRH + lane], a0);
                a1 = fmaf(r, W[(size_t)k * DRH + 64 + lane], a1);
            }
            float p = gelu_f(a0) * psW2[g * DRH + lane] + gelu_f(a1) * psW2[g * DRH + 64 + lane];
            #pragma unroll
            for (int m = 1; m < 64; m <<= 1) p += __shfl_xor(p, m);
            if (lane == 0) s_gl[g] = p + psb2[g];
        }
        __syncthreads();

        if (tid == 0) {
            int i1 = 0; float m1 = s_gl[0];
            #pragma unroll
            for (int g = 1; g < NG; ++g) if (s_gl[g] > m1) { m1 = s_gl[g]; i1 = g; }
            int i2 = -1; float m2 = -3.4e38f;
            #pragma unroll
            for (int g = 0; g < NG; ++g) if (g != i1 && s_gl[g] > m2) { m2 = s_gl[g]; i2 = g; }
            const float ex = expf(m2 - m1);
            const float inv = 1.0f / (1.0f + ex);
            s_sel[0] = i1; s_sel[1] = i2;
            s_wsel[0] = inv; s_wsel[1] = ex * inv;
        }
        __syncthreads();

        const int pr = w >> 1;
        const int gsel = s_sel[pr];
        if ((w & 1) == 0) {
            float ge = gfb[gsel * DFEMB + lane];
            #pragma unroll
            for (int f = 0; f < 8; ++f)
                ge = fmaf(feat[(size_t)t * FFEAT + gsel * 8 + f],
                          gfW[(size_t)(gsel * 8 + f) * DFEMB + lane], ge);
            s_tail[pr][lane] = ge;
        }
        __syncthreads();

        {
            const int col = (w & 1) * 64 + lane;
            float a = irb1[gsel * DRH + col];
            const float* W = irW1 + (size_t)gsel * RIN * DRH + col;
            #pragma unroll 8
            for (int k = 0; k < DMODEL; ++k)
                a = fmaf(s_rin[k], W[(size_t)k * DRH], a);
            #pragma unroll 8
            for (int k = 0; k < DFEMB; ++k)
                a = fmaf(s_tail[pr][k], W[(size_t)(DMODEL + k) * DRH], a);
            const float v = gelu_f(a);
            float e0 = v * irW2[(size_t)(gsel * DRH + col) * NES + 0];
            float e1 = v * irW2[(size_t)(gsel * DRH + col) * NES + 1];
            #pragma unroll
            for (int m = 1; m < 64; m <<= 1) {
                e0 += __shfl_xor(e0, m);
                e1 += __shfl_xor(e1, m);
            }
            if (lane == 0) { s_part[w][0] = e0; s_part[w][1] = e1; }
        }
        __syncthreads();

        if (tid == 0) {
            #pragma unroll
            for (int p2 = 0; p2 < 2; ++p2) {
                const float e0 = s_part[p2 * 2][0] + s_part[p2 * 2 + 1][0];
                const float e1 = s_part[p2 * 2][1] + s_part[p2 * 2 + 1][1];
                const int eid = s_sel[p2] * NES + ((e1 > e0) ? 1 : 0);
                const int pos = atomicAdd(&counts[eid], 1);
                list_tok[(size_t)eid * T_TOKENS + pos] = t;
                list_w[(size_t)eid * T_TOKENS + pos] = s_wsel[p2];
                list_slot[(size_t)eid * T_TOKENS + pos] = p2;
            }
        }
        __syncthreads();
    }
}

// ---------- Kernel 3a: expert GEMM1 -> ehbuf (fp16, swizzled by tile-row) ----------
__global__ __launch_bounds__(256) void k_e1(
    const unsigned short* __restrict__ Ahi,
    const unsigned short* __restrict__ eW1T, const float* __restrict__ eb1,
    const int* __restrict__ counts, const int* __restrict__ list_tok,
    const int* __restrict__ list_slot, unsigned short* __restrict__ ehbuf)
{
    __shared__ unsigned short sA[2][64 * 32];
    __shared__ unsigned short sB[2][256 * 32];
    __shared__ int s_tok[64];
    __shared__ int s_pair[64];

    const int e = blockIdx.y;
    const int cnt = counts[e];
    const int base = blockIdx.x * 64;
    if (base >= cnt) return;
    const int nrow = min(64, cnt - base);
    const int tid = threadIdx.x, lane = tid & 63, w = tid >> 6;

    if (tid < 64) {
        const int src = base + ((tid < nrow) ? tid : (nrow - 1));
        s_tok[tid] = list_tok[(size_t)e * T_TOKENS + src];
        s_pair[tid] = s_tok[tid] * 2 + list_slot[(size_t)e * T_TOKENS + src];
    }
    __syncthreads();

    const int srow = w * 16 + (lane >> 2);
    const int stok = s_tok[srow];
    const int qcor = ((srow >> 1) & 3) ^ ((stok >> 1) & 3);
    const unsigned short* gA = Ahi + (size_t)stok * RIN + 8 * ((lane & 3) ^ qcor);
    const int sgr = (lane & 3) * 8;
    const unsigned short* gB[4];
    #pragma unroll
    for (int i = 0; i < 4; ++i)
        gB[i] = eW1T + (size_t)e * DHID * DMODEL + (size_t)(w * 64 + i * 16 + (lane >> 2)) * DMODEL + sgr;

    const int arow = lane & 15, koff = (lane >> 4) * 8;
    const int q8r = ((arow >> 1) & 3) * 8;
    int aoff[4], boff[4];
    #pragma unroll
    for (int m = 0; m < 4; ++m) aoff[m] = (m * 16 + arow) * 32 + (koff ^ q8r);
    #pragma unroll
    for (int n = 0; n < 4; ++n) boff[n] = (w * 64 + n * 16 + arow) * 32 + (koff ^ q8r);

    f32x4 acc[4][4];
    #pragma unroll
    for (int m = 0; m < 4; ++m)
        #pragma unroll
        for (int n = 0; n < 4; ++n) { acc[m][n].x = 0.f; acc[m][n].y = 0.f; acc[m][n].z = 0.f; acc[m][n].w = 0.f; }

    auto STAGE = [&](int b, int kt) {
        const int kk = kt * 32;
        gl_lds16(gA + kk, &sA[b][w * 512]);
        #pragma unroll
        for (int i = 0; i < 4; ++i) gl_lds16(gB[i] + kk, &sB[b][w * 2048 + i * 512]);
    };

    STAGE(0, 0);
    __syncthreads();
    int buf = 0;
    for (int kt = 0; kt < 16; ++kt) {
        if (kt + 1 < 16) STAGE(buf ^ 1, kt + 1);
        f16x8 a[4];
        #pragma unroll
        for (int m = 0; m < 4; ++m) a[m] = *(const f16x8*)&sA[buf][aoff[m]];
        #pragma unroll
        for (int n = 0; n < 4; ++n) {
            f16x8 b = *(const f16x8*)&sB[buf][boff[n]];
            #pragma unroll
            for (int m = 0; m < 4; ++m) acc[m][n] = MFMA16F(a[m], b, acc[m][n]);
        }
        __syncthreads();
        buf ^= 1;
    }

    const int q = lane >> 4;
    #pragma unroll
    for (int m = 0; m < 4; ++m)
        #pragma unroll
        for (int n = 0; n < 4; ++n) {
            const int col = w * 64 + n * 16 + arow;
            const float bv = eb1[e * DHID + col];
            #pragma unroll
            for (int j = 0; j < 4; ++j) {
                const int rr = m * 16 + q * 4 + j;
                if (rr < nrow) {   // padded rows alias real ehbuf rows with a different swizzle key -> must skip
                    const size_t d = (size_t)s_pair[rr] * DHID
                                   + (col & 0xE0) + ((col & 31) ^ (((rr >> 1) & 3) * 8));
                    ehbuf[d] = f2h(gelu_f(acc[m][n][j] + bv));
                }
            }
        }
}

// ---------- Kernel 3b: expert GEMM2 -> contrib ----------
__global__ __launch_bounds__(256) void k_e2(
    const unsigned short* __restrict__ ehbuf,
    const unsigned short* __restrict__ eW2T, const float* __restrict__ eb2,
    const float* __restrict__ alpha_p,
    const int* __restrict__ counts, const int* __restrict__ list_tok,
    const float* __restrict__ list_w, const int* __restrict__ list_slot,
    unsigned short* __restrict__ contrib)
{
    __shared__ unsigned short sA[2][64 * 32];
    __shared__ unsigned short sB[2][256 * 32];
    __shared__ int s_pair[64];
    __shared__ float s_w[64];

    const int e = blockIdx.y;
    const int cnt = counts[e];
    const int base = blockIdx.x * 64;
    if (base >= cnt) return;
    const int ch = blockIdx.z;
    const int nrow = min(64, cnt - base);
    const int tid = threadIdx.x, lane = tid & 63, w = tid >> 6;

    if (tid < 64) {
        const int src = base + ((tid < nrow) ? tid : (nrow - 1));
        const int tok = list_tok[(size_t)e * T_TOKENS + src];
        s_pair[tid] = tok * 2 + list_slot[(size_t)e * T_TOKENS + src];
        s_w[tid] = (tid < nrow) ? list_w[(size_t)e * T_TOKENS + base + tid] : 0.f;
    }
    __syncthreads();

    const int srow = w * 16 + (lane >> 2);
    const unsigned short* gA = ehbuf + (size_t)s_pair[srow] * DHID + (lane & 3) * 8;
    const int sgr = (lane & 3) * 8;
    const unsigned short* gB[4];
    #pragma unroll
    for (int i = 0; i < 4; ++i)
        gB[i] = eW2T + (size_t)e * DMODEL * DHID
              + (size_t)(ch * 256 + w * 64 + i * 16 + (lane >> 2)) * DHID + sgr;

    const int arow = lane & 15, koff = (lane >> 4) * 8;
    const int q8r = ((arow >> 1) & 3) * 8;
    int aoff[4], boff[4];
    #pragma unroll
    for (int m = 0; m < 4; ++m) aoff[m] = (m * 16 + arow) * 32 + (koff ^ q8r);
    #pragma unroll
    for (int n = 0; n < 4; ++n) boff[n] = (w * 64 + n * 16 + arow) * 32 + (koff ^ q8r);

    f32x4 acc[4][4];
    #pragma unroll
    for (int m = 0; m < 4; ++m)
        #pragma unroll
        for (int n = 0; n < 4; ++n) { acc[m][n].x = 0.f; acc[m][n].y = 0.f; acc[m][n].z = 0.f; acc[m][n].w = 0.f; }

    auto STAGE = [&](int b, int kt) {
        const int kk = kt * 32;
        gl_lds16(gA + kk, &sA[b][w * 512]);
        #pragma unroll
        for (int i = 0; i < 4; ++i) gl_lds16(gB[i] + kk, &sB[b][w * 2048 + i * 512]);
    };

    STAGE(0, 0);
    __syncthreads();
    int buf = 0;
    for (int kt = 0; kt < 8; ++kt) {
        if (kt + 1 < 8) STAGE(buf ^ 1, kt + 1);
        f16x8 a[4];
        #pragma unroll
        for (int m = 0; m < 4; ++m) a[m] = *(const f16x8*)&sA[buf][aoff[m]];
        #pragma unroll
        for (int n = 0; n < 4; ++n) {
            f16x8 b = *(const f16x8*)&sB[buf][boff[n]];
            #pragma unroll
            for (int m = 0; m < 4; ++m) acc[m][n] = MFMA16F(a[m], b, acc[m][n]);
        }
        __syncthreads();
        buf ^= 1;
    }

    const float alpha = alpha_p[0];
    const int q = lane >> 4;
    #pragma unroll
    for (int m = 0; m < 4; ++m)
        #pragma unroll
        for (int n = 0; n < 4; ++n) {
            const int col = ch * 256 + w * 64 + n * 16 + arow;
            const float b2v = eb2[e * DMODEL + col];
            #pragma unroll
            for (int j = 0; j < 4; ++j) {
                const int r = m * 16 + q * 4 + j;
                if (r < nrow)
                    contrib[(size_t)s_pair[r] * DMODEL + col] =
                        f2h(s_w[r] * alpha * (acc[m][n][j] + b2v));
            }
        }
}

// ---------- Kernel 4: combine out = hidden + c0 + c1 ----------
__global__ __launch_bounds__(256) void k_combine(
    const float* __restrict__ hidden, const unsigned short* __restrict__ contrib,
    float* __restrict__ out)
{
    const size_t gid = (size_t)blockIdx.x * 256 + threadIdx.x;
    const int t = (int)(gid >> 6);
    const int c = (int)(gid & 63) * 8;
    const float* hp = hidden + (size_t)t * DMODEL + c;
    float4 h0 = ((const float4*)hp)[0];
    float4 h1 = ((const float4*)hp)[1];
    const unsigned short* c0p = contrib + ((size_t)t * 2 + 0) * DMODEL + c;
    const unsigned short* c1p = contrib + ((size_t)t * 2 + 1) * DMODEL + c;
    ushort4 a0 = ((const ushort4*)c0p)[0], a1 = ((const ushort4*)c0p)[1];
    ushort4 b0 = ((const ushort4*)c1p)[0], b1 = ((const ushort4*)c1p)[1];
    float4 o0, o1;
    o0.x = h0.x + h2f(a0.x) + h2f(b0.x);
    o0.y = h0.y + h2f(a0.y) + h2f(b0.y);
    o0.z = h0.z + h2f(a0.z) + h2f(b0.z);
    o0.w = h0.w + h2f(a0.w) + h2f(b0.w);
    o1.x = h1.x + h2f(a1.x) + h2f(b1.x);
    o1.y = h1.y + h2f(a1.y) + h2f(b1.y);
    o1.z = h1.z + h2f(a1.z) + h2f(b1.z);
    o1.w = h1.w + h2f(a1.w) + h2f(b1.w);
    float* op = out + (size_t)t * DMODEL + c;
    ((float4*)op)[0] = o0;
    ((float4*)op)[1] = o1;
}

// ---------- launch ----------
extern "C" void kernel_launch(void* const* d_in, const int* in_sizes, int n_in,
                              void* d_out, int out_size, void* d_ws, size_t ws_size,
                              hipStream_t stream) {
    const float* hidden = (const float*)d_in[0];
    const float* feat   = (const float*)d_in[1];
    const float* ln_g   = (const float*)d_in[2];
    const float* ln_b   = (const float*)d_in[3];
    const float* stageW = (const float*)d_in[4];
    const float* stageb = (const float*)d_in[5];
    const float* gfW    = (const float*)d_in[6];
    const float* gfb    = (const float*)d_in[7];
    const float* psW1   = (const float*)d_in[8];
    const float* psb1   = (const float*)d_in[9];
    const float* psW2   = (const float*)d_in[10];
    const float* psb2   = (const float*)d_in[11];
    const float* irW1   = (const float*)d_in[12];
    const float* irb1   = (const float*)d_in[13];
    const float* irW2   = (const float*)d_in[14];
    const float* irb2   = (const float*)d_in[15];
    const float* eW1    = (const float*)d_in[16];
    const float* eb1    = (const float*)d_in[17];
    const float* eW2    = (const float*)d_in[18];
    const float* eb2    = (const float*)d_in[19];
    const float* alpha  = (const float*)d_in[20];

    float* out = (float*)d_out;

    char* p = (char*)d_ws;
    unsigned short* Ahi = (unsigned short*)p; p += (size_t)T_TOKENS * RIN * 2;
    unsigned short* Bhi = (unsigned short*)p; p += (size_t)2048 * RIN * 2;
    unsigned short* eW1T = (unsigned short*)p; p += (size_t)NE * DHID * DMODEL * 2;
    unsigned short* eW2T = (unsigned short*)p; p += (size_t)NE * DMODEL * DHID * 2;
    unsigned short* contrib = (unsigned short*)p; p += (size_t)T_TOKENS * 2 * DMODEL * 2;
    unsigned short* ehbuf = (unsigned short*)p; p += (size_t)T_TOKENS * 2 * DHID * 2;
    float* Dps = (float*)p;   p += (size_t)NG * 64 * DRH * 4;
    float* Cir = (float*)p;   p += (size_t)NG * 8 * DRH * 4;
    float* fbps = (float*)p;  p += (size_t)NG * DRH * 4;
    float* fbir = (float*)p;  p += (size_t)NG * DRH * 4;
    float* glog_buf = (float*)p; p += (size_t)T_TOKENS * NG * 4;
    float* ilog_buf = (float*)p; p += (size_t)T_TOKENS * NG * NES * 4;
    int* counts = (int*)p;    p += 128;
    int* nfix = counts + 16;
    int* fix_list = (int*)p;  p += (size_t)T_TOKENS * 4;
    int* list_tok = (int*)p;  p += (size_t)NE * T_TOKENS * 4;
    float* list_w = (float*)p; p += (size_t)NE * T_TOKENS * 4;
    int* list_slot = (int*)p; p += (size_t)NE * T_TOKENS * 4;

    hipMemsetAsync(counts, 0, 128, stream);

    k_prep<<<T_TOKENS / 4, 256, 0, stream>>>(hidden, feat, ln_g, ln_b, Ahi);

    k_fold_ps<<<dim3(NG, 65), 128, 0, stream>>>(stageW, stageb, psW1, psb1, Dps, fbps);
    k_fold_ir<<<dim3(NG, 9), 128, 0, stream>>>(gfW, gfb, irW1, irb1, Cir, fbir);

    k_bsplitT<<<dim3(64, NG), 256, 0, stream>>>(
        psW1, Bhi, 512, DRH, RIN, 0, (long)RIN * DRH, (long)DRH * RIN);
    k_bsplitT<<<dim3(64, NG), 256, 0, stream>>>(
        irW1, Bhi + (size_t)1024 * RIN, 512, DRH, RIN, 0, (long)RIN * DRH, (long)DRH * RIN);
    k_bsplitT<<<dim3(8, NG), 256, 0, stream>>>(
        Dps, Bhi, 64, DRH, RIN, 512, (long)64 * DRH, (long)DRH * RIN);
    k_irtail<<<NG, 128, 0, stream>>>(Cir, Bhi);

    k_bsplitT<<<dim3(128, NE), 256, 0, stream>>>(
        eW1, eW1T, DMODEL, DHID, DMODEL, 0, (long)DMODEL * DHID, (long)DHID * DMODEL);
    k_bsplitT<<<dim3(128, NE), 256, 0, stream>>>(
        eW2, eW2T, DHID, DMODEL, DHID, 0, (long)DHID * DMODEL, (long)DMODEL * DHID);

    k_rgemm<<<dim3(T_TOKENS / 128, 8), 512, 0, stream>>>(
        Ahi, Bhi, fbps, psW2, psb2, fbir, irW2, irb2, glog_buf, ilog_buf);

    hg_finalize2<<<T_TOKENS / 256, 256, 0, stream>>>(
        glog_buf, ilog_buf, counts, nfix, fix_list, list_tok, list_w, list_slot);

    hg_fixup<<<1024, 256, 0, stream>>>(
        hidden, feat, ln_g, ln_b, stageW, stageb, gfW, gfb,
        psW1, psb1, psW2, psb2, irW1, irb1, irW2, irb2,
        nfix, fix_list, counts, list_tok, list_w, list_slot);

    k_e1<<<dim3(T_TOKENS / 64, NE), 256, 0, stream>>>(
        Ahi, eW1T, eb1, counts, list_tok, list_slot, ehbuf);

    k_e2<<<dim3(T_TOKENS / 64, NE, 2), 256, 0, stream>>>(
        ehbuf, eW2T, eb2, alpha, counts, list_tok, list_w, list_slot, contrib);

    k_combine<<<(T_TOKENS * DMODEL / 8) / 256, 256, 0, stream>>>(hidden, contrib, out);
}